// Round 1
// baseline (6107.859 us; speedup 1.0000x reference)
//
#include <hip/hip_runtime.h>
#include <stdint.h>

#define B_   2
#define T_   16
#define D_   128
#define D2_  256
#define H_   64
#define W_   64
#define HW_  4096
#define BT_  32
#define N_   8192
#define ND_  1048576           // N_*D_
#define PLANE_ 16777216        // B*T*D*H*W  (one of re/im)
#define WT_FLOATS 589824       // 256*256*9

// ---------------- device helpers ----------------

__device__ __forceinline__ float softplus_f(float x) {
  // matches jax.nn.softplus = logaddexp(x, 0)
  return fmaxf(x, 0.0f) + log1pf(expf(-fabsf(x)));
}

__device__ __forceinline__ float gelu_tanh(float x) {
  // jax.nn.gelu(approximate=True)
  const float kA = 0.7978845608028654f;  // sqrt(2/pi)
  float x3 = x * x * x;
  return 0.5f * x * (1.0f + tanhf(kA * fmaf(0.044715f, x3, x)));
}

// ---------------- kernel 0: conv weight transpose [co][ci][k] -> [k][ci][co] ----------------

__global__ __launch_bounds__(256) void k_wt(const float* __restrict__ wg,
                                            float* __restrict__ wt) {
  int idx = blockIdx.x * 256 + threadIdx.x;
  if (idx >= 256 * 256 * 9) return;
  int kk = idx % 9;
  int rem = idx / 9;
  int ci = rem & 255;
  int co = rem >> 8;
  wt[((size_t)kk * 256 + ci) * 256 + co] = wg[idx];
}

// ---------------- kernel 1: spatial complex LN + metric scale -> xri [BT][256][H][W] ----------------

__global__ __launch_bounds__(256) void k_spatial_ln(
    const float* __restrict__ x_re, const float* __restrict__ x_im,
    const float* __restrict__ g, const float* __restrict__ bb,
    const float* __restrict__ metric, float* __restrict__ xri) {
  __shared__ float vals[256][64];
  __shared__ float red1[4][64];
  __shared__ float red2[4][64];
  __shared__ float mean_s[64];
  __shared__ float rstd_s[64];
  const int blk = blockIdx.x;      // bt*64 + h
  const int bt = blk >> 6;
  const int h = blk & 63;
  const int tid = threadIdx.x;
  const int w = tid & 63, q = tid >> 6;

  float s1 = 0.f, s2 = 0.f;
  #pragma unroll 4
  for (int i = 0; i < 64; ++i) {
    const int c = i * 4 + q;
    const int d = c & 127;
    const float* src = (c < 128) ? x_re : x_im;
    float v = src[((size_t)bt * D_ + d) * HW_ + h * W_ + w];
    vals[c][w] = v;
    s1 += v; s2 += v * v;
  }
  red1[q][w] = s1; red2[q][w] = s2;
  __syncthreads();
  if (tid < 64) {
    float m = red1[0][tid] + red1[1][tid] + red1[2][tid] + red1[3][tid];
    float ss = red2[0][tid] + red2[1][tid] + red2[2][tid] + red2[3][tid];
    m *= (1.f / 256.f);
    float var = ss * (1.f / 256.f) - m * m;
    mean_s[tid] = m;
    rstd_s[tid] = rsqrtf(var + 1e-5f);
  }
  __syncthreads();
  const float m = mean_s[w], rs = rstd_s[w];
  #pragma unroll 4
  for (int i = 0; i < 64; ++i) {
    const int c = i * 4 + q;
    float v = (vals[c][w] - m) * rs * g[c] + bb[c];
    v *= metric[(size_t)c * HW_ + h * W_ + w];
    xri[((size_t)bt * D2_ + c) * HW_ + h * W_ + w] = v;
  }
}

// ---------------- kernel 2: 3x3 conv (256->256) + bias + residual -> x2 planar ----------------
// block: one (bt, h) row; tile 64 w x 256 co; 256 threads, 8x8 per thread.

__global__ __launch_bounds__(256) void k_conv(
    const float* __restrict__ xri, const float* __restrict__ wt,
    const float* __restrict__ bias,
    const float* __restrict__ x_re, const float* __restrict__ x_im,
    float* __restrict__ x2_re, float* __restrict__ x2_im) {
  __shared__ float As[32][64];
  __shared__ float Bs[32][256];
  const int blk = blockIdx.x;      // bt*64 + h
  const int h = blk & 63;
  const int bt = blk >> 6;
  const int tid = threadIdx.x;
  const int tx = tid & 31;   // co group: co = tx*8+j
  const int ty = tid >> 5;   // 0..7: w group: w = ty*8+i

  float acc[8][8];
  #pragma unroll
  for (int i = 0; i < 8; ++i)
    #pragma unroll
    for (int j = 0; j < 8; ++j) acc[i][j] = 0.f;

  for (int kh = 0; kh < 3; ++kh) {
    const int hh = h + kh - 1;
    const bool hok = (hh >= 0) && (hh < 64);
    for (int kw = 0; kw < 3; ++kw) {
      const int kk = kh * 3 + kw;
      for (int cc = 0; cc < 8; ++cc) {
        __syncthreads();
        // stage input slice (32 ci x 64 w), shifted by (kh-1, kw-1), zero-padded
        #pragma unroll
        for (int r = 0; r < 8; ++r) {
          int idx = r * 256 + tid;
          int ci = idx >> 6, ww = idx & 63;
          int wsrc = ww + kw - 1;
          float v = 0.f;
          if (hok && wsrc >= 0 && wsrc < 64)
            v = xri[((size_t)bt * D2_ + cc * 32 + ci) * HW_ + hh * W_ + wsrc];
          As[ci][ww] = v;
        }
        // stage weights (32 ci x 256 co), coalesced from pre-transposed wt
        #pragma unroll
        for (int r = 0; r < 32; ++r) {
          Bs[r][tid] = wt[((size_t)kk * 256 + cc * 32 + r) * 256 + tid];
        }
        __syncthreads();
        #pragma unroll 4
        for (int k = 0; k < 32; ++k) {
          float4 a0 = *(const float4*)&As[k][ty * 8];
          float4 a1 = *(const float4*)&As[k][ty * 8 + 4];
          float4 b0 = *(const float4*)&Bs[k][tx * 8];
          float4 b1 = *(const float4*)&Bs[k][tx * 8 + 4];
          float av[8] = {a0.x, a0.y, a0.z, a0.w, a1.x, a1.y, a1.z, a1.w};
          float bv[8] = {b0.x, b0.y, b0.z, b0.w, b1.x, b1.y, b1.z, b1.w};
          #pragma unroll
          for (int i = 0; i < 8; ++i)
            #pragma unroll
            for (int j = 0; j < 8; ++j)
              acc[i][j] = fmaf(av[i], bv[j], acc[i][j]);
        }
      }
    }
  }
  // epilogue: bias + residual(original x), split re/im
  #pragma unroll
  for (int j = 0; j < 8; ++j) {
    const int c = tx * 8 + j;
    const int d = c & 127;
    const float bv = bias[c];
    const float* resid = (c < 128) ? x_re : x_im;
    float* dst = (c < 128) ? x2_re : x2_im;
    #pragma unroll
    for (int i = 0; i < 8; ++i) {
      const int ww = ty * 8 + i;
      const size_t off = ((size_t)bt * D_ + d) * HW_ + h * W_ + ww;
      dst[off] = acc[i][j] + bv + resid[off];
    }
  }
}

// ---------------- kernel 3: temporal complex LN + encode + src + ZOH forcing -> u [T][N][D] ----------------
// block: (b, t, h); 64 w-sites x full D. (stochastic term intentionally omitted this round)

__global__ __launch_bounds__(256) void k_temporal(
    const float* __restrict__ x2_re, const float* __restrict__ x2_im,
    const float* __restrict__ dt,
    const float* __restrict__ g, const float* __restrict__ bb,
    const float* __restrict__ enc_re, const float* __restrict__ enc_im,
    const float* __restrict__ nu, const float* __restrict__ theta,
    const float* __restrict__ src_gain,
    float* __restrict__ u_re, float* __restrict__ u_im) {
  __shared__ float xr[64][129];
  __shared__ float xi[64][129];
  __shared__ float red1[4][64], red2[4][64];
  __shared__ float mean_s[64], rstd_s[64];
  __shared__ float fre_s[128], fim_s[128], gain_s[128];
  const int blk = blockIdx.x;          // ((b*16)+t)*64 + h
  const int h = blk & 63;
  const int t = (blk >> 6) & 15;
  const int b = blk >> 10;
  const int tid = threadIdx.x;
  const int w = tid & 63, q = tid >> 6;
  const float dtv = dt[b * T_ + t];
  const size_t img = ((size_t)(b * T_ + t)) * D_ * HW_ + h * W_ + w;

  float s1 = 0.f, s2 = 0.f;
  #pragma unroll 4
  for (int i = 0; i < 32; ++i) {
    const int d = i * 4 + q;
    float vr = x2_re[img + (size_t)d * HW_];
    float vi = x2_im[img + (size_t)d * HW_];
    xr[w][d] = vr; xi[w][d] = vi;
    s1 += vr + vi;
    s2 += vr * vr + vi * vi;
  }
  red1[q][w] = s1; red2[q][w] = s2;
  __syncthreads();
  if (tid < 64) {
    float m = red1[0][tid] + red1[1][tid] + red1[2][tid] + red1[3][tid];
    float ss = red2[0][tid] + red2[1][tid] + red2[2][tid] + red2[3][tid];
    m *= (1.f / 256.f);
    float var = ss * (1.f / 256.f) - m * m;
    mean_s[tid] = m; rstd_s[tid] = rsqrtf(var + 1e-5f);
  }
  if (tid < 128) {
    const int d = tid;
    float lr = -softplus_f(nu[d]);
    float li = theta[d];
    float s, c;
    sincosf(li * dtv, &s, &c);
    float er = expf(lr * dtv);
    float dcr = er * c, dci = er * s;       // op_decay
    float den = lr * lr + li * li;
    float nr = dcr - 1.f, ni = dci;
    fre_s[d] = (nr * lr + ni * li) / den;   // (decay-1)/lam
    fim_s[d] = (ni * lr - nr * li) / den;
    gain_s[d] = src_gain[d];
  }
  __syncthreads();
  {
    const float m = mean_s[w], rs = rstd_s[w];
    #pragma unroll 4
    for (int i = 0; i < 32; ++i) {
      const int d = i * 4 + q;
      xr[w][d] = (xr[w][d] - m) * rs * g[d] + bb[d];
      xi[w][d] = (xi[w][d] - m) * rs * g[128 + d] + bb[128 + d];
    }
  }
  __syncthreads();

  // complex GEMM: xe[w][j] = sum_d xn[w][d] * enc[d][j]
  const int tx = tid & 15, ty = tid >> 4;
  const int w0 = ty * 4, j0 = tx * 8;
  float accr[4][8], acci[4][8];
  #pragma unroll
  for (int i = 0; i < 4; ++i)
    #pragma unroll
    for (int j = 0; j < 8; ++j) { accr[i][j] = 0.f; acci[i][j] = 0.f; }

  for (int k = 0; k < 128; ++k) {
    float ar[4], ai[4];
    #pragma unroll
    for (int i = 0; i < 4; ++i) { ar[i] = xr[w0 + i][k]; ai[i] = xi[w0 + i][k]; }
    float4 er0 = *(const float4*)&enc_re[(size_t)k * D_ + j0];
    float4 er1 = *(const float4*)&enc_re[(size_t)k * D_ + j0 + 4];
    float4 ei0 = *(const float4*)&enc_im[(size_t)k * D_ + j0];
    float4 ei1 = *(const float4*)&enc_im[(size_t)k * D_ + j0 + 4];
    float br[8] = {er0.x, er0.y, er0.z, er0.w, er1.x, er1.y, er1.z, er1.w};
    float bi[8] = {ei0.x, ei0.y, ei0.z, ei0.w, ei1.x, ei1.y, ei1.z, ei1.w};
    #pragma unroll
    for (int i = 0; i < 4; ++i)
      #pragma unroll
      for (int j = 0; j < 8; ++j) {
        accr[i][j] += ar[i] * br[j] - ai[i] * bi[j];
        acci[i][j] += ar[i] * bi[j] + ai[i] * br[j];
      }
  }

  const int nbase = (b * 64 + h) * 64;
  #pragma unroll
  for (int i = 0; i < 4; ++i) {
    const int ww = w0 + i;
    const int nidx = nbase + ww;
    const size_t orow = (size_t)t * ND_ + (size_t)nidx * D_;
    #pragma unroll
    for (int j = 0; j < 8; ++j) {
      const int dd = j0 + j;
      float xer = accr[i][j], xei = acci[i][j];
      float sr = tanhf(xer) * gain_s[dd];
      float si = tanhf(xei) * gain_s[dd];
      float vr = xer + sr, vi = xei + si;
      float ur = vr * fre_s[dd] - vi * fim_s[dd];
      float ui = vr * fim_s[dd] + vi * fre_s[dd];
      u_re[orow + dd] = ur;
      u_im[orow + dd] = ui;
    }
  }
}

// ---------------- kernel 4: sequential scan over T (in place) ----------------

__global__ __launch_bounds__(256) void k_scan(
    float* __restrict__ u_re, float* __restrict__ u_im,
    const float* __restrict__ dt,
    const float* __restrict__ nu, const float* __restrict__ theta) {
  const int idx = blockIdx.x * 256 + threadIdx.x;   // n*128 + d
  const int d = idx & 127;
  const int n = idx >> 7;
  const int b = n >> 12;
  const float lr = -softplus_f(nu[d]);
  const float li = theta[d];
  float hr = 0.f, hi = 0.f;
  for (int t = 0; t < 16; ++t) {
    const float dtv = dt[b * 16 + t];
    float s, c;
    sincosf(li * dtv, &s, &c);
    const float er = expf(lr * dtv);
    const float ar = er * c, ai = er * s;
    const size_t off = (size_t)t * ND_ + idx;
    const float ur = u_re[off], ui = u_im[off];
    const float nr = ar * hr - ai * hi + ur;
    const float ni = ar * hi + ai * hr + ui;
    hr = nr; hi = ni;
    u_re[off] = hr; u_im[off] = hi;
  }
}

// ---------------- kernel 5: decode (real part) + residual add (in place on x2_re) ----------------

__global__ __launch_bounds__(256) void k_decode(
    const float* __restrict__ h_re, const float* __restrict__ h_im,
    const float* __restrict__ dec_re, const float* __restrict__ dec_im,
    float* __restrict__ x2_re) {
  __shared__ float hr[64][129];
  __shared__ float hi[64][129];
  const int blk = blockIdx.x;          // ((b*16)+t)*64 + h
  const int hh = blk & 63;
  const int t = (blk >> 6) & 15;
  const int b = blk >> 10;
  const int tid = threadIdx.x;
  const size_t rowbase = (size_t)t * ND_ + (size_t)((b * 64 + hh) * 64) * D_;
  #pragma unroll
  for (int it = 0; it < 32; ++it) {
    int flat = it * 256 + tid;
    int d = flat & 127, w = flat >> 7;
    hr[w][d] = h_re[rowbase + (size_t)w * D_ + d];
    hi[w][d] = h_im[rowbase + (size_t)w * D_ + d];
  }
  __syncthreads();
  const int tx = tid & 15, ty = tid >> 4;
  const int w0 = ty * 4, j0 = tx * 8;
  float acc[4][8];
  #pragma unroll
  for (int i = 0; i < 4; ++i)
    #pragma unroll
    for (int j = 0; j < 8; ++j) acc[i][j] = 0.f;

  for (int k = 0; k < 128; ++k) {
    float ar[4], ai[4];
    #pragma unroll
    for (int i = 0; i < 4; ++i) { ar[i] = hr[w0 + i][k]; ai[i] = hi[w0 + i][k]; }
    float4 dr0 = *(const float4*)&dec_re[(size_t)k * D_ + j0];
    float4 dr1 = *(const float4*)&dec_re[(size_t)k * D_ + j0 + 4];
    float4 di0 = *(const float4*)&dec_im[(size_t)k * D_ + j0];
    float4 di1 = *(const float4*)&dec_im[(size_t)k * D_ + j0 + 4];
    float br[8] = {dr0.x, dr0.y, dr0.z, dr0.w, dr1.x, dr1.y, dr1.z, dr1.w};
    float bi[8] = {di0.x, di0.y, di0.z, di0.w, di1.x, di1.y, di1.z, di1.w};
    #pragma unroll
    for (int i = 0; i < 4; ++i)
      #pragma unroll
      for (int j = 0; j < 8; ++j)
        acc[i][j] += ar[i] * br[j] - ai[i] * bi[j];   // real part only
  }
  #pragma unroll
  for (int j = 0; j < 8; ++j) {
    const int dd = j0 + j;
    const size_t ob = ((size_t)(b * 16 + t) * D_ + dd) * HW_ + hh * W_;
    #pragma unroll
    for (int i = 0; i < 4; ++i) {
      const int ww = w0 + i;
      x2_re[ob + ww] += acc[i][j];
    }
  }
}

// ---------------- kernel 6: complex FFN + final residual, writes [B,T,D,H,W,2] ----------------
// 512 threads; chunked hidden (8 x 64); act staged in LDS; coalesced float2 output via LDS.

__global__ __launch_bounds__(512) void k_ffn(
    const float* __restrict__ x3_re, const float* __restrict__ x3_im,
    const float* __restrict__ w1_re, const float* __restrict__ w1_im,
    const float* __restrict__ b1_re, const float* __restrict__ b1_im,
    const float* __restrict__ w2_re, const float* __restrict__ w2_im,
    const float* __restrict__ b2_re, const float* __restrict__ b2_im,
    float* __restrict__ out) {
  __shared__ float xr[64][129], xi[64][129];
  __shared__ float actr[64][68], acti[64][68];
  const int blk = blockIdx.x;          // bt*64 + hh
  const int hh = blk & 63;
  const int bt = blk >> 6;
  const int tid = threadIdx.x;
  {
    const int w = tid & 63, q = tid >> 6;   // q: 0..7
    #pragma unroll
    for (int i = 0; i < 16; ++i) {
      const int d = i * 8 + q;
      const size_t off = ((size_t)bt * D_ + d) * HW_ + hh * W_ + w;
      xr[w][d] = x3_re[off];
      xi[w][d] = x3_im[off];
    }
  }
  __syncthreads();
  const int tx = tid & 15;   // 0..15
  const int ty = tid >> 4;   // 0..31
  const int w0 = ty * 2;
  const int j0 = tx * 4;     // within 64-wide hidden chunk
  const int o0 = tx * 8;     // output dout group

  float dacc[2][8][2];
  #pragma unroll
  for (int wi = 0; wi < 2; ++wi)
    #pragma unroll
    for (int j = 0; j < 8; ++j) { dacc[wi][j][0] = 0.f; dacc[wi][j][1] = 0.f; }

  for (int c = 0; c < 8; ++c) {
    float hacc[2][4][2];
    #pragma unroll
    for (int wi = 0; wi < 2; ++wi)
      #pragma unroll
      for (int j = 0; j < 4; ++j) { hacc[wi][j][0] = 0.f; hacc[wi][j][1] = 0.f; }

    for (int k = 0; k < 128; ++k) {
      const float a0r = xr[w0][k],     a0i = xi[w0][k];
      const float a1r = xr[w0 + 1][k], a1i = xi[w0 + 1][k];
      const float4 b_r = *(const float4*)&w1_re[(size_t)k * 512 + c * 64 + j0];
      const float4 b_i = *(const float4*)&w1_im[(size_t)k * 512 + c * 64 + j0];
      const float brj[4] = {b_r.x, b_r.y, b_r.z, b_r.w};
      const float bij[4] = {b_i.x, b_i.y, b_i.z, b_i.w};
      #pragma unroll
      for (int j = 0; j < 4; ++j) {
        hacc[0][j][0] += a0r * brj[j] - a0i * bij[j];
        hacc[0][j][1] += a0r * bij[j] + a0i * brj[j];
        hacc[1][j][0] += a1r * brj[j] - a1i * bij[j];
        hacc[1][j][1] += a1r * bij[j] + a1i * brj[j];
      }
    }
    __syncthreads();   // previous chunk's GEMM2 done reading act
    #pragma unroll
    for (int wi = 0; wi < 2; ++wi) {
      float4 vr, vi;
      float* pr = (float*)&vr;
      float* pi = (float*)&vi;
      #pragma unroll
      for (int j = 0; j < 4; ++j) {
        const int jj = c * 64 + j0 + j;
        pr[j] = gelu_tanh(hacc[wi][j][0] + b1_re[jj]);
        pi[j] = gelu_tanh(hacc[wi][j][1] + b1_im[jj]);
      }
      *(float4*)&actr[w0 + wi][j0] = vr;
      *(float4*)&acti[w0 + wi][j0] = vi;
    }
    __syncthreads();
    for (int k = 0; k < 64; ++k) {
      const float a0r = actr[w0][k],     a0i = acti[w0][k];
      const float a1r = actr[w0 + 1][k], a1i = acti[w0 + 1][k];
      const float4 c_r0 = *(const float4*)&w2_re[(size_t)(c * 64 + k) * D_ + o0];
      const float4 c_r1 = *(const float4*)&w2_re[(size_t)(c * 64 + k) * D_ + o0 + 4];
      const float4 c_i0 = *(const float4*)&w2_im[(size_t)(c * 64 + k) * D_ + o0];
      const float4 c_i1 = *(const float4*)&w2_im[(size_t)(c * 64 + k) * D_ + o0 + 4];
      const float brj[8] = {c_r0.x, c_r0.y, c_r0.z, c_r0.w, c_r1.x, c_r1.y, c_r1.z, c_r1.w};
      const float bij[8] = {c_i0.x, c_i0.y, c_i0.z, c_i0.w, c_i1.x, c_i1.y, c_i1.z, c_i1.w};
      #pragma unroll
      for (int j = 0; j < 8; ++j) {
        dacc[0][j][0] += a0r * brj[j] - a0i * bij[j];
        dacc[0][j][1] += a0r * bij[j] + a0i * brj[j];
        dacc[1][j][0] += a1r * brj[j] - a1i * bij[j];
        dacc[1][j][1] += a1r * bij[j] + a1i * brj[j];
      }
    }
  }

  // output: stage 64-dout half-panels through act LDS for coalesced float2 stores
  for (int p = 0; p < 2; ++p) {
    __syncthreads();
    if ((o0 >> 6) == p) {
      const int col = o0 & 63;
      #pragma unroll
      for (int wi = 0; wi < 2; ++wi) {
        #pragma unroll
        for (int j = 0; j < 8; ++j) {
          const int dd = o0 + j;
          actr[w0 + wi][col + j] = xr[w0 + wi][dd] + dacc[wi][j][0] + b2_re[dd];
          acti[w0 + wi][col + j] = xi[w0 + wi][dd] + dacc[wi][j][1] + b2_im[dd];
        }
      }
    }
    __syncthreads();
    const int w = tid & 63, q = tid >> 6;
    #pragma unroll
    for (int i = 0; i < 8; ++i) {
      const int ddl = i * 8 + q;
      const int dd = p * 64 + ddl;
      float2 v;
      v.x = actr[w][ddl];
      v.y = acti[w][ddl];
      *(float2*)&out[(((size_t)bt * D_ + dd) * HW_ + hh * W_ + w) * 2] = v;
    }
  }
}

// ---------------- host launcher ----------------

extern "C" void kernel_launch(void* const* d_in, const int* in_sizes, int n_in,
                              void* d_out, int out_size, void* d_ws, size_t ws_size,
                              hipStream_t stream) {
  const float* x_re   = (const float*)d_in[0];
  const float* x_im   = (const float*)d_in[1];
  const float* dt     = (const float*)d_in[2];
  const float* ln_s_g = (const float*)d_in[3];
  const float* ln_s_b = (const float*)d_in[4];
  const float* ln_t_g = (const float*)d_in[5];
  const float* ln_t_b = (const float*)d_in[6];
  const float* metric = (const float*)d_in[7];
  const float* conv_w = (const float*)d_in[8];
  const float* conv_b = (const float*)d_in[9];
  const float* nu     = (const float*)d_in[10];
  const float* theta  = (const float*)d_in[11];
  const float* enc_re = (const float*)d_in[12];
  const float* enc_im = (const float*)d_in[13];
  const float* dec_re = (const float*)d_in[14];
  const float* dec_im = (const float*)d_in[15];
  const float* src_g  = (const float*)d_in[16];
  const float* w1_re  = (const float*)d_in[17];
  const float* w1_im  = (const float*)d_in[18];
  const float* b1_re  = (const float*)d_in[19];
  const float* b1_im  = (const float*)d_in[20];
  const float* w2_re  = (const float*)d_in[21];
  const float* w2_im  = (const float*)d_in[22];
  const float* b2_re  = (const float*)d_in[23];
  const float* b2_im  = (const float*)d_in[24];
  float* out = (float*)d_out;
  float* ws = (float*)d_ws;

  // workspace layout
  float* wt   = ws;                          // 589,824 floats
  float* bufA = ws + WT_FLOATS;              // 33,554,432 floats (xri, then u/h)
  float* u_re = bufA;
  float* u_im = bufA + PLANE_;

  const size_t needA = (size_t)(WT_FLOATS + 2 * PLANE_ + 2 * PLANE_) * 4;
  const bool planA = ws_size >= needA;
  float *x2_re, *x2_im, *ffn_out;
  if (planA) {
    x2_re = bufA + 2 * (size_t)PLANE_;       // ws-resident x2
    x2_im = x2_re + PLANE_;
    ffn_out = out;
  } else {
    // plan B: x2/x3 planar live in d_out; FFN writes bufA; final d2d copy
    x2_re = out;
    x2_im = out + PLANE_;
    ffn_out = bufA;
  }

  k_wt<<<2304, 256, 0, stream>>>(conv_w, wt);
  k_spatial_ln<<<BT_ * H_, 256, 0, stream>>>(x_re, x_im, ln_s_g, ln_s_b, metric, bufA);
  k_conv<<<BT_ * H_, 256, 0, stream>>>(bufA, wt, conv_b, x_re, x_im, x2_re, x2_im);
  k_temporal<<<B_ * T_ * H_, 256, 0, stream>>>(x2_re, x2_im, dt, ln_t_g, ln_t_b,
                                               enc_re, enc_im, nu, theta, src_g,
                                               u_re, u_im);
  k_scan<<<ND_ / 256, 256, 0, stream>>>(u_re, u_im, dt, nu, theta);
  k_decode<<<B_ * T_ * H_, 256, 0, stream>>>(u_re, u_im, dec_re, dec_im, x2_re);
  k_ffn<<<BT_ * H_, 512, 0, stream>>>(x2_re, x2_im, w1_re, w1_im, b1_re, b1_im,
                                      w2_re, w2_im, b2_re, b2_im, ffn_out);
  if (!planA) {
    hipMemcpyAsync(d_out, ffn_out, (size_t)2 * PLANE_ * sizeof(float),
                   hipMemcpyDeviceToDevice, stream);
  }
}

// Round 2
// 3248.699 us; speedup vs baseline: 1.8801x; 1.8801x over previous
//
#include <hip/hip_runtime.h>
#include <stdint.h>

#define B_   2
#define T_   16
#define D_   128
#define D2_  256
#define H_   64
#define W_   64
#define HW_  4096
#define BT_  32
#define N_   8192
#define ND_  1048576           // N_*D_
#define PLANE_ 16777216        // B*T*D*H*W  (one of re/im)
#define WT_FLOATS 589824       // 256*256*9

typedef short bf16x8 __attribute__((ext_vector_type(8)));
typedef float f32x4 __attribute__((ext_vector_type(4)));
typedef unsigned int uint;
typedef unsigned short ushort;

// ---------------- device helpers ----------------

__device__ __forceinline__ float softplus_f(float x) {
  return fmaxf(x, 0.0f) + log1pf(expf(-fabsf(x)));
}

__device__ __forceinline__ float gelu_tanh(float x) {
  const float kA = 0.7978845608028654f;  // sqrt(2/pi)
  float x3 = x * x * x;
  return 0.5f * x * (1.0f + tanhf(kA * fmaf(0.044715f, x3, x)));
}

__device__ __forceinline__ ushort f2bf(float f) {
  uint u = __float_as_uint(f);
  uint r = (u + 0x7fffu + ((u >> 16) & 1u)) >> 16;   // RNE
  return (ushort)r;
}

__device__ __forceinline__ uint pack2bf(float a, float b) {
  return (uint)f2bf(a) | ((uint)f2bf(b) << 16);
}

// ---------------- kernel 0: conv weight transpose [co][ci][k] -> [k][ci][co] ----------------

__global__ __launch_bounds__(256) void k_wt(const float* __restrict__ wg,
                                            float* __restrict__ wt) {
  int idx = blockIdx.x * 256 + threadIdx.x;
  if (idx >= 256 * 256 * 9) return;
  int kk = idx % 9;
  int rem = idx / 9;
  int ci = rem & 255;
  int co = rem >> 8;
  wt[((size_t)kk * 256 + ci) * 256 + co] = wg[idx];
}

// ---------------- kernel 1: spatial complex LN + metric scale -> xri [BT][256][H][W] ----------------

__global__ __launch_bounds__(256) void k_spatial_ln(
    const float* __restrict__ x_re, const float* __restrict__ x_im,
    const float* __restrict__ g, const float* __restrict__ bb,
    const float* __restrict__ metric, float* __restrict__ xri) {
  __shared__ float vals[256][64];
  __shared__ float red1[4][64];
  __shared__ float red2[4][64];
  __shared__ float mean_s[64];
  __shared__ float rstd_s[64];
  const int blk = blockIdx.x;      // bt*64 + h
  const int bt = blk >> 6;
  const int h = blk & 63;
  const int tid = threadIdx.x;
  const int w = tid & 63, q = tid >> 6;

  float s1 = 0.f, s2 = 0.f;
  #pragma unroll 4
  for (int i = 0; i < 64; ++i) {
    const int c = i * 4 + q;
    const int d = c & 127;
    const float* src = (c < 128) ? x_re : x_im;
    float v = src[((size_t)bt * D_ + d) * HW_ + h * W_ + w];
    vals[c][w] = v;
    s1 += v; s2 += v * v;
  }
  red1[q][w] = s1; red2[q][w] = s2;
  __syncthreads();
  if (tid < 64) {
    float m = red1[0][tid] + red1[1][tid] + red1[2][tid] + red1[3][tid];
    float ss = red2[0][tid] + red2[1][tid] + red2[2][tid] + red2[3][tid];
    m *= (1.f / 256.f);
    float var = ss * (1.f / 256.f) - m * m;
    mean_s[tid] = m;
    rstd_s[tid] = rsqrtf(var + 1e-5f);
  }
  __syncthreads();
  const float m = mean_s[w], rs = rstd_s[w];
  #pragma unroll 4
  for (int i = 0; i < 64; ++i) {
    const int c = i * 4 + q;
    float v = (vals[c][w] - m) * rs * g[c] + bb[c];
    v *= metric[(size_t)c * HW_ + h * W_ + w];
    xri[((size_t)bt * D2_ + c) * HW_ + h * W_ + w] = v;
  }
}

// ---------------- kernel 2: 3x3 conv (256->256) + bias + residual -> x2 planar ----------------

__global__ __launch_bounds__(256) void k_conv(
    const float* __restrict__ xri, const float* __restrict__ wt,
    const float* __restrict__ bias,
    const float* __restrict__ x_re, const float* __restrict__ x_im,
    float* __restrict__ x2_re, float* __restrict__ x2_im) {
  __shared__ float As[32][64];
  __shared__ float Bs[32][256];
  const int blk = blockIdx.x;      // bt*64 + h
  const int h = blk & 63;
  const int bt = blk >> 6;
  const int tid = threadIdx.x;
  const int tx = tid & 31;   // co group: co = tx*8+j
  const int ty = tid >> 5;   // 0..7: w group: w = ty*8+i

  float acc[8][8];
  #pragma unroll
  for (int i = 0; i < 8; ++i)
    #pragma unroll
    for (int j = 0; j < 8; ++j) acc[i][j] = 0.f;

  for (int kh = 0; kh < 3; ++kh) {
    const int hh = h + kh - 1;
    const bool hok = (hh >= 0) && (hh < 64);
    for (int kw = 0; kw < 3; ++kw) {
      const int kk = kh * 3 + kw;
      for (int cc = 0; cc < 8; ++cc) {
        __syncthreads();
        #pragma unroll
        for (int r = 0; r < 8; ++r) {
          int idx = r * 256 + tid;
          int ci = idx >> 6, ww = idx & 63;
          int wsrc = ww + kw - 1;
          float v = 0.f;
          if (hok && wsrc >= 0 && wsrc < 64)
            v = xri[((size_t)bt * D2_ + cc * 32 + ci) * HW_ + hh * W_ + wsrc];
          As[ci][ww] = v;
        }
        #pragma unroll
        for (int r = 0; r < 32; ++r) {
          Bs[r][tid] = wt[((size_t)kk * 256 + cc * 32 + r) * 256 + tid];
        }
        __syncthreads();
        #pragma unroll 4
        for (int k = 0; k < 32; ++k) {
          float4 a0 = *(const float4*)&As[k][ty * 8];
          float4 a1 = *(const float4*)&As[k][ty * 8 + 4];
          float4 b0 = *(const float4*)&Bs[k][tx * 8];
          float4 b1 = *(const float4*)&Bs[k][tx * 8 + 4];
          float av[8] = {a0.x, a0.y, a0.z, a0.w, a1.x, a1.y, a1.z, a1.w};
          float bv[8] = {b0.x, b0.y, b0.z, b0.w, b1.x, b1.y, b1.z, b1.w};
          #pragma unroll
          for (int i = 0; i < 8; ++i)
            #pragma unroll
            for (int j = 0; j < 8; ++j)
              acc[i][j] = fmaf(av[i], bv[j], acc[i][j]);
        }
      }
    }
  }
  #pragma unroll
  for (int j = 0; j < 8; ++j) {
    const int c = tx * 8 + j;
    const int d = c & 127;
    const float bv = bias[c];
    const float* resid = (c < 128) ? x_re : x_im;
    float* dst = (c < 128) ? x2_re : x2_im;
    #pragma unroll
    for (int i = 0; i < 8; ++i) {
      const int ww = ty * 8 + i;
      const size_t off = ((size_t)bt * D_ + d) * HW_ + h * W_ + ww;
      dst[off] = acc[i][j] + bv + resid[off];
    }
  }
}

// ---------------- kernel 3: temporal complex LN + encode + src + ZOH forcing -> u [T][N][D] ----------------

__global__ __launch_bounds__(256) void k_temporal(
    const float* __restrict__ x2_re, const float* __restrict__ x2_im,
    const float* __restrict__ dt,
    const float* __restrict__ g, const float* __restrict__ bb,
    const float* __restrict__ enc_re, const float* __restrict__ enc_im,
    const float* __restrict__ nu, const float* __restrict__ theta,
    const float* __restrict__ src_gain,
    float* __restrict__ u_re, float* __restrict__ u_im) {
  __shared__ float xr[64][129];
  __shared__ float xi[64][129];
  __shared__ float red1[4][64], red2[4][64];
  __shared__ float mean_s[64], rstd_s[64];
  __shared__ float fre_s[128], fim_s[128], gain_s[128];
  const int blk = blockIdx.x;          // ((b*16)+t)*64 + h
  const int h = blk & 63;
  const int t = (blk >> 6) & 15;
  const int b = blk >> 10;
  const int tid = threadIdx.x;
  const int w = tid & 63, q = tid >> 6;
  const float dtv = dt[b * T_ + t];
  const size_t img = ((size_t)(b * T_ + t)) * D_ * HW_ + h * W_ + w;

  float s1 = 0.f, s2 = 0.f;
  #pragma unroll 4
  for (int i = 0; i < 32; ++i) {
    const int d = i * 4 + q;
    float vr = x2_re[img + (size_t)d * HW_];
    float vi = x2_im[img + (size_t)d * HW_];
    xr[w][d] = vr; xi[w][d] = vi;
    s1 += vr + vi;
    s2 += vr * vr + vi * vi;
  }
  red1[q][w] = s1; red2[q][w] = s2;
  __syncthreads();
  if (tid < 64) {
    float m = red1[0][tid] + red1[1][tid] + red1[2][tid] + red1[3][tid];
    float ss = red2[0][tid] + red2[1][tid] + red2[2][tid] + red2[3][tid];
    m *= (1.f / 256.f);
    float var = ss * (1.f / 256.f) - m * m;
    mean_s[tid] = m; rstd_s[tid] = rsqrtf(var + 1e-5f);
  }
  if (tid < 128) {
    const int d = tid;
    float lr = -softplus_f(nu[d]);
    float li = theta[d];
    float s, c;
    sincosf(li * dtv, &s, &c);
    float er = expf(lr * dtv);
    float dcr = er * c, dci = er * s;
    float den = lr * lr + li * li;
    float nr = dcr - 1.f, ni = dci;
    fre_s[d] = (nr * lr + ni * li) / den;
    fim_s[d] = (ni * lr - nr * li) / den;
    gain_s[d] = src_gain[d];
  }
  __syncthreads();
  {
    const float m = mean_s[w], rs = rstd_s[w];
    #pragma unroll 4
    for (int i = 0; i < 32; ++i) {
      const int d = i * 4 + q;
      xr[w][d] = (xr[w][d] - m) * rs * g[d] + bb[d];
      xi[w][d] = (xi[w][d] - m) * rs * g[128 + d] + bb[128 + d];
    }
  }
  __syncthreads();

  const int tx = tid & 15, ty = tid >> 4;
  const int w0 = ty * 4, j0 = tx * 8;
  float accr[4][8], acci[4][8];
  #pragma unroll
  for (int i = 0; i < 4; ++i)
    #pragma unroll
    for (int j = 0; j < 8; ++j) { accr[i][j] = 0.f; acci[i][j] = 0.f; }

  for (int k = 0; k < 128; ++k) {
    float ar[4], ai[4];
    #pragma unroll
    for (int i = 0; i < 4; ++i) { ar[i] = xr[w0 + i][k]; ai[i] = xi[w0 + i][k]; }
    float4 er0 = *(const float4*)&enc_re[(size_t)k * D_ + j0];
    float4 er1 = *(const float4*)&enc_re[(size_t)k * D_ + j0 + 4];
    float4 ei0 = *(const float4*)&enc_im[(size_t)k * D_ + j0];
    float4 ei1 = *(const float4*)&enc_im[(size_t)k * D_ + j0 + 4];
    float br[8] = {er0.x, er0.y, er0.z, er0.w, er1.x, er1.y, er1.z, er1.w};
    float bi[8] = {ei0.x, ei0.y, ei0.z, ei0.w, ei1.x, ei1.y, ei1.z, ei1.w};
    #pragma unroll
    for (int i = 0; i < 4; ++i)
      #pragma unroll
      for (int j = 0; j < 8; ++j) {
        accr[i][j] += ar[i] * br[j] - ai[i] * bi[j];
        acci[i][j] += ar[i] * bi[j] + ai[i] * br[j];
      }
  }

  const int nbase = (b * 64 + h) * 64;
  #pragma unroll
  for (int i = 0; i < 4; ++i) {
    const int ww = w0 + i;
    const int nidx = nbase + ww;
    const size_t orow = (size_t)t * ND_ + (size_t)nidx * D_;
    #pragma unroll
    for (int j = 0; j < 8; ++j) {
      const int dd = j0 + j;
      float xer = accr[i][j], xei = acci[i][j];
      float sr = tanhf(xer) * gain_s[dd];
      float si = tanhf(xei) * gain_s[dd];
      float vr = xer + sr, vi = xei + si;
      float ur = vr * fre_s[dd] - vi * fim_s[dd];
      float ui = vr * fim_s[dd] + vi * fre_s[dd];
      u_re[orow + dd] = ur;
      u_im[orow + dd] = ui;
    }
  }
}

// ---------------- kernel 4: sequential scan over T (in place) ----------------

__global__ __launch_bounds__(256) void k_scan(
    float* __restrict__ u_re, float* __restrict__ u_im,
    const float* __restrict__ dt,
    const float* __restrict__ nu, const float* __restrict__ theta) {
  const int idx = blockIdx.x * 256 + threadIdx.x;   // n*128 + d
  const int d = idx & 127;
  const int n = idx >> 7;
  const int b = n >> 12;
  const float lr = -softplus_f(nu[d]);
  const float li = theta[d];
  float hr = 0.f, hi = 0.f;
  for (int t = 0; t < 16; ++t) {
    const float dtv = dt[b * 16 + t];
    float s, c;
    sincosf(li * dtv, &s, &c);
    const float er = expf(lr * dtv);
    const float ar = er * c, ai = er * s;
    const size_t off = (size_t)t * ND_ + idx;
    const float ur = u_re[off], ui = u_im[off];
    const float nr = ar * hr - ai * hi + ur;
    const float ni = ar * hi + ai * hr + ui;
    hr = nr; hi = ni;
    u_re[off] = hr; u_im[off] = hi;
  }
}

// ---------------- kernel 5: decode (real part) + residual add (in place on x2_re) ----------------

__global__ __launch_bounds__(256) void k_decode(
    const float* __restrict__ h_re, const float* __restrict__ h_im,
    const float* __restrict__ dec_re, const float* __restrict__ dec_im,
    float* __restrict__ x2_re) {
  __shared__ float hr[64][129];
  __shared__ float hi[64][129];
  const int blk = blockIdx.x;          // ((b*16)+t)*64 + h
  const int hh = blk & 63;
  const int t = (blk >> 6) & 15;
  const int b = blk >> 10;
  const int tid = threadIdx.x;
  const size_t rowbase = (size_t)t * ND_ + (size_t)((b * 64 + hh) * 64) * D_;
  #pragma unroll
  for (int it = 0; it < 32; ++it) {
    int flat = it * 256 + tid;
    int d = flat & 127, w = flat >> 7;
    hr[w][d] = h_re[rowbase + (size_t)w * D_ + d];
    hi[w][d] = h_im[rowbase + (size_t)w * D_ + d];
  }
  __syncthreads();
  const int tx = tid & 15, ty = tid >> 4;
  const int w0 = ty * 4, j0 = tx * 8;
  float acc[4][8];
  #pragma unroll
  for (int i = 0; i < 4; ++i)
    #pragma unroll
    for (int j = 0; j < 8; ++j) acc[i][j] = 0.f;

  for (int k = 0; k < 128; ++k) {
    float ar[4], ai[4];
    #pragma unroll
    for (int i = 0; i < 4; ++i) { ar[i] = hr[w0 + i][k]; ai[i] = hi[w0 + i][k]; }
    float4 dr0 = *(const float4*)&dec_re[(size_t)k * D_ + j0];
    float4 dr1 = *(const float4*)&dec_re[(size_t)k * D_ + j0 + 4];
    float4 di0 = *(const float4*)&dec_im[(size_t)k * D_ + j0];
    float4 di1 = *(const float4*)&dec_im[(size_t)k * D_ + j0 + 4];
    float br[8] = {dr0.x, dr0.y, dr0.z, dr0.w, dr1.x, dr1.y, dr1.z, dr1.w};
    float bi[8] = {di0.x, di0.y, di0.z, di0.w, di1.x, di1.y, di1.z, di1.w};
    #pragma unroll
    for (int i = 0; i < 4; ++i)
      #pragma unroll
      for (int j = 0; j < 8; ++j)
        acc[i][j] += ar[i] * br[j] - ai[i] * bi[j];
  }
  #pragma unroll
  for (int j = 0; j < 8; ++j) {
    const int dd = j0 + j;
    const size_t ob = ((size_t)(b * 16 + t) * D_ + dd) * HW_ + hh * W_;
    #pragma unroll
    for (int i = 0; i < 4; ++i) {
      const int ww = w0 + i;
      x2_re[ob + ww] += acc[i][j];
    }
  }
}

// ---------------- FFN weight prep: pre-swizzled bf16 fragment order ----------------
// B1p (256x1024) packed complex GEMM1 weight, stored transposed in fragment order:
// frag t: ntile=t>>9, ks=(t>>6)&7, lane=t&63; n=ntile*16+(lane&15), k=ks*32+(lane>>4)*8+e

__global__ __launch_bounds__(256) void k_prep_b1(
    const float* __restrict__ w1_re, const float* __restrict__ w1_im,
    ushort* __restrict__ b1swz) {
  const int t = blockIdx.x * 256 + threadIdx.x;   // 0..32767
  const int lane = t & 63;
  const int ks = (t >> 6) & 7;
  const int ntile = t >> 9;
  const int n = ntile * 16 + (lane & 15);
  const int k0 = ks * 32 + (lane >> 4) * 8;
  ushort v[8];
  #pragma unroll
  for (int e = 0; e < 8; ++e) {
    const int k = k0 + e;
    float val;
    if (k < 128) {
      val = (n < 512) ? w1_re[k * 512 + n] : w1_im[k * 512 + (n - 512)];
    } else {
      const int kk = k - 128;
      val = (n < 512) ? -w1_im[kk * 512 + n] : w1_re[kk * 512 + (n - 512)];
    }
    v[e] = f2bf(val);
  }
  uint4 u;
  u.x = (uint)v[0] | ((uint)v[1] << 16);
  u.y = (uint)v[2] | ((uint)v[3] << 16);
  u.z = (uint)v[4] | ((uint)v[5] << 16);
  u.w = (uint)v[6] | ((uint)v[7] << 16);
  ((uint4*)b1swz)[t] = u;
}

// B2p (1024x256): frag t: rowtile=t>>11, kc=(t>>6)&31, lane=t&63

__global__ __launch_bounds__(256) void k_prep_b2(
    const float* __restrict__ w2_re, const float* __restrict__ w2_im,
    ushort* __restrict__ b2swz) {
  const int t = blockIdx.x * 256 + threadIdx.x;   // 0..32767
  const int lane = t & 63;
  const int kc = (t >> 6) & 31;
  const int rowtile = t >> 11;
  const int n2 = rowtile * 16 + (lane & 15);
  const int k0 = kc * 32 + (lane >> 4) * 8;
  ushort v[8];
  #pragma unroll
  for (int e = 0; e < 8; ++e) {
    const int k = k0 + e;
    float val;
    if (k < 512) {
      val = (n2 < 128) ? w2_re[k * 128 + n2] : w2_im[k * 128 + (n2 - 128)];
    } else {
      const int kk = k - 512;
      val = (n2 < 128) ? -w2_im[kk * 128 + n2] : w2_re[kk * 128 + (n2 - 128)];
    }
    v[e] = f2bf(val);
  }
  uint4 u;
  u.x = (uint)v[0] | ((uint)v[1] << 16);
  u.y = (uint)v[2] | ((uint)v[3] << 16);
  u.z = (uint)v[4] | ((uint)v[5] << 16);
  u.w = (uint)v[6] | ((uint)v[7] << 16);
  ((uint4*)b2swz)[t] = u;
}

// ---------------- kernel 6: complex FFN via bf16 MFMA (swapped/transposed form) ----------------
// Block = 64 sites (one bt, one h-row). hdn^T = B1p^T @ x^T, gelu, delta^T = B2p^T @ act^T.
// C-frag col = site, row = packed-n. fp32 residual re-read from global.

__global__ __launch_bounds__(256, 2) void k_ffn_mfma(
    const float* __restrict__ x3_re, const float* __restrict__ x3_im,
    const ushort* __restrict__ b1swz, const ushort* __restrict__ b2swz,
    const float* __restrict__ b1_re, const float* __restrict__ b1_im,
    const float* __restrict__ b2_re, const float* __restrict__ b2_im,
    float* __restrict__ out) {
  __shared__ ushort xlds[64][264];    // [site][k=re0..127,im128..255], pad 8
  __shared__ ushort actlds[64][136];  // [site][nlocal 0..127], pad 8
  const int tid = threadIdx.x;
  const int wave = tid >> 6, lane = tid & 63;
  const int lrow = lane & 15, lgrp = lane >> 4;
  const int blk = blockIdx.x;        // 2048 = bt*64 + h
  const int bt = blk >> 6;
  const int hw0 = (blk & 63) * 64;
  const size_t base = (size_t)bt * D_ * HW_ + hw0;

  // stage x -> bf16 LDS (transposed), packed 2 d's per b32 write
  uint* xlds32 = (uint*)&xlds[0][0];
  #pragma unroll
  for (int i = 0; i < 16; ++i) {
    const int p = i * 4 + wave;      // d-pair 0..63
    const float r0 = x3_re[base + (size_t)(2 * p) * HW_ + lane];
    const float r1 = x3_re[base + (size_t)(2 * p + 1) * HW_ + lane];
    const float i0 = x3_im[base + (size_t)(2 * p) * HW_ + lane];
    const float i1 = x3_im[base + (size_t)(2 * p + 1) * HW_ + lane];
    xlds32[lane * 132 + p] = pack2bf(r0, r1);
    xlds32[lane * 132 + 64 + p] = pack2bf(i0, i1);
  }
  __syncthreads();

  f32x4 dacc[4][4];
  #pragma unroll
  for (int rt = 0; rt < 4; ++rt)
    #pragma unroll
    for (int st = 0; st < 4; ++st) dacc[rt][st] = (f32x4)0.f;

  uint* act32 = (uint*)&actlds[0][0];

  for (int chunk = 0; chunk < 8; ++chunk) {
    // ---- GEMM1: hdn^T chunk (128 n) ; wave handles n-tiles {wave*2, wave*2+1}
    f32x4 hacc[2][4];
    #pragma unroll
    for (int ntl = 0; ntl < 2; ++ntl)
      #pragma unroll
      for (int st = 0; st < 4; ++st) hacc[ntl][st] = (f32x4)0.f;

    #pragma unroll
    for (int ks = 0; ks < 8; ++ks) {
      bf16x8 bfr[4];
      #pragma unroll
      for (int st = 0; st < 4; ++st)
        bfr[st] = *(const bf16x8*)&xlds[st * 16 + lrow][ks * 32 + lgrp * 8];
      #pragma unroll
      for (int ntl = 0; ntl < 2; ++ntl) {
        const int ntile = chunk * 8 + wave * 2 + ntl;
        const bf16x8 afr = ((const bf16x8*)b1swz)[(ntile * 8 + ks) * 64 + lane];
        #pragma unroll
        for (int st = 0; st < 4; ++st)
          hacc[ntl][st] = __builtin_amdgcn_mfma_f32_16x16x32_bf16(
              afr, bfr[st], hacc[ntl][st], 0, 0, 0);
      }
    }
    __syncthreads();   // prev chunk's GEMM2 done reading actlds
    // ---- bias + gelu -> act LDS (bf16)
    #pragma unroll
    for (int ntl = 0; ntl < 2; ++ntl) {
      const int nlocal0 = (wave * 2 + ntl) * 16 + lgrp * 4;
      const int ng0 = chunk * 128 + nlocal0;
      #pragma unroll
      for (int st = 0; st < 4; ++st) {
        float gv[4];
        #pragma unroll
        for (int j = 0; j < 4; ++j) {
          const int ng = ng0 + j;
          const float bias = (ng < 512) ? b1_re[ng] : b1_im[ng - 512];
          gv[j] = gelu_tanh(hacc[ntl][st][j] + bias);
        }
        const int site = st * 16 + lrow;
        act32[site * 68 + (nlocal0 >> 1)] = pack2bf(gv[0], gv[1]);
        act32[site * 68 + (nlocal0 >> 1) + 1] = pack2bf(gv[2], gv[3]);
      }
    }
    __syncthreads();
    // ---- GEMM2 partial accumulate over this chunk's 128 k
    #pragma unroll
    for (int ks2 = 0; ks2 < 4; ++ks2) {
      bf16x8 bfr[4];
      #pragma unroll
      for (int st = 0; st < 4; ++st)
        bfr[st] = *(const bf16x8*)&actlds[st * 16 + lrow][ks2 * 32 + lgrp * 8];
      const int kc = chunk * 4 + ks2;
      #pragma unroll
      for (int rt = 0; rt < 4; ++rt) {
        const int rowtile = wave * 4 + rt;
        const bf16x8 afr = ((const bf16x8*)b2swz)[(rowtile * 32 + kc) * 64 + lane];
        #pragma unroll
        for (int st = 0; st < 4; ++st)
          dacc[rt][st] = __builtin_amdgcn_mfma_f32_16x16x32_bf16(
              afr, bfr[st], dacc[rt][st], 0, 0, 0);
      }
    }
  }

  // ---- epilogue: out = x3 + delta + b2, interleaved [.,2]
  #pragma unroll
  for (int rt = 0; rt < 4; ++rt) {
    #pragma unroll
    for (int j = 0; j < 4; ++j) {
      const int n2 = (wave * 4 + rt) * 16 + lgrp * 4 + j;
      const int d = n2 & 127;
      const int c = n2 >> 7;
      const float bias2 = c ? b2_im[d] : b2_re[d];
      const float* rsrc = c ? x3_im : x3_re;
      #pragma unroll
      for (int st = 0; st < 4; ++st) {
        const size_t idx = (size_t)(bt * D_ + d) * HW_ + hw0 + st * 16 + lrow;
        out[idx * 2 + c] = rsrc[idx] + dacc[rt][st][j] + bias2;
      }
    }
  }
}

// ---------------- host launcher ----------------

extern "C" void kernel_launch(void* const* d_in, const int* in_sizes, int n_in,
                              void* d_out, int out_size, void* d_ws, size_t ws_size,
                              hipStream_t stream) {
  const float* x_re   = (const float*)d_in[0];
  const float* x_im   = (const float*)d_in[1];
  const float* dt     = (const float*)d_in[2];
  const float* ln_s_g = (const float*)d_in[3];
  const float* ln_s_b = (const float*)d_in[4];
  const float* ln_t_g = (const float*)d_in[5];
  const float* ln_t_b = (const float*)d_in[6];
  const float* metric = (const float*)d_in[7];
  const float* conv_w = (const float*)d_in[8];
  const float* conv_b = (const float*)d_in[9];
  const float* nu     = (const float*)d_in[10];
  const float* theta  = (const float*)d_in[11];
  const float* enc_re = (const float*)d_in[12];
  const float* enc_im = (const float*)d_in[13];
  const float* dec_re = (const float*)d_in[14];
  const float* dec_im = (const float*)d_in[15];
  const float* src_g  = (const float*)d_in[16];
  const float* w1_re  = (const float*)d_in[17];
  const float* w1_im  = (const float*)d_in[18];
  const float* b1_re  = (const float*)d_in[19];
  const float* b1_im  = (const float*)d_in[20];
  const float* w2_re  = (const float*)d_in[21];
  const float* w2_im  = (const float*)d_in[22];
  const float* b2_re  = (const float*)d_in[23];
  const float* b2_im  = (const float*)d_in[24];
  float* out = (float*)d_out;
  float* ws = (float*)d_ws;

  // workspace layout
  float* wt   = ws;                          // 589,824 floats; reused for FFN weights after conv
  float* bufA = ws + WT_FLOATS;
  float* u_re = bufA;
  float* u_im = bufA + PLANE_;
  ushort* b1swz = (ushort*)wt;               // 262,144 bf16 (512 KB)
  ushort* b2swz = b1swz + 262144;            // 262,144 bf16

  const size_t needA = (size_t)(WT_FLOATS + 2 * PLANE_ + 2 * PLANE_) * 4;
  const bool planA = ws_size >= needA;
  float *x2_re, *x2_im, *ffn_out;
  if (planA) {
    x2_re = bufA + 2 * (size_t)PLANE_;
    x2_im = x2_re + PLANE_;
    ffn_out = out;
  } else {
    x2_re = out;
    x2_im = out + PLANE_;
    ffn_out = bufA;
  }

  k_wt<<<2304, 256, 0, stream>>>(conv_w, wt);
  k_spatial_ln<<<BT_ * H_, 256, 0, stream>>>(x_re, x_im, ln_s_g, ln_s_b, metric, bufA);
  k_conv<<<BT_ * H_, 256, 0, stream>>>(bufA, wt, conv_b, x_re, x_im, x2_re, x2_im);
  // wt region is dead after k_conv; overwrite with FFN fragment-order weights
  k_prep_b1<<<128, 256, 0, stream>>>(w1_re, w1_im, b1swz);
  k_prep_b2<<<128, 256, 0, stream>>>(w2_re, w2_im, b2swz);
  k_temporal<<<B_ * T_ * H_, 256, 0, stream>>>(x2_re, x2_im, dt, ln_t_g, ln_t_b,
                                               enc_re, enc_im, nu, theta, src_g,
                                               u_re, u_im);
  k_scan<<<ND_ / 256, 256, 0, stream>>>(u_re, u_im, dt, nu, theta);
  k_decode<<<B_ * T_ * H_, 256, 0, stream>>>(u_re, u_im, dec_re, dec_im, x2_re);
  k_ffn_mfma<<<BT_ * H_, 256, 0, stream>>>(x2_re, x2_im, b1swz, b2swz,
                                           b1_re, b1_im, b2_re, b2_im, ffn_out);
  if (!planA) {
    hipMemcpyAsync(d_out, ffn_out, (size_t)2 * PLANE_ * sizeof(float),
                   hipMemcpyDeviceToDevice, stream);
  }
}

// Round 3
// 1410.779 us; speedup vs baseline: 4.3294x; 2.3028x over previous
//
#include <hip/hip_runtime.h>
#include <stdint.h>

#define B_   2
#define T_   16
#define D_   128
#define D2_  256
#define H_   64
#define W_   64
#define HW_  4096
#define BT_  32
#define N_   8192
#define ND_  1048576           // N_*D_
#define PLANE_ 16777216        // B*T*D*H*W  (one of re/im)
#define WT_FLOATS 589824       // 256*256*9

typedef short bf16x8 __attribute__((ext_vector_type(8)));
typedef float f32x4 __attribute__((ext_vector_type(4)));
typedef unsigned int uint;
typedef unsigned short ushort;

// ---------------- device helpers ----------------

__device__ __forceinline__ float softplus_f(float x) {
  return fmaxf(x, 0.0f) + log1pf(expf(-fabsf(x)));
}

__device__ __forceinline__ float gelu_tanh(float x) {
  const float kA = 0.7978845608028654f;  // sqrt(2/pi)
  float x3 = x * x * x;
  return 0.5f * x * (1.0f + tanhf(kA * fmaf(0.044715f, x3, x)));
}

__device__ __forceinline__ ushort f2bf(float f) {
  uint u = __float_as_uint(f);
  uint r = (u + 0x7fffu + ((u >> 16) & 1u)) >> 16;   // RNE
  return (ushort)r;
}

__device__ __forceinline__ uint pack2bf(float a, float b) {
  return (uint)f2bf(a) | ((uint)f2bf(b) << 16);
}

// ---------------- kernel 1: spatial complex LN + metric scale -> xri bf16 [BT][256][H][W] ----------------

__global__ __launch_bounds__(256) void k_spatial_ln(
    const float* __restrict__ x_re, const float* __restrict__ x_im,
    const float* __restrict__ g, const float* __restrict__ bb,
    const float* __restrict__ metric, ushort* __restrict__ xri) {
  __shared__ float vals[256][64];
  __shared__ float red1[4][64];
  __shared__ float red2[4][64];
  __shared__ float mean_s[64];
  __shared__ float rstd_s[64];
  const int blk = blockIdx.x;      // bt*64 + h
  const int bt = blk >> 6;
  const int h = blk & 63;
  const int tid = threadIdx.x;
  const int w = tid & 63, q = tid >> 6;

  float s1 = 0.f, s2 = 0.f;
  #pragma unroll 4
  for (int i = 0; i < 64; ++i) {
    const int c = i * 4 + q;
    const int d = c & 127;
    const float* src = (c < 128) ? x_re : x_im;
    float v = src[((size_t)bt * D_ + d) * HW_ + h * W_ + w];
    vals[c][w] = v;
    s1 += v; s2 += v * v;
  }
  red1[q][w] = s1; red2[q][w] = s2;
  __syncthreads();
  if (tid < 64) {
    float m = red1[0][tid] + red1[1][tid] + red1[2][tid] + red1[3][tid];
    float ss = red2[0][tid] + red2[1][tid] + red2[2][tid] + red2[3][tid];
    m *= (1.f / 256.f);
    float var = ss * (1.f / 256.f) - m * m;
    mean_s[tid] = m;
    rstd_s[tid] = rsqrtf(var + 1e-5f);
  }
  __syncthreads();
  const float m = mean_s[w], rs = rstd_s[w];
  #pragma unroll 4
  for (int i = 0; i < 64; ++i) {
    const int c = i * 4 + q;
    float v = (vals[c][w] - m) * rs * g[c] + bb[c];
    v *= metric[(size_t)c * HW_ + h * W_ + w];
    xri[((size_t)bt * D2_ + c) * HW_ + h * W_ + w] = f2bf(v);
  }
}

// ---------------- conv weight prep: fragment-order bf16 ----------------
// cwswz frag layout: flat = ((kk*8 + ks)*16 + nt)*64 + lane; each frag = 8 bf16.
// co = nt*16 + (lane&15); ci = ks*32 + (lane>>4)*8 + e; conv_w is [co][ci][kh][kw].

__global__ __launch_bounds__(256) void k_prep_conv(
    const float* __restrict__ wg, ushort* __restrict__ cwswz) {
  const int t = blockIdx.x * 256 + threadIdx.x;   // 0..73727
  if (t >= 73728) return;
  const int lane = t & 63;
  const int nt = (t >> 6) & 15;
  const int ks = (t >> 10) & 7;
  const int kk = t >> 13;                         // 0..8
  const int co = nt * 16 + (lane & 15);
  const int ci0 = ks * 32 + (lane >> 4) * 8;
  ushort v[8];
  #pragma unroll
  for (int e = 0; e < 8; ++e)
    v[e] = f2bf(wg[((size_t)co * 256 + ci0 + e) * 9 + kk]);
  uint4 u;
  u.x = (uint)v[0] | ((uint)v[1] << 16);
  u.y = (uint)v[2] | ((uint)v[3] << 16);
  u.z = (uint)v[4] | ((uint)v[5] << 16);
  u.w = (uint)v[6] | ((uint)v[7] << 16);
  ((uint4*)cwswz)[t] = u;
}

// ---------------- kernel 2: 3x3 conv via bf16 MFMA (implicit GEMM) ----------------
// block = one bt, 2 h rows (128 sites). 8 waves: cw=wave&3 (4 co-tiles), sg=wave>>2 (4 site-tiles).
// LDS: input rows h0-1..h0+2, [4][66 w][264 ci] bf16.

__global__ __launch_bounds__(512, 1) void k_conv_mfma(
    const ushort* __restrict__ xri, const ushort* __restrict__ cwswz,
    const float* __restrict__ bias,
    const float* __restrict__ x_re, const float* __restrict__ x_im,
    float* __restrict__ x2_re, float* __restrict__ x2_im) {
  __shared__ ushort xb[4][66][264];   // 139,392 B
  const int tid = threadIdx.x;
  const int wave = tid >> 6, lane = tid & 63;
  const int lrow = lane & 15, lgrp = lane >> 4;
  const int blk = blockIdx.x;         // 1024 = bt*32 + hp
  const int bt = blk >> 5;
  const int h0 = (blk & 31) * 2;

  uint* xb32 = (uint*)&xb[0][0][0];
  // zero halo columns (w-col 0 and 65)
  {
    const int j = tid >> 7;           // 0..3
    const int p = tid & 127;          // ci-pair
    xb32[(j * 66 + 0) * 132 + p] = 0;
    xb32[(j * 66 + 65) * 132 + p] = 0;
  }
  // main staging: LDS[j][1+w][ci] <- xri[bt][ci][h0+j-1][w]
  #pragma unroll
  for (int i = 0; i < 64; ++i) {
    const int idx = i * 8 + wave;     // 0..511
    const int j = idx >> 7;           // row 0..3
    const int p = idx & 127;          // ci-pair
    const int hh = h0 + j - 1;
    uint v = 0;
    if (hh >= 0 && hh < 64) {
      const ushort* src = &xri[((size_t)bt * D2_ + 2 * p) * HW_ + hh * W_ + lane];
      uint lo = src[0];
      uint hi = src[HW_];
      v = lo | (hi << 16);
    }
    xb32[(j * 66 + 1 + lane) * 132 + p] = v;
  }
  __syncthreads();

  const int cw = wave & 3;    // co group: co-tiles cw*4..cw*4+3
  const int sg = wave >> 2;   // output row r = sg (0/1); site-tiles sg*4..sg*4+3
  f32x4 acc[4][4];
  #pragma unroll
  for (int j = 0; j < 4; ++j)
    #pragma unroll
    for (int i = 0; i < 4; ++i) acc[j][i] = (f32x4)0.f;

  for (int kh = 0; kh < 3; ++kh) {
    const ushort* xrow = &xb[sg + kh][0][0];
    for (int kw = 0; kw < 3; ++kw) {
      const int kk = kh * 3 + kw;
      #pragma unroll
      for (int ks = 0; ks < 8; ++ks) {
        bf16x8 bfr[4];
        #pragma unroll
        for (int i = 0; i < 4; ++i)
          bfr[i] = *(const bf16x8*)&xrow[(i * 16 + lrow + kw) * 264 + ks * 32 + lgrp * 8];
        const int fbase = ((kk * 8 + ks) * 16 + cw * 4) * 64 + lane;
        #pragma unroll
        for (int j = 0; j < 4; ++j) {
          const bf16x8 afr = ((const bf16x8*)cwswz)[fbase + j * 64];
          #pragma unroll
          for (int i = 0; i < 4; ++i)
            acc[j][i] = __builtin_amdgcn_mfma_f32_16x16x32_bf16(
                afr, bfr[i], acc[j][i], 0, 0, 0);
        }
      }
    }
  }

  // epilogue: bias + residual, split re/im planar fp32
  #pragma unroll
  for (int j = 0; j < 4; ++j) {
    #pragma unroll
    for (int jj = 0; jj < 4; ++jj) {
      const int co = (cw * 4 + j) * 16 + lgrp * 4 + jj;
      const int d = co & 127;
      const float bv = bias[co];
      const float* rsrc = (co < 128) ? x_re : x_im;
      float* dst = (co < 128) ? x2_re : x2_im;
      const size_t rowoff = ((size_t)bt * D_ + d) * HW_ + (h0 + sg) * W_;
      #pragma unroll
      for (int i = 0; i < 4; ++i) {
        const int w = i * 16 + lrow;
        dst[rowoff + w] = acc[j][i][jj] + bv + rsrc[rowoff + w];
      }
    }
  }
}

// ---------------- kernel 3: temporal complex LN + encode + src + ZOH forcing -> u [T][N][D] ----------------

__global__ __launch_bounds__(256) void k_temporal(
    const float* __restrict__ x2_re, const float* __restrict__ x2_im,
    const float* __restrict__ dt,
    const float* __restrict__ g, const float* __restrict__ bb,
    const float* __restrict__ enc_re, const float* __restrict__ enc_im,
    const float* __restrict__ nu, const float* __restrict__ theta,
    const float* __restrict__ src_gain,
    float* __restrict__ u_re, float* __restrict__ u_im) {
  __shared__ float xr[64][129];
  __shared__ float xi[64][129];
  __shared__ float red1[4][64], red2[4][64];
  __shared__ float mean_s[64], rstd_s[64];
  __shared__ float fre_s[128], fim_s[128], gain_s[128];
  const int blk = blockIdx.x;          // ((b*16)+t)*64 + h
  const int h = blk & 63;
  const int t = (blk >> 6) & 15;
  const int b = blk >> 10;
  const int tid = threadIdx.x;
  const int w = tid & 63, q = tid >> 6;
  const float dtv = dt[b * T_ + t];
  const size_t img = ((size_t)(b * T_ + t)) * D_ * HW_ + h * W_ + w;

  float s1 = 0.f, s2 = 0.f;
  #pragma unroll 4
  for (int i = 0; i < 32; ++i) {
    const int d = i * 4 + q;
    float vr = x2_re[img + (size_t)d * HW_];
    float vi = x2_im[img + (size_t)d * HW_];
    xr[w][d] = vr; xi[w][d] = vi;
    s1 += vr + vi;
    s2 += vr * vr + vi * vi;
  }
  red1[q][w] = s1; red2[q][w] = s2;
  __syncthreads();
  if (tid < 64) {
    float m = red1[0][tid] + red1[1][tid] + red1[2][tid] + red1[3][tid];
    float ss = red2[0][tid] + red2[1][tid] + red2[2][tid] + red2[3][tid];
    m *= (1.f / 256.f);
    float var = ss * (1.f / 256.f) - m * m;
    mean_s[tid] = m; rstd_s[tid] = rsqrtf(var + 1e-5f);
  }
  if (tid < 128) {
    const int d = tid;
    float lr = -softplus_f(nu[d]);
    float li = theta[d];
    float s, c;
    sincosf(li * dtv, &s, &c);
    float er = expf(lr * dtv);
    float dcr = er * c, dci = er * s;
    float den = lr * lr + li * li;
    float nr = dcr - 1.f, ni = dci;
    fre_s[d] = (nr * lr + ni * li) / den;
    fim_s[d] = (ni * lr - nr * li) / den;
    gain_s[d] = src_gain[d];
  }
  __syncthreads();
  {
    const float m = mean_s[w], rs = rstd_s[w];
    #pragma unroll 4
    for (int i = 0; i < 32; ++i) {
      const int d = i * 4 + q;
      xr[w][d] = (xr[w][d] - m) * rs * g[d] + bb[d];
      xi[w][d] = (xi[w][d] - m) * rs * g[128 + d] + bb[128 + d];
    }
  }
  __syncthreads();

  const int tx = tid & 15, ty = tid >> 4;
  const int w0 = ty * 4, j0 = tx * 8;
  float accr[4][8], acci[4][8];
  #pragma unroll
  for (int i = 0; i < 4; ++i)
    #pragma unroll
    for (int j = 0; j < 8; ++j) { accr[i][j] = 0.f; acci[i][j] = 0.f; }

  for (int k = 0; k < 128; ++k) {
    float ar[4], ai[4];
    #pragma unroll
    for (int i = 0; i < 4; ++i) { ar[i] = xr[w0 + i][k]; ai[i] = xi[w0 + i][k]; }
    float4 er0 = *(const float4*)&enc_re[(size_t)k * D_ + j0];
    float4 er1 = *(const float4*)&enc_re[(size_t)k * D_ + j0 + 4];
    float4 ei0 = *(const float4*)&enc_im[(size_t)k * D_ + j0];
    float4 ei1 = *(const float4*)&enc_im[(size_t)k * D_ + j0 + 4];
    float br[8] = {er0.x, er0.y, er0.z, er0.w, er1.x, er1.y, er1.z, er1.w};
    float bi[8] = {ei0.x, ei0.y, ei0.z, ei0.w, ei1.x, ei1.y, ei1.z, ei1.w};
    #pragma unroll
    for (int i = 0; i < 4; ++i)
      #pragma unroll
      for (int j = 0; j < 8; ++j) {
        accr[i][j] += ar[i] * br[j] - ai[i] * bi[j];
        acci[i][j] += ar[i] * bi[j] + ai[i] * br[j];
      }
  }

  const int nbase = (b * 64 + h) * 64;
  #pragma unroll
  for (int i = 0; i < 4; ++i) {
    const int ww = w0 + i;
    const int nidx = nbase + ww;
    const size_t orow = (size_t)t * ND_ + (size_t)nidx * D_;
    #pragma unroll
    for (int j = 0; j < 8; ++j) {
      const int dd = j0 + j;
      float xer = accr[i][j], xei = acci[i][j];
      float sr = tanhf(xer) * gain_s[dd];
      float si = tanhf(xei) * gain_s[dd];
      float vr = xer + sr, vi = xei + si;
      float ur = vr * fre_s[dd] - vi * fim_s[dd];
      float ui = vr * fim_s[dd] + vi * fre_s[dd];
      u_re[orow + dd] = ur;
      u_im[orow + dd] = ui;
    }
  }
}

// ---------------- kernel 4: sequential scan over T (in place) ----------------

__global__ __launch_bounds__(256) void k_scan(
    float* __restrict__ u_re, float* __restrict__ u_im,
    const float* __restrict__ dt,
    const float* __restrict__ nu, const float* __restrict__ theta) {
  const int idx = blockIdx.x * 256 + threadIdx.x;   // n*128 + d
  const int d = idx & 127;
  const int n = idx >> 7;
  const int b = n >> 12;
  const float lr = -softplus_f(nu[d]);
  const float li = theta[d];
  float hr = 0.f, hi = 0.f;
  for (int t = 0; t < 16; ++t) {
    const float dtv = dt[b * 16 + t];
    float s, c;
    sincosf(li * dtv, &s, &c);
    const float er = expf(lr * dtv);
    const float ar = er * c, ai = er * s;
    const size_t off = (size_t)t * ND_ + idx;
    const float ur = u_re[off], ui = u_im[off];
    const float nr = ar * hr - ai * hi + ur;
    const float ni = ar * hi + ai * hr + ui;
    hr = nr; hi = ni;
    u_re[off] = hr; u_im[off] = hi;
  }
}

// ---------------- kernel 5: decode (real part) + residual add (in place on x2_re) ----------------

__global__ __launch_bounds__(256) void k_decode(
    const float* __restrict__ h_re, const float* __restrict__ h_im,
    const float* __restrict__ dec_re, const float* __restrict__ dec_im,
    float* __restrict__ x2_re) {
  __shared__ float hr[64][129];
  __shared__ float hi[64][129];
  const int blk = blockIdx.x;          // ((b*16)+t)*64 + h
  const int hh = blk & 63;
  const int t = (blk >> 6) & 15;
  const int b = blk >> 10;
  const int tid = threadIdx.x;
  const size_t rowbase = (size_t)t * ND_ + (size_t)((b * 64 + hh) * 64) * D_;
  #pragma unroll
  for (int it = 0; it < 32; ++it) {
    int flat = it * 256 + tid;
    int d = flat & 127, w = flat >> 7;
    hr[w][d] = h_re[rowbase + (size_t)w * D_ + d];
    hi[w][d] = h_im[rowbase + (size_t)w * D_ + d];
  }
  __syncthreads();
  const int tx = tid & 15, ty = tid >> 4;
  const int w0 = ty * 4, j0 = tx * 8;
  float acc[4][8];
  #pragma unroll
  for (int i = 0; i < 4; ++i)
    #pragma unroll
    for (int j = 0; j < 8; ++j) acc[i][j] = 0.f;

  for (int k = 0; k < 128; ++k) {
    float ar[4], ai[4];
    #pragma unroll
    for (int i = 0; i < 4; ++i) { ar[i] = hr[w0 + i][k]; ai[i] = hi[w0 + i][k]; }
    float4 dr0 = *(const float4*)&dec_re[(size_t)k * D_ + j0];
    float4 dr1 = *(const float4*)&dec_re[(size_t)k * D_ + j0 + 4];
    float4 di0 = *(const float4*)&dec_im[(size_t)k * D_ + j0];
    float4 di1 = *(const float4*)&dec_im[(size_t)k * D_ + j0 + 4];
    float br[8] = {dr0.x, dr0.y, dr0.z, dr0.w, dr1.x, dr1.y, dr1.z, dr1.w};
    float bi[8] = {di0.x, di0.y, di0.z, di0.w, di1.x, di1.y, di1.z, di1.w};
    #pragma unroll
    for (int i = 0; i < 4; ++i)
      #pragma unroll
      for (int j = 0; j < 8; ++j)
        acc[i][j] += ar[i] * br[j] - ai[i] * bi[j];
  }
  #pragma unroll
  for (int j = 0; j < 8; ++j) {
    const int dd = j0 + j;
    const size_t ob = ((size_t)(b * 16 + t) * D_ + dd) * HW_ + hh * W_;
    #pragma unroll
    for (int i = 0; i < 4; ++i) {
      const int ww = w0 + i;
      x2_re[ob + ww] += acc[i][j];
    }
  }
}

// ---------------- FFN weight prep: pre-swizzled bf16 fragment order ----------------

__global__ __launch_bounds__(256) void k_prep_b1(
    const float* __restrict__ w1_re, const float* __restrict__ w1_im,
    ushort* __restrict__ b1swz) {
  const int t = blockIdx.x * 256 + threadIdx.x;   // 0..32767
  const int lane = t & 63;
  const int ks = (t >> 6) & 7;
  const int ntile = t >> 9;
  const int n = ntile * 16 + (lane & 15);
  const int k0 = ks * 32 + (lane >> 4) * 8;
  ushort v[8];
  #pragma unroll
  for (int e = 0; e < 8; ++e) {
    const int k = k0 + e;
    float val;
    if (k < 128) {
      val = (n < 512) ? w1_re[k * 512 + n] : w1_im[k * 512 + (n - 512)];
    } else {
      const int kk = k - 128;
      val = (n < 512) ? -w1_im[kk * 512 + n] : w1_re[kk * 512 + (n - 512)];
    }
    v[e] = f2bf(val);
  }
  uint4 u;
  u.x = (uint)v[0] | ((uint)v[1] << 16);
  u.y = (uint)v[2] | ((uint)v[3] << 16);
  u.z = (uint)v[4] | ((uint)v[5] << 16);
  u.w = (uint)v[6] | ((uint)v[7] << 16);
  ((uint4*)b1swz)[t] = u;
}

__global__ __launch_bounds__(256) void k_prep_b2(
    const float* __restrict__ w2_re, const float* __restrict__ w2_im,
    ushort* __restrict__ b2swz) {
  const int t = blockIdx.x * 256 + threadIdx.x;   // 0..32767
  const int lane = t & 63;
  const int kc = (t >> 6) & 31;
  const int rowtile = t >> 11;
  const int n2 = rowtile * 16 + (lane & 15);
  const int k0 = kc * 32 + (lane >> 4) * 8;
  ushort v[8];
  #pragma unroll
  for (int e = 0; e < 8; ++e) {
    const int k = k0 + e;
    float val;
    if (k < 512) {
      val = (n2 < 128) ? w2_re[k * 128 + n2] : w2_im[k * 128 + (n2 - 128)];
    } else {
      const int kk = k - 512;
      val = (n2 < 128) ? -w2_im[kk * 128 + n2] : w2_re[kk * 128 + (n2 - 128)];
    }
    v[e] = f2bf(val);
  }
  uint4 u;
  u.x = (uint)v[0] | ((uint)v[1] << 16);
  u.y = (uint)v[2] | ((uint)v[3] << 16);
  u.z = (uint)v[4] | ((uint)v[5] << 16);
  u.w = (uint)v[6] | ((uint)v[7] << 16);
  ((uint4*)b2swz)[t] = u;
}

// ---------------- kernel 6: complex FFN via bf16 MFMA ----------------

__global__ __launch_bounds__(256, 2) void k_ffn_mfma(
    const float* __restrict__ x3_re, const float* __restrict__ x3_im,
    const ushort* __restrict__ b1swz, const ushort* __restrict__ b2swz,
    const float* __restrict__ b1_re, const float* __restrict__ b1_im,
    const float* __restrict__ b2_re, const float* __restrict__ b2_im,
    float* __restrict__ out) {
  __shared__ ushort xlds[64][264];
  __shared__ ushort actlds[64][136];
  const int tid = threadIdx.x;
  const int wave = tid >> 6, lane = tid & 63;
  const int lrow = lane & 15, lgrp = lane >> 4;
  const int blk = blockIdx.x;        // 2048 = bt*64 + h
  const int bt = blk >> 6;
  const int hw0 = (blk & 63) * 64;
  const size_t base = (size_t)bt * D_ * HW_ + hw0;

  uint* xlds32 = (uint*)&xlds[0][0];
  #pragma unroll
  for (int i = 0; i < 16; ++i) {
    const int p = i * 4 + wave;
    const float r0 = x3_re[base + (size_t)(2 * p) * HW_ + lane];
    const float r1 = x3_re[base + (size_t)(2 * p + 1) * HW_ + lane];
    const float i0 = x3_im[base + (size_t)(2 * p) * HW_ + lane];
    const float i1 = x3_im[base + (size_t)(2 * p + 1) * HW_ + lane];
    xlds32[lane * 132 + p] = pack2bf(r0, r1);
    xlds32[lane * 132 + 64 + p] = pack2bf(i0, i1);
  }
  __syncthreads();

  f32x4 dacc[4][4];
  #pragma unroll
  for (int rt = 0; rt < 4; ++rt)
    #pragma unroll
    for (int st = 0; st < 4; ++st) dacc[rt][st] = (f32x4)0.f;

  uint* act32 = (uint*)&actlds[0][0];

  for (int chunk = 0; chunk < 8; ++chunk) {
    f32x4 hacc[2][4];
    #pragma unroll
    for (int ntl = 0; ntl < 2; ++ntl)
      #pragma unroll
      for (int st = 0; st < 4; ++st) hacc[ntl][st] = (f32x4)0.f;

    #pragma unroll
    for (int ks = 0; ks < 8; ++ks) {
      bf16x8 bfr[4];
      #pragma unroll
      for (int st = 0; st < 4; ++st)
        bfr[st] = *(const bf16x8*)&xlds[st * 16 + lrow][ks * 32 + lgrp * 8];
      #pragma unroll
      for (int ntl = 0; ntl < 2; ++ntl) {
        const int ntile = chunk * 8 + wave * 2 + ntl;
        const bf16x8 afr = ((const bf16x8*)b1swz)[(ntile * 8 + ks) * 64 + lane];
        #pragma unroll
        for (int st = 0; st < 4; ++st)
          hacc[ntl][st] = __builtin_amdgcn_mfma_f32_16x16x32_bf16(
              afr, bfr[st], hacc[ntl][st], 0, 0, 0);
      }
    }
    __syncthreads();
    #pragma unroll
    for (int ntl = 0; ntl < 2; ++ntl) {
      const int nlocal0 = (wave * 2 + ntl) * 16 + lgrp * 4;
      const int ng0 = chunk * 128 + nlocal0;
      #pragma unroll
      for (int st = 0; st < 4; ++st) {
        float gv[4];
        #pragma unroll
        for (int j = 0; j < 4; ++j) {
          const int ng = ng0 + j;
          const float bias = (ng < 512) ? b1_re[ng] : b1_im[ng - 512];
          gv[j] = gelu_tanh(hacc[ntl][st][j] + bias);
        }
        const int site = st * 16 + lrow;
        act32[site * 68 + (nlocal0 >> 1)] = pack2bf(gv[0], gv[1]);
        act32[site * 68 + (nlocal0 >> 1) + 1] = pack2bf(gv[2], gv[3]);
      }
    }
    __syncthreads();
    #pragma unroll
    for (int ks2 = 0; ks2 < 4; ++ks2) {
      bf16x8 bfr[4];
      #pragma unroll
      for (int st = 0; st < 4; ++st)
        bfr[st] = *(const bf16x8*)&actlds[st * 16 + lrow][ks2 * 32 + lgrp * 8];
      const int kc = chunk * 4 + ks2;
      #pragma unroll
      for (int rt = 0; rt < 4; ++rt) {
        const int rowtile = wave * 4 + rt;
        const bf16x8 afr = ((const bf16x8*)b2swz)[(rowtile * 32 + kc) * 64 + lane];
        #pragma unroll
        for (int st = 0; st < 4; ++st)
          dacc[rt][st] = __builtin_amdgcn_mfma_f32_16x16x32_bf16(
              afr, bfr[st], dacc[rt][st], 0, 0, 0);
      }
    }
  }

  #pragma unroll
  for (int rt = 0; rt < 4; ++rt) {
    #pragma unroll
    for (int j = 0; j < 4; ++j) {
      const int n2 = (wave * 4 + rt) * 16 + lgrp * 4 + j;
      const int d = n2 & 127;
      const int c = n2 >> 7;
      const float bias2 = c ? b2_im[d] : b2_re[d];
      const float* rsrc = c ? x3_im : x3_re;
      #pragma unroll
      for (int st = 0; st < 4; ++st) {
        const size_t idx = (size_t)(bt * D_ + d) * HW_ + hw0 + st * 16 + lrow;
        out[idx * 2 + c] = rsrc[idx] + dacc[rt][st][j] + bias2;
      }
    }
  }
}

// ---------------- host launcher ----------------

extern "C" void kernel_launch(void* const* d_in, const int* in_sizes, int n_in,
                              void* d_out, int out_size, void* d_ws, size_t ws_size,
                              hipStream_t stream) {
  const float* x_re   = (const float*)d_in[0];
  const float* x_im   = (const float*)d_in[1];
  const float* dt     = (const float*)d_in[2];
  const float* ln_s_g = (const float*)d_in[3];
  const float* ln_s_b = (const float*)d_in[4];
  const float* ln_t_g = (const float*)d_in[5];
  const float* ln_t_b = (const float*)d_in[6];
  const float* metric = (const float*)d_in[7];
  const float* conv_w = (const float*)d_in[8];
  const float* conv_b = (const float*)d_in[9];
  const float* nu     = (const float*)d_in[10];
  const float* theta  = (const float*)d_in[11];
  const float* enc_re = (const float*)d_in[12];
  const float* enc_im = (const float*)d_in[13];
  const float* dec_re = (const float*)d_in[14];
  const float* dec_im = (const float*)d_in[15];
  const float* src_g  = (const float*)d_in[16];
  const float* w1_re  = (const float*)d_in[17];
  const float* w1_im  = (const float*)d_in[18];
  const float* b1_re  = (const float*)d_in[19];
  const float* b1_im  = (const float*)d_in[20];
  const float* w2_re  = (const float*)d_in[21];
  const float* w2_im  = (const float*)d_in[22];
  const float* b2_re  = (const float*)d_in[23];
  const float* b2_im  = (const float*)d_in[24];
  float* out = (float*)d_out;
  float* ws = (float*)d_ws;

  // workspace layout
  float* wt   = ws;                          // weight-prep region (2.3 MB)
  float* bufA = ws + WT_FLOATS;
  float* u_re = bufA;
  float* u_im = bufA + PLANE_;
  ushort* cwswz = (ushort*)wt;               // 589,824 bf16 (conv frags)
  ushort* b1swz = (ushort*)wt;               // FFN frags (overwrite cwswz after conv)
  ushort* b2swz = b1swz + 262144;
  ushort* xri_bf = (ushort*)bufA;            // 33.5 MB bf16 LN output (dead after conv)

  const size_t needA = (size_t)(WT_FLOATS + 2 * PLANE_ + 2 * PLANE_) * 4;
  const bool planA = ws_size >= needA;
  float *x2_re, *x2_im, *ffn_out;
  if (planA) {
    x2_re = bufA + 2 * (size_t)PLANE_;
    x2_im = x2_re + PLANE_;
    ffn_out = out;
  } else {
    x2_re = out;
    x2_im = out + PLANE_;
    ffn_out = bufA;
  }

  k_prep_conv<<<288, 256, 0, stream>>>(conv_w, cwswz);
  k_spatial_ln<<<BT_ * H_, 256, 0, stream>>>(x_re, x_im, ln_s_g, ln_s_b, metric, xri_bf);
  k_conv_mfma<<<BT_ * 32, 512, 0, stream>>>(xri_bf, cwswz, conv_b, x_re, x_im,
                                            x2_re, x2_im);
  // cwswz dead after conv; overwrite with FFN fragment-order weights
  k_prep_b1<<<128, 256, 0, stream>>>(w1_re, w1_im, b1swz);
  k_prep_b2<<<128, 256, 0, stream>>>(w2_re, w2_im, b2swz);
  k_temporal<<<B_ * T_ * H_, 256, 0, stream>>>(x2_re, x2_im, dt, ln_t_g, ln_t_b,
                                               enc_re, enc_im, nu, theta, src_g,
                                               u_re, u_im);
  k_scan<<<ND_ / 256, 256, 0, stream>>>(u_re, u_im, dt, nu, theta);
  k_decode<<<B_ * T_ * H_, 256, 0, stream>>>(u_re, u_im, dec_re, dec_im, x2_re);
  k_ffn_mfma<<<BT_ * H_, 256, 0, stream>>>(x2_re, x2_im, b1swz, b2swz,
                                           b1_re, b1_im, b2_re, b2_im, ffn_out);
  if (!planA) {
    hipMemcpyAsync(d_out, ffn_out, (size_t)2 * PLANE_ * sizeof(float),
                   hipMemcpyDeviceToDevice, stream);
  }
}

// Round 4
// 946.810 us; speedup vs baseline: 6.4510x; 1.4900x over previous
//
#include <hip/hip_runtime.h>
#include <stdint.h>

#define B_   2
#define T_   16
#define D_   128
#define D2_  256
#define H_   64
#define W_   64
#define HW_  4096
#define BT_  32
#define N_   8192
#define ND_  1048576           // N_*D_
#define PLANE_ 16777216        // B*T*D*H*W  (one of re/im)
#define WT_FLOATS 589824       // 256*256*9

typedef short bf16x8 __attribute__((ext_vector_type(8)));
typedef float f32x4 __attribute__((ext_vector_type(4)));
typedef unsigned int uint;
typedef unsigned short ushort;

// ---------------- device helpers ----------------

__device__ __forceinline__ float softplus_f(float x) {
  return fmaxf(x, 0.0f) + log1pf(expf(-fabsf(x)));
}

__device__ __forceinline__ float gelu_tanh(float x) {
  const float kA = 0.7978845608028654f;  // sqrt(2/pi)
  float x3 = x * x * x;
  return 0.5f * x * (1.0f + tanhf(kA * fmaf(0.044715f, x3, x)));
}

__device__ __forceinline__ ushort f2bf(float f) {
  uint u = __float_as_uint(f);
  uint r = (u + 0x7fffu + ((u >> 16) & 1u)) >> 16;   // RNE
  return (ushort)r;
}

__device__ __forceinline__ uint pack2bf(float a, float b) {
  return (uint)f2bf(a) | ((uint)f2bf(b) << 16);
}

// ---------------- kernel 1: spatial complex LN + metric scale -> xri bf16 [BT][256][H][W] ----------------

__global__ __launch_bounds__(256) void k_spatial_ln(
    const float* __restrict__ x_re, const float* __restrict__ x_im,
    const float* __restrict__ g, const float* __restrict__ bb,
    const float* __restrict__ metric, ushort* __restrict__ xri) {
  __shared__ float vals[256][64];
  __shared__ float red1[4][64];
  __shared__ float red2[4][64];
  __shared__ float mean_s[64];
  __shared__ float rstd_s[64];
  const int blk = blockIdx.x;      // bt*64 + h
  const int bt = blk >> 6;
  const int h = blk & 63;
  const int tid = threadIdx.x;
  const int w = tid & 63, q = tid >> 6;

  float s1 = 0.f, s2 = 0.f;
  #pragma unroll 4
  for (int i = 0; i < 64; ++i) {
    const int c = i * 4 + q;
    const int d = c & 127;
    const float* src = (c < 128) ? x_re : x_im;
    float v = src[((size_t)bt * D_ + d) * HW_ + h * W_ + w];
    vals[c][w] = v;
    s1 += v; s2 += v * v;
  }
  red1[q][w] = s1; red2[q][w] = s2;
  __syncthreads();
  if (tid < 64) {
    float m = red1[0][tid] + red1[1][tid] + red1[2][tid] + red1[3][tid];
    float ss = red2[0][tid] + red2[1][tid] + red2[2][tid] + red2[3][tid];
    m *= (1.f / 256.f);
    float var = ss * (1.f / 256.f) - m * m;
    mean_s[tid] = m;
    rstd_s[tid] = rsqrtf(var + 1e-5f);
  }
  __syncthreads();
  const float m = mean_s[w], rs = rstd_s[w];
  #pragma unroll 4
  for (int i = 0; i < 64; ++i) {
    const int c = i * 4 + q;
    float v = (vals[c][w] - m) * rs * g[c] + bb[c];
    v *= metric[(size_t)c * HW_ + h * W_ + w];
    xri[((size_t)bt * D2_ + c) * HW_ + h * W_ + w] = f2bf(v);
  }
}

// ---------------- conv weight prep: fragment-order bf16 ----------------

__global__ __launch_bounds__(256) void k_prep_conv(
    const float* __restrict__ wg, ushort* __restrict__ cwswz) {
  const int t = blockIdx.x * 256 + threadIdx.x;   // 0..73727
  if (t >= 73728) return;
  const int lane = t & 63;
  const int nt = (t >> 6) & 15;
  const int ks = (t >> 10) & 7;
  const int kk = t >> 13;                         // 0..8
  const int co = nt * 16 + (lane & 15);
  const int ci0 = ks * 32 + (lane >> 4) * 8;
  ushort v[8];
  #pragma unroll
  for (int e = 0; e < 8; ++e)
    v[e] = f2bf(wg[((size_t)co * 256 + ci0 + e) * 9 + kk]);
  uint4 u;
  u.x = (uint)v[0] | ((uint)v[1] << 16);
  u.y = (uint)v[2] | ((uint)v[3] << 16);
  u.z = (uint)v[4] | ((uint)v[5] << 16);
  u.w = (uint)v[6] | ((uint)v[7] << 16);
  ((uint4*)cwswz)[t] = u;
}

// ---------------- kernel 2: 3x3 conv via bf16 MFMA (implicit GEMM) ----------------

__global__ __launch_bounds__(512, 1) void k_conv_mfma(
    const ushort* __restrict__ xri, const ushort* __restrict__ cwswz,
    const float* __restrict__ bias,
    const float* __restrict__ x_re, const float* __restrict__ x_im,
    float* __restrict__ x2_re, float* __restrict__ x2_im) {
  __shared__ ushort xb[4][66][264];   // 139,392 B
  const int tid = threadIdx.x;
  const int wave = tid >> 6, lane = tid & 63;
  const int lrow = lane & 15, lgrp = lane >> 4;
  const int blk = blockIdx.x;         // 1024 = bt*32 + hp
  const int bt = blk >> 5;
  const int h0 = (blk & 31) * 2;

  uint* xb32 = (uint*)&xb[0][0][0];
  {
    const int j = tid >> 7;           // 0..3
    const int p = tid & 127;          // ci-pair
    xb32[(j * 66 + 0) * 132 + p] = 0;
    xb32[(j * 66 + 65) * 132 + p] = 0;
  }
  #pragma unroll
  for (int i = 0; i < 64; ++i) {
    const int idx = i * 8 + wave;     // 0..511
    const int j = idx >> 7;           // row 0..3
    const int p = idx & 127;          // ci-pair
    const int hh = h0 + j - 1;
    uint v = 0;
    if (hh >= 0 && hh < 64) {
      const ushort* src = &xri[((size_t)bt * D2_ + 2 * p) * HW_ + hh * W_ + lane];
      uint lo = src[0];
      uint hi = src[HW_];
      v = lo | (hi << 16);
    }
    xb32[(j * 66 + 1 + lane) * 132 + p] = v;
  }
  __syncthreads();

  const int cw = wave & 3;
  const int sg = wave >> 2;
  f32x4 acc[4][4];
  #pragma unroll
  for (int j = 0; j < 4; ++j)
    #pragma unroll
    for (int i = 0; i < 4; ++i) acc[j][i] = (f32x4)0.f;

  for (int kh = 0; kh < 3; ++kh) {
    const ushort* xrow = &xb[sg + kh][0][0];
    for (int kw = 0; kw < 3; ++kw) {
      const int kk = kh * 3 + kw;
      #pragma unroll
      for (int ks = 0; ks < 8; ++ks) {
        bf16x8 bfr[4];
        #pragma unroll
        for (int i = 0; i < 4; ++i)
          bfr[i] = *(const bf16x8*)&xrow[(i * 16 + lrow + kw) * 264 + ks * 32 + lgrp * 8];
        const int fbase = ((kk * 8 + ks) * 16 + cw * 4) * 64 + lane;
        #pragma unroll
        for (int j = 0; j < 4; ++j) {
          const bf16x8 afr = ((const bf16x8*)cwswz)[fbase + j * 64];
          #pragma unroll
          for (int i = 0; i < 4; ++i)
            acc[j][i] = __builtin_amdgcn_mfma_f32_16x16x32_bf16(
                afr, bfr[i], acc[j][i], 0, 0, 0);
        }
      }
    }
  }

  #pragma unroll
  for (int j = 0; j < 4; ++j) {
    #pragma unroll
    for (int jj = 0; jj < 4; ++jj) {
      const int co = (cw * 4 + j) * 16 + lgrp * 4 + jj;
      const int d = co & 127;
      const float bv = bias[co];
      const float* rsrc = (co < 128) ? x_re : x_im;
      float* dst = (co < 128) ? x2_re : x2_im;
      const size_t rowoff = ((size_t)bt * D_ + d) * HW_ + (h0 + sg) * W_;
      #pragma unroll
      for (int i = 0; i < 4; ++i) {
        const int w = i * 16 + lrow;
        dst[rowoff + w] = acc[j][i][jj] + bv + rsrc[rowoff + w];
      }
    }
  }
}

// ---------------- temporal-encode weight prep ----------------
// encP (256x256 packed complex, rows g-scaled) in fragment order.
// frag t: ntile=t>>9 (0..15), ks=(t>>6)&7, lane=t&63.

__global__ __launch_bounds__(256) void k_prep_enc(
    const float* __restrict__ enc_re, const float* __restrict__ enc_im,
    const float* __restrict__ g, ushort* __restrict__ encswz) {
  const int t = blockIdx.x * 256 + threadIdx.x;   // 0..8191
  const int lane = t & 63;
  const int ks = (t >> 6) & 7;
  const int ntile = t >> 9;
  const int n = ntile * 16 + (lane & 15);
  const int k0 = ks * 32 + (lane >> 4) * 8;
  ushort v[8];
  #pragma unroll
  for (int e = 0; e < 8; ++e) {
    const int k = k0 + e;
    float val;
    if (k < 128) {
      val = (n < 128) ? enc_re[k * 128 + n] : enc_im[k * 128 + (n - 128)];
    } else {
      const int kk = k - 128;
      val = (n < 128) ? -enc_im[kk * 128 + n] : enc_re[kk * 128 + (n - 128)];
    }
    v[e] = f2bf(val * g[k]);
  }
  uint4 u;
  u.x = (uint)v[0] | ((uint)v[1] << 16);
  u.y = (uint)v[2] | ((uint)v[3] << 16);
  u.z = (uint)v[4] | ((uint)v[5] << 16);
  u.w = (uint)v[6] | ((uint)v[7] << 16);
  ((uint4*)encswz)[t] = u;
}

// evec[n] = sum_k g[k]*encP[k][n]; cvec[n] = sum_k b[k]*encP[k][n]  (fp32, unscaled encP)

__global__ __launch_bounds__(256) void k_prep_encvec(
    const float* __restrict__ enc_re, const float* __restrict__ enc_im,
    const float* __restrict__ g, const float* __restrict__ bb,
    float* __restrict__ evec, float* __restrict__ cvec) {
  const int n = threadIdx.x;   // one block of 256
  float se = 0.f, sc = 0.f;
  for (int k = 0; k < 256; ++k) {
    float ep;
    if (k < 128) {
      ep = (n < 128) ? enc_re[k * 128 + n] : enc_im[k * 128 + (n - 128)];
    } else {
      const int kk = k - 128;
      ep = (n < 128) ? -enc_im[kk * 128 + n] : enc_re[kk * 128 + (n - 128)];
    }
    se = fmaf(g[k], ep, se);
    sc = fmaf(bb[k], ep, sc);
  }
  evec[n] = se;
  cvec[n] = sc;
}

// decP (256x128, real-part decode) in fragment order. frag t: ntile=t>>9 (0..7), ks=(t>>6)&7.

__global__ __launch_bounds__(256) void k_prep_dec(
    const float* __restrict__ dec_re, const float* __restrict__ dec_im,
    ushort* __restrict__ decswz) {
  const int t = blockIdx.x * 256 + threadIdx.x;   // 0..4095
  const int lane = t & 63;
  const int ks = (t >> 6) & 7;
  const int ntile = t >> 9;
  const int n = ntile * 16 + (lane & 15);
  const int k0 = ks * 32 + (lane >> 4) * 8;
  ushort v[8];
  #pragma unroll
  for (int e = 0; e < 8; ++e) {
    const int k = k0 + e;
    float val = (k < 128) ? dec_re[k * 128 + n] : -dec_im[(k - 128) * 128 + n];
    v[e] = f2bf(val);
  }
  uint4 u;
  u.x = (uint)v[0] | ((uint)v[1] << 16);
  u.y = (uint)v[2] | ((uint)v[3] << 16);
  u.z = (uint)v[4] | ((uint)v[5] << 16);
  u.w = (uint)v[6] | ((uint)v[7] << 16);
  ((uint4*)decswz)[t] = u;
}

// ---------------- kernel 3: temporal LN (folded) + encode MFMA + src + ZOH -> u [T][D][N] ----------------
// block = (b,t,h): 64 sites. LN folded into GEMM: xe = rs*G - rs*m*evec + cvec.
// wave w owns n-tiles {2w,2w+1,2w+8,2w+9} so (re,im) pairs are thread-local.

__global__ __launch_bounds__(256, 2) void k_temporal_mfma(
    const float* __restrict__ x2_re, const float* __restrict__ x2_im,
    const float* __restrict__ dt,
    const ushort* __restrict__ encswz,
    const float* __restrict__ evec, const float* __restrict__ cvec,
    const float* __restrict__ nu, const float* __restrict__ theta,
    const float* __restrict__ src_gain,
    float* __restrict__ u_re, float* __restrict__ u_im) {
  __shared__ ushort xlds[64][264];
  __shared__ float red1[4][64], red2[4][64];
  __shared__ float mean_s[64], rstd_s[64];
  __shared__ float fre_s[128], fim_s[128], gain_s[128];
  const int tid = threadIdx.x;
  const int wave = tid >> 6, lane = tid & 63;
  const int lrow = lane & 15, lgrp = lane >> 4;
  const int blk = blockIdx.x;          // ((b*16)+t)*64 + h
  const int h = blk & 63;
  const int t = (blk >> 6) & 15;
  const int b = blk >> 10;
  const int bt = b * T_ + t;
  const float dtv = dt[b * T_ + t];
  const size_t base = (size_t)bt * D_ * HW_ + h * W_;

  // stage RAW x2 -> bf16 LDS (transposed) + LN sums
  uint* xlds32 = (uint*)&xlds[0][0];
  float s1 = 0.f, s2 = 0.f;
  #pragma unroll
  for (int i = 0; i < 16; ++i) {
    const int p = i * 4 + wave;        // d-pair 0..63
    const float r0 = x2_re[base + (size_t)(2 * p) * HW_ + lane];
    const float r1 = x2_re[base + (size_t)(2 * p + 1) * HW_ + lane];
    const float i0 = x2_im[base + (size_t)(2 * p) * HW_ + lane];
    const float i1 = x2_im[base + (size_t)(2 * p + 1) * HW_ + lane];
    xlds32[lane * 132 + p] = pack2bf(r0, r1);
    xlds32[lane * 132 + 64 + p] = pack2bf(i0, i1);
    s1 += r0 + r1 + i0 + i1;
    s2 += r0 * r0 + r1 * r1 + i0 * i0 + i1 * i1;
  }
  red1[wave][lane] = s1;
  red2[wave][lane] = s2;
  __syncthreads();
  if (tid < 64) {
    float m = red1[0][tid] + red1[1][tid] + red1[2][tid] + red1[3][tid];
    float ss = red2[0][tid] + red2[1][tid] + red2[2][tid] + red2[3][tid];
    m *= (1.f / 256.f);
    float var = ss * (1.f / 256.f) - m * m;
    mean_s[tid] = m;
    rstd_s[tid] = rsqrtf(var + 1e-5f);
  }
  if (tid < 128) {
    const int d = tid;
    float lr = -softplus_f(nu[d]);
    float li = theta[d];
    float s, c;
    sincosf(li * dtv, &s, &c);
    float er = expf(lr * dtv);
    float dcr = er * c, dci = er * s;
    float den = lr * lr + li * li;
    float nr = dcr - 1.f, ni = dci;
    fre_s[d] = (nr * lr + ni * li) / den;
    fim_s[d] = (ni * lr - nr * li) / den;
    gain_s[d] = src_gain[d];
  }
  __syncthreads();

  // MFMA: 4 ntiles/wave x 4 site-tiles x 8 k-steps
  f32x4 acc[4][4];
  #pragma unroll
  for (int ntl = 0; ntl < 4; ++ntl)
    #pragma unroll
    for (int st = 0; st < 4; ++st) acc[ntl][st] = (f32x4)0.f;

  const int ntb[4] = {wave * 2, wave * 2 + 1, wave * 2 + 8, wave * 2 + 9};
  #pragma unroll
  for (int ks = 0; ks < 8; ++ks) {
    bf16x8 bfr[4];
    #pragma unroll
    for (int st = 0; st < 4; ++st)
      bfr[st] = *(const bf16x8*)&xlds[st * 16 + lrow][ks * 32 + lgrp * 8];
    #pragma unroll
    for (int ntl = 0; ntl < 4; ++ntl) {
      const bf16x8 afr = ((const bf16x8*)encswz)[(ntb[ntl] * 8 + ks) * 64 + lane];
      #pragma unroll
      for (int st = 0; st < 4; ++st)
        acc[ntl][st] = __builtin_amdgcn_mfma_f32_16x16x32_bf16(
            afr, bfr[st], acc[ntl][st], 0, 0, 0);
    }
  }

  // epilogue: LN affine + src + forcing; u layout [T][D][N]
  const int nbase = (b * 64 + h) * 64;
  #pragma unroll
  for (int ntl = 0; ntl < 2; ++ntl) {
    const int d0 = ntb[ntl] * 16 + lgrp * 4;    // <128
    #pragma unroll
    for (int st = 0; st < 4; ++st) {
      const int site = st * 16 + lrow;
      const float m = mean_s[site], rs = rstd_s[site];
      #pragma unroll
      for (int j = 0; j < 4; ++j) {
        const int d = d0 + j;
        const float xer = rs * acc[ntl][st][j] - rs * m * evec[d] + cvec[d];
        const float xei = rs * acc[ntl + 2][st][j] - rs * m * evec[d + 128] + cvec[d + 128];
        const float sr = tanhf(xer) * gain_s[d];
        const float si = tanhf(xei) * gain_s[d];
        const float vr = xer + sr, vi = xei + si;
        const float ur = vr * fre_s[d] - vi * fim_s[d];
        const float ui = vr * fim_s[d] + vi * fre_s[d];
        const size_t off = (size_t)t * ND_ + (size_t)d * N_ + nbase + site;
        u_re[off] = ur;
        u_im[off] = ui;
      }
    }
  }
}

// ---------------- kernel 4: sequential scan over T (in place, u layout [T][D][N]) ----------------

__global__ __launch_bounds__(256) void k_scan(
    float* __restrict__ u_re, float* __restrict__ u_im,
    const float* __restrict__ dt,
    const float* __restrict__ nu, const float* __restrict__ theta) {
  const int idx = blockIdx.x * 256 + threadIdx.x;   // d*N + n
  const int n = idx & 8191;
  const int d = idx >> 13;
  const int b = n >> 12;
  const float lr = -softplus_f(nu[d]);
  const float li = theta[d];
  float hr = 0.f, hi = 0.f;
  for (int t = 0; t < 16; ++t) {
    const float dtv = dt[b * 16 + t];
    float s, c;
    sincosf(li * dtv, &s, &c);
    const float er = expf(lr * dtv);
    const float ar = er * c, ai = er * s;
    const size_t off = (size_t)t * ND_ + idx;
    const float ur = u_re[off], ui = u_im[off];
    const float nr = ar * hr - ai * hi + ur;
    const float ni = ar * hi + ai * hr + ui;
    hr = nr; hi = ni;
    u_re[off] = hr; u_im[off] = hi;
  }
}

// ---------------- kernel 5: decode via MFMA (real part) + residual (in place on x2_re) ----------------
// block = (b,t,h): 64 sites; h[t] read from u [T][D][N]; wave w owns n-tiles {2w,2w+1}

__global__ __launch_bounds__(256, 2) void k_decode_mfma(
    const float* __restrict__ h_re, const float* __restrict__ h_im,
    const ushort* __restrict__ decswz,
    float* __restrict__ x2_re) {
  __shared__ ushort xlds[64][264];
  const int tid = threadIdx.x;
  const int wave = tid >> 6, lane = tid & 63;
  const int lrow = lane & 15, lgrp = lane >> 4;
  const int blk = blockIdx.x;          // ((b*16)+t)*64 + h
  const int h = blk & 63;
  const int t = (blk >> 6) & 15;
  const int b = blk >> 10;
  const int bt = b * T_ + t;
  const int nbase = (b * 64 + h) * 64;

  uint* xlds32 = (uint*)&xlds[0][0];
  #pragma unroll
  for (int i = 0; i < 16; ++i) {
    const int p = i * 4 + wave;        // d-pair
    const size_t o0 = (size_t)t * ND_ + (size_t)(2 * p) * N_ + nbase + lane;
    const size_t o1 = o0 + N_;
    xlds32[lane * 132 + p] = pack2bf(h_re[o0], h_re[o1]);
    xlds32[lane * 132 + 64 + p] = pack2bf(h_im[o0], h_im[o1]);
  }
  __syncthreads();

  f32x4 acc[2][4];
  #pragma unroll
  for (int ntl = 0; ntl < 2; ++ntl)
    #pragma unroll
    for (int st = 0; st < 4; ++st) acc[ntl][st] = (f32x4)0.f;

  #pragma unroll
  for (int ks = 0; ks < 8; ++ks) {
    bf16x8 bfr[4];
    #pragma unroll
    for (int st = 0; st < 4; ++st)
      bfr[st] = *(const bf16x8*)&xlds[st * 16 + lrow][ks * 32 + lgrp * 8];
    #pragma unroll
    for (int ntl = 0; ntl < 2; ++ntl) {
      const int ntile = wave * 2 + ntl;
      const bf16x8 afr = ((const bf16x8*)decswz)[(ntile * 8 + ks) * 64 + lane];
      #pragma unroll
      for (int st = 0; st < 4; ++st)
        acc[ntl][st] = __builtin_amdgcn_mfma_f32_16x16x32_bf16(
            afr, bfr[st], acc[ntl][st], 0, 0, 0);
    }
  }

  #pragma unroll
  for (int ntl = 0; ntl < 2; ++ntl) {
    #pragma unroll
    for (int j = 0; j < 4; ++j) {
      const int d = (wave * 2 + ntl) * 16 + lgrp * 4 + j;
      const size_t rowoff = ((size_t)bt * D_ + d) * HW_ + h * W_;
      #pragma unroll
      for (int st = 0; st < 4; ++st) {
        const int site = st * 16 + lrow;
        x2_re[rowoff + site] += acc[ntl][st][j];
      }
    }
  }
}

// ---------------- FFN weight prep ----------------

__global__ __launch_bounds__(256) void k_prep_b1(
    const float* __restrict__ w1_re, const float* __restrict__ w1_im,
    ushort* __restrict__ b1swz) {
  const int t = blockIdx.x * 256 + threadIdx.x;   // 0..32767
  const int lane = t & 63;
  const int ks = (t >> 6) & 7;
  const int ntile = t >> 9;
  const int n = ntile * 16 + (lane & 15);
  const int k0 = ks * 32 + (lane >> 4) * 8;
  ushort v[8];
  #pragma unroll
  for (int e = 0; e < 8; ++e) {
    const int k = k0 + e;
    float val;
    if (k < 128) {
      val = (n < 512) ? w1_re[k * 512 + n] : w1_im[k * 512 + (n - 512)];
    } else {
      const int kk = k - 128;
      val = (n < 512) ? -w1_im[kk * 512 + n] : w1_re[kk * 512 + (n - 512)];
    }
    v[e] = f2bf(val);
  }
  uint4 u;
  u.x = (uint)v[0] | ((uint)v[1] << 16);
  u.y = (uint)v[2] | ((uint)v[3] << 16);
  u.z = (uint)v[4] | ((uint)v[5] << 16);
  u.w = (uint)v[6] | ((uint)v[7] << 16);
  ((uint4*)b1swz)[t] = u;
}

__global__ __launch_bounds__(256) void k_prep_b2(
    const float* __restrict__ w2_re, const float* __restrict__ w2_im,
    ushort* __restrict__ b2swz) {
  const int t = blockIdx.x * 256 + threadIdx.x;   // 0..32767
  const int lane = t & 63;
  const int kc = (t >> 6) & 31;
  const int rowtile = t >> 11;
  const int n2 = rowtile * 16 + (lane & 15);
  const int k0 = kc * 32 + (lane >> 4) * 8;
  ushort v[8];
  #pragma unroll
  for (int e = 0; e < 8; ++e) {
    const int k = k0 + e;
    float val;
    if (k < 512) {
      val = (n2 < 128) ? w2_re[k * 128 + n2] : w2_im[k * 128 + (n2 - 128)];
    } else {
      const int kk = k - 512;
      val = (n2 < 128) ? -w2_im[kk * 128 + n2] : w2_re[kk * 128 + (n2 - 128)];
    }
    v[e] = f2bf(val);
  }
  uint4 u;
  u.x = (uint)v[0] | ((uint)v[1] << 16);
  u.y = (uint)v[2] | ((uint)v[3] << 16);
  u.z = (uint)v[4] | ((uint)v[5] << 16);
  u.w = (uint)v[6] | ((uint)v[7] << 16);
  ((uint4*)b2swz)[t] = u;
}

// ---------------- kernel 6: complex FFN via bf16 MFMA ----------------

__global__ __launch_bounds__(256, 2) void k_ffn_mfma(
    const float* __restrict__ x3_re, const float* __restrict__ x3_im,
    const ushort* __restrict__ b1swz, const ushort* __restrict__ b2swz,
    const float* __restrict__ b1_re, const float* __restrict__ b1_im,
    const float* __restrict__ b2_re, const float* __restrict__ b2_im,
    float* __restrict__ out) {
  __shared__ ushort xlds[64][264];
  __shared__ ushort actlds[64][136];
  const int tid = threadIdx.x;
  const int wave = tid >> 6, lane = tid & 63;
  const int lrow = lane & 15, lgrp = lane >> 4;
  const int blk = blockIdx.x;        // 2048 = bt*64 + h
  const int bt = blk >> 6;
  const int hw0 = (blk & 63) * 64;
  const size_t base = (size_t)bt * D_ * HW_ + hw0;

  uint* xlds32 = (uint*)&xlds[0][0];
  #pragma unroll
  for (int i = 0; i < 16; ++i) {
    const int p = i * 4 + wave;
    const float r0 = x3_re[base + (size_t)(2 * p) * HW_ + lane];
    const float r1 = x3_re[base + (size_t)(2 * p + 1) * HW_ + lane];
    const float i0 = x3_im[base + (size_t)(2 * p) * HW_ + lane];
    const float i1 = x3_im[base + (size_t)(2 * p + 1) * HW_ + lane];
    xlds32[lane * 132 + p] = pack2bf(r0, r1);
    xlds32[lane * 132 + 64 + p] = pack2bf(i0, i1);
  }
  __syncthreads();

  f32x4 dacc[4][4];
  #pragma unroll
  for (int rt = 0; rt < 4; ++rt)
    #pragma unroll
    for (int st = 0; st < 4; ++st) dacc[rt][st] = (f32x4)0.f;

  uint* act32 = (uint*)&actlds[0][0];

  for (int chunk = 0; chunk < 8; ++chunk) {
    f32x4 hacc[2][4];
    #pragma unroll
    for (int ntl = 0; ntl < 2; ++ntl)
      #pragma unroll
      for (int st = 0; st < 4; ++st) hacc[ntl][st] = (f32x4)0.f;

    #pragma unroll
    for (int ks = 0; ks < 8; ++ks) {
      bf16x8 bfr[4];
      #pragma unroll
      for (int st = 0; st < 4; ++st)
        bfr[st] = *(const bf16x8*)&xlds[st * 16 + lrow][ks * 32 + lgrp * 8];
      #pragma unroll
      for (int ntl = 0; ntl < 2; ++ntl) {
        const int ntile = chunk * 8 + wave * 2 + ntl;
        const bf16x8 afr = ((const bf16x8*)b1swz)[(ntile * 8 + ks) * 64 + lane];
        #pragma unroll
        for (int st = 0; st < 4; ++st)
          hacc[ntl][st] = __builtin_amdgcn_mfma_f32_16x16x32_bf16(
              afr, bfr[st], hacc[ntl][st], 0, 0, 0);
      }
    }
    __syncthreads();
    #pragma unroll
    for (int ntl = 0; ntl < 2; ++ntl) {
      const int nlocal0 = (wave * 2 + ntl) * 16 + lgrp * 4;
      const int ng0 = chunk * 128 + nlocal0;
      #pragma unroll
      for (int st = 0; st < 4; ++st) {
        float gv[4];
        #pragma unroll
        for (int j = 0; j < 4; ++j) {
          const int ng = ng0 + j;
          const float bias = (ng < 512) ? b1_re[ng] : b1_im[ng - 512];
          gv[j] = gelu_tanh(hacc[ntl][st][j] + bias);
        }
        const int site = st * 16 + lrow;
        act32[site * 68 + (nlocal0 >> 1)] = pack2bf(gv[0], gv[1]);
        act32[site * 68 + (nlocal0 >> 1) + 1] = pack2bf(gv[2], gv[3]);
      }
    }
    __syncthreads();
    #pragma unroll
    for (int ks2 = 0; ks2 < 4; ++ks2) {
      bf16x8 bfr[4];
      #pragma unroll
      for (int st = 0; st < 4; ++st)
        bfr[st] = *(const bf16x8*)&actlds[st * 16 + lrow][ks2 * 32 + lgrp * 8];
      const int kc = chunk * 4 + ks2;
      #pragma unroll
      for (int rt = 0; rt < 4; ++rt) {
        const int rowtile = wave * 4 + rt;
        const bf16x8 afr = ((const bf16x8*)b2swz)[(rowtile * 32 + kc) * 64 + lane];
        #pragma unroll
        for (int st = 0; st < 4; ++st)
          dacc[rt][st] = __builtin_amdgcn_mfma_f32_16x16x32_bf16(
              afr, bfr[st], dacc[rt][st], 0, 0, 0);
      }
    }
  }

  #pragma unroll
  for (int rt = 0; rt < 4; ++rt) {
    #pragma unroll
    for (int j = 0; j < 4; ++j) {
      const int n2 = (wave * 4 + rt) * 16 + lgrp * 4 + j;
      const int d = n2 & 127;
      const int c = n2 >> 7;
      const float bias2 = c ? b2_im[d] : b2_re[d];
      const float* rsrc = c ? x3_im : x3_re;
      #pragma unroll
      for (int st = 0; st < 4; ++st) {
        const size_t idx = (size_t)(bt * D_ + d) * HW_ + hw0 + st * 16 + lrow;
        out[idx * 2 + c] = rsrc[idx] + dacc[rt][st][j] + bias2;
      }
    }
  }
}

// ---------------- host launcher ----------------

extern "C" void kernel_launch(void* const* d_in, const int* in_sizes, int n_in,
                              void* d_out, int out_size, void* d_ws, size_t ws_size,
                              hipStream_t stream) {
  const float* x_re   = (const float*)d_in[0];
  const float* x_im   = (const float*)d_in[1];
  const float* dt     = (const float*)d_in[2];
  const float* ln_s_g = (const float*)d_in[3];
  const float* ln_s_b = (const float*)d_in[4];
  const float* ln_t_g = (const float*)d_in[5];
  const float* ln_t_b = (const float*)d_in[6];
  const float* metric = (const float*)d_in[7];
  const float* conv_w = (const float*)d_in[8];
  const float* conv_b = (const float*)d_in[9];
  const float* nu     = (const float*)d_in[10];
  const float* theta  = (const float*)d_in[11];
  const float* enc_re = (const float*)d_in[12];
  const float* enc_im = (const float*)d_in[13];
  const float* dec_re = (const float*)d_in[14];
  const float* dec_im = (const float*)d_in[15];
  const float* src_g  = (const float*)d_in[16];
  const float* w1_re  = (const float*)d_in[17];
  const float* w1_im  = (const float*)d_in[18];
  const float* b1_re  = (const float*)d_in[19];
  const float* b1_im  = (const float*)d_in[20];
  const float* w2_re  = (const float*)d_in[21];
  const float* w2_im  = (const float*)d_in[22];
  const float* b2_re  = (const float*)d_in[23];
  const float* b2_im  = (const float*)d_in[24];
  float* out = (float*)d_out;
  float* ws = (float*)d_ws;

  // workspace layout
  float* wt   = ws;                          // weight-prep region (2.36 MB)
  float* bufA = ws + WT_FLOATS;
  float* u_re = bufA;
  float* u_im = bufA + PLANE_;
  ushort* wt16  = (ushort*)wt;
  ushort* cwswz = wt16;                      // 589,824 bf16 (conv frags, dead after conv)
  ushort* b1swz = wt16;                      // 262,144 bf16
  ushort* b2swz = wt16 + 262144;             // 262,144 bf16
  ushort* encswz = wt16 + 524288;            // 65,536 bf16
  ushort* decswz = wt16 + 589824;            // 32,768 bf16
  float*  evec   = (float*)(wt16 + 622592);  // 256 f32
  float*  cvec   = evec + 256;               // 256 f32
  ushort* xri_bf = (ushort*)bufA;            // bf16 LN output (dead after conv)

  const size_t needA = (size_t)(WT_FLOATS + 2 * PLANE_ + 2 * PLANE_) * 4;
  const bool planA = ws_size >= needA;
  float *x2_re, *x2_im, *ffn_out;
  if (planA) {
    x2_re = bufA + 2 * (size_t)PLANE_;
    x2_im = x2_re + PLANE_;
    ffn_out = out;
  } else {
    x2_re = out;
    x2_im = out + PLANE_;
    ffn_out = bufA;
  }

  k_prep_conv<<<288, 256, 0, stream>>>(conv_w, cwswz);
  k_spatial_ln<<<BT_ * H_, 256, 0, stream>>>(x_re, x_im, ln_s_g, ln_s_b, metric, xri_bf);
  k_conv_mfma<<<BT_ * 32, 512, 0, stream>>>(xri_bf, cwswz, conv_b, x_re, x_im,
                                            x2_re, x2_im);
  // cwswz dead after conv; overwrite region with GEMM weights
  k_prep_b1<<<128, 256, 0, stream>>>(w1_re, w1_im, b1swz);
  k_prep_b2<<<128, 256, 0, stream>>>(w2_re, w2_im, b2swz);
  k_prep_enc<<<32, 256, 0, stream>>>(enc_re, enc_im, ln_t_g, encswz);
  k_prep_encvec<<<1, 256, 0, stream>>>(enc_re, enc_im, ln_t_g, ln_t_b, evec, cvec);
  k_prep_dec<<<16, 256, 0, stream>>>(dec_re, dec_im, decswz);
  k_temporal_mfma<<<B_ * T_ * H_, 256, 0, stream>>>(x2_re, x2_im, dt, encswz,
                                                    evec, cvec, nu, theta, src_g,
                                                    u_re, u_im);
  k_scan<<<ND_ / 256, 256, 0, stream>>>(u_re, u_im, dt, nu, theta);
  k_decode_mfma<<<B_ * T_ * H_, 256, 0, stream>>>(u_re, u_im, decswz, x2_re);
  k_ffn_mfma<<<BT_ * H_, 256, 0, stream>>>(x2_re, x2_im, b1swz, b2swz,
                                           b1_re, b1_im, b2_re, b2_im, ffn_out);
  if (!planA) {
    hipMemcpyAsync(d_out, ffn_out, (size_t)2 * PLANE_ * sizeof(float),
                   hipMemcpyDeviceToDevice, stream);
  }
}

// Round 5
// 913.429 us; speedup vs baseline: 6.6867x; 1.0365x over previous
//
#include <hip/hip_runtime.h>
#include <hip/hip_bf16.h>
#include <stdint.h>

#define B_   2
#define T_   16
#define D_   128
#define D2_  256
#define H_   64
#define W_   64
#define HW_  4096
#define BT_  32
#define N_   8192
#define ND_  1048576           // N_*D_
#define PLANE_ 16777216        // B*T*D*H*W  (one of re/im)
#define WT_FLOATS 589824       // 256*256*9

typedef short bf16x8 __attribute__((ext_vector_type(8)));
typedef float f32x4 __attribute__((ext_vector_type(4)));
typedef unsigned int uint;
typedef unsigned short ushort;

// ---------------- device helpers ----------------

__device__ __forceinline__ float softplus_f(float x) {
  return fmaxf(x, 0.0f) + log1pf(expf(-fabsf(x)));
}

// gelu(tanh approx) = x*(1 - 1/(exp(2*z)+1)), z = sqrt(2/pi)*(x+0.044715 x^3)
__device__ __forceinline__ float gelu_fast(float x) {
  const float Ac = 2.3022082963f;   // 2*sqrt(2/pi)*log2(e)
  const float Bc = 0.1029437f;      // Ac*0.044715
  float t = x * x;
  float z = x * fmaf(Bc, t, Ac);
  float e = __builtin_amdgcn_exp2f(z);
  float r = __builtin_amdgcn_rcpf(e + 1.0f);
  return fmaf(-x, r, x);
}

__device__ __forceinline__ float tanh_fast(float x) {
  float e = __builtin_amdgcn_exp2f(x * 2.8853900818f);  // 2*log2(e)
  float r = __builtin_amdgcn_rcpf(e + 1.0f);
  return fmaf(-2.0f, r, 1.0f);
}

__device__ __forceinline__ ushort f2bf(float f) {
  uint u = __float_as_uint(f);
  uint r = (u + 0x7fffu + ((u >> 16) & 1u)) >> 16;   // RNE
  return (ushort)r;
}

__device__ __forceinline__ uint cvt_pk(float a, float b) {
  __hip_bfloat162 h = __float22bfloat162_rn(make_float2(a, b));
  return *reinterpret_cast<uint*>(&h);
}

// ---------------- kernel 1: spatial complex LN + metric scale -> xri bf16 [BT][256][H][W] ----------------

__global__ __launch_bounds__(256) void k_spatial_ln(
    const float* __restrict__ x_re, const float* __restrict__ x_im,
    const float* __restrict__ g, const float* __restrict__ bb,
    const float* __restrict__ metric, ushort* __restrict__ xri) {
  __shared__ float vals[256][64];
  __shared__ float red1[4][64];
  __shared__ float red2[4][64];
  __shared__ float mean_s[64];
  __shared__ float rstd_s[64];
  const int blk = blockIdx.x;      // bt*64 + h
  const int bt = blk >> 6;
  const int h = blk & 63;
  const int tid = threadIdx.x;
  const int w = tid & 63, q = tid >> 6;

  float s1 = 0.f, s2 = 0.f;
  #pragma unroll 4
  for (int i = 0; i < 64; ++i) {
    const int c = i * 4 + q;
    const int d = c & 127;
    const float* src = (c < 128) ? x_re : x_im;
    float v = src[((size_t)bt * D_ + d) * HW_ + h * W_ + w];
    vals[c][w] = v;
    s1 += v; s2 += v * v;
  }
  red1[q][w] = s1; red2[q][w] = s2;
  __syncthreads();
  if (tid < 64) {
    float m = red1[0][tid] + red1[1][tid] + red1[2][tid] + red1[3][tid];
    float ss = red2[0][tid] + red2[1][tid] + red2[2][tid] + red2[3][tid];
    m *= (1.f / 256.f);
    float var = ss * (1.f / 256.f) - m * m;
    mean_s[tid] = m;
    rstd_s[tid] = rsqrtf(var + 1e-5f);
  }
  __syncthreads();
  const float m = mean_s[w], rs = rstd_s[w];
  #pragma unroll 4
  for (int i = 0; i < 64; ++i) {
    const int c = i * 4 + q;
    float v = (vals[c][w] - m) * rs * g[c] + bb[c];
    v *= metric[(size_t)c * HW_ + h * W_ + w];
    xri[((size_t)bt * D2_ + c) * HW_ + h * W_ + w] = f2bf(v);
  }
}

// ---------------- conv weight prep: fragment-order bf16 (K = ci straight) ----------------

__global__ __launch_bounds__(256) void k_prep_conv(
    const float* __restrict__ wg, ushort* __restrict__ cwswz) {
  const int t = blockIdx.x * 256 + threadIdx.x;   // 0..73727
  if (t >= 73728) return;
  const int lane = t & 63;
  const int nt = (t >> 6) & 15;
  const int ks = (t >> 10) & 7;
  const int kk = t >> 13;                         // 0..8
  const int co = nt * 16 + (lane & 15);
  const int ci0 = ks * 32 + (lane >> 4) * 8;
  ushort v[8];
  #pragma unroll
  for (int e = 0; e < 8; ++e)
    v[e] = f2bf(wg[((size_t)co * 256 + ci0 + e) * 9 + kk]);
  uint4 u;
  u.x = (uint)v[0] | ((uint)v[1] << 16);
  u.y = (uint)v[2] | ((uint)v[3] << 16);
  u.z = (uint)v[4] | ((uint)v[5] << 16);
  u.w = (uint)v[6] | ((uint)v[7] << 16);
  ((uint4*)cwswz)[t] = u;
}

// ---------------- kernel 2: 3x3 conv via bf16 MFMA (implicit GEMM) ----------------
// LDS rows 512B (256 bf16 ci), XOR-swizzled 16B units: unit' = unit ^ (row&7).

__global__ __launch_bounds__(512, 1) void k_conv_mfma(
    const ushort* __restrict__ xri, const ushort* __restrict__ cwswz,
    const float* __restrict__ bias,
    const float* __restrict__ x_re, const float* __restrict__ x_im,
    float* __restrict__ x2_re, float* __restrict__ x2_im) {
  __shared__ ushort xb[67584];   // 4*66 rows * 256 bf16 = 132 KB
  const int tid = threadIdx.x;
  const int wave = tid >> 6, lane = tid & 63;
  const int lrow = lane & 15, lgrp = lane >> 4;
  const int blk = blockIdx.x;         // 1024 = bt*32 + hp
  const int bt = blk >> 5;
  const int h0 = (blk & 31) * 2;

  uint* xb32 = (uint*)xb;
  // zero halo rows (row_in_block 0 and 65 of each j)
  {
    const int r = tid >> 7;           // 0..3
    const int p = tid & 127;          // dword
    xb32[(r * 66 + 0) * 128 + p] = 0;
    xb32[(r * 66 + 65) * 128 + p] = 0;
  }
  // main staging: 16 iters, b128 swizzled writes (conflict-free)
  #pragma unroll
  for (int i = 0; i < 16; ++i) {
    const int idx = i * 512 + tid;    // 0..8191
    const int j = idx >> 11;          // h row 0..3
    const int rem = idx & 2047;
    const int q = rem >> 6;           // ci-quad 0..31
    const int w = rem & 63;
    const int hh = h0 + j - 1;
    uint4 u = {0u, 0u, 0u, 0u};
    if (hh >= 0 && hh < 64) {
      const ushort* src = &xri[((size_t)bt * D2_ + q * 8) * HW_ + hh * W_ + w];
      #pragma unroll
      for (int e = 0; e < 4; ++e) {
        uint lo = src[(size_t)(2 * e) * HW_];
        uint hi = src[(size_t)(2 * e + 1) * HW_];
        ((uint*)&u)[e] = lo | (hi << 16);
      }
    }
    const int row = j * 66 + 1 + w;
    *(uint4*)&xb[row * 256 + ((q ^ (row & 7)) << 3)] = u;
  }
  __syncthreads();

  const int cw = wave & 3;
  const int sg = wave >> 2;
  f32x4 acc[4][4];
  #pragma unroll
  for (int j = 0; j < 4; ++j)
    #pragma unroll
    for (int i = 0; i < 4; ++i) acc[j][i] = (f32x4)0.f;

  for (int kh = 0; kh < 3; ++kh) {
    const int rowb = (sg + kh) * 66;
    for (int kw = 0; kw < 3; ++kw) {
      const int kk = kh * 3 + kw;
      #pragma unroll
      for (int ks = 0; ks < 8; ++ks) {
        bf16x8 bfr[4];
        #pragma unroll
        for (int i = 0; i < 4; ++i) {
          const int row = rowb + i * 16 + lrow + kw;
          bfr[i] = *(const bf16x8*)&xb[row * 256 + (((ks * 4 + lgrp) ^ (row & 7)) << 3)];
        }
        const int fbase = ((kk * 8 + ks) * 16 + cw * 4) * 64 + lane;
        #pragma unroll
        for (int j = 0; j < 4; ++j) {
          const bf16x8 afr = ((const bf16x8*)cwswz)[fbase + j * 64];
          #pragma unroll
          for (int i = 0; i < 4; ++i)
            acc[j][i] = __builtin_amdgcn_mfma_f32_16x16x32_bf16(
                afr, bfr[i], acc[j][i], 0, 0, 0);
        }
      }
    }
  }

  #pragma unroll
  for (int j = 0; j < 4; ++j) {
    #pragma unroll
    for (int jj = 0; jj < 4; ++jj) {
      const int co = (cw * 4 + j) * 16 + lgrp * 4 + jj;
      const int d = co & 127;
      const float bv = bias[co];
      const float* rsrc = (co < 128) ? x_re : x_im;
      float* dst = (co < 128) ? x2_re : x2_im;
      const size_t rowoff = ((size_t)bt * D_ + d) * HW_ + (h0 + sg) * W_;
      #pragma unroll
      for (int i = 0; i < 4; ++i) {
        const int w = i * 16 + lrow;
        dst[rowoff + w] = acc[j][i][jj] + bv + rsrc[rowoff + w];
      }
    }
  }
}

// ---------------- decay/forcing table: [BT][128] float4 {decay_re, decay_im, f_re, f_im} ----------------

__global__ __launch_bounds__(256) void k_prep_decay(
    const float* __restrict__ dt, const float* __restrict__ nu,
    const float* __restrict__ theta, float4* __restrict__ decay) {
  const int idx = blockIdx.x * 256 + threadIdx.x;  // 0..4095
  const int d = idx & 127;
  const int bt = idx >> 7;
  const float dtv = dt[bt];
  const float lr = -softplus_f(nu[d]);
  const float li = theta[d];
  float s, c;
  sincosf(li * dtv, &s, &c);
  const float er = expf(lr * dtv);
  const float ar = er * c, ai = er * s;
  const float den = lr * lr + li * li;
  const float nr = ar - 1.f, ni = ai;
  float4 v;
  v.x = ar; v.y = ai;
  v.z = (nr * lr + ni * li) / den;
  v.w = (ni * lr - nr * li) / den;
  decay[idx] = v;
}

// ---------------- temporal-encode weight prep (K rows permuted to interleaved re/im) ----------------

__global__ __launch_bounds__(256) void k_prep_enc(
    const float* __restrict__ enc_re, const float* __restrict__ enc_im,
    const float* __restrict__ g, ushort* __restrict__ encswz) {
  const int t = blockIdx.x * 256 + threadIdx.x;   // 0..8191
  const int lane = t & 63;
  const int ks = (t >> 6) & 7;
  const int ntile = t >> 9;
  const int n = ntile * 16 + (lane & 15);
  const int k0 = ks * 32 + (lane >> 4) * 8;
  ushort v[8];
  #pragma unroll
  for (int e = 0; e < 8; ++e) {
    const int kp = k0 + e;
    const int k = (kp >> 1) | ((kp & 1) << 7);   // physical -> logical
    float val;
    if (k < 128) {
      val = (n < 128) ? enc_re[k * 128 + n] : enc_im[k * 128 + (n - 128)];
    } else {
      const int kk = k - 128;
      val = (n < 128) ? -enc_im[kk * 128 + n] : enc_re[kk * 128 + (n - 128)];
    }
    v[e] = f2bf(val * g[k]);
  }
  uint4 u;
  u.x = (uint)v[0] | ((uint)v[1] << 16);
  u.y = (uint)v[2] | ((uint)v[3] << 16);
  u.z = (uint)v[4] | ((uint)v[5] << 16);
  u.w = (uint)v[6] | ((uint)v[7] << 16);
  ((uint4*)encswz)[t] = u;
}

__global__ __launch_bounds__(256) void k_prep_encvec(
    const float* __restrict__ enc_re, const float* __restrict__ enc_im,
    const float* __restrict__ g, const float* __restrict__ bb,
    float* __restrict__ evec, float* __restrict__ cvec) {
  const int n = threadIdx.x;   // one block of 256
  float se = 0.f, sc = 0.f;
  for (int k = 0; k < 256; ++k) {
    float ep;
    if (k < 128) {
      ep = (n < 128) ? enc_re[k * 128 + n] : enc_im[k * 128 + (n - 128)];
    } else {
      const int kk = k - 128;
      ep = (n < 128) ? -enc_im[kk * 128 + n] : enc_re[kk * 128 + (n - 128)];
    }
    se = fmaf(g[k], ep, se);
    sc = fmaf(bb[k], ep, sc);
  }
  evec[n] = se;
  cvec[n] = sc;
}

__global__ __launch_bounds__(256) void k_prep_dec(
    const float* __restrict__ dec_re, const float* __restrict__ dec_im,
    ushort* __restrict__ decswz) {
  const int t = blockIdx.x * 256 + threadIdx.x;   // 0..4095
  const int lane = t & 63;
  const int ks = (t >> 6) & 7;
  const int ntile = t >> 9;
  const int n = ntile * 16 + (lane & 15);
  const int k0 = ks * 32 + (lane >> 4) * 8;
  ushort v[8];
  #pragma unroll
  for (int e = 0; e < 8; ++e) {
    const int kp = k0 + e;
    const int k = (kp >> 1) | ((kp & 1) << 7);
    float val = (k < 128) ? dec_re[k * 128 + n] : -dec_im[(k - 128) * 128 + n];
    v[e] = f2bf(val);
  }
  uint4 u;
  u.x = (uint)v[0] | ((uint)v[1] << 16);
  u.y = (uint)v[2] | ((uint)v[3] << 16);
  u.z = (uint)v[4] | ((uint)v[5] << 16);
  u.w = (uint)v[6] | ((uint)v[7] << 16);
  ((uint4*)decswz)[t] = u;
}

// ---------------- kernel 3: temporal LN (folded) + encode MFMA + src + ZOH -> u [T][D][N] ----------------

__global__ __launch_bounds__(256, 2) void k_temporal_mfma(
    const float* __restrict__ x2_re, const float* __restrict__ x2_im,
    const ushort* __restrict__ encswz,
    const float* __restrict__ evec, const float* __restrict__ cvec,
    const float4* __restrict__ decay,
    const float* __restrict__ src_gain,
    float* __restrict__ u_re, float* __restrict__ u_im) {
  __shared__ ushort xlds[64][256];
  __shared__ float red1[4][64], red2[4][64];
  __shared__ float mean_s[64], rstd_s[64];
  __shared__ float fre_s[128], fim_s[128], gain_s[128];
  const int tid = threadIdx.x;
  const int wave = tid >> 6, lane = tid & 63;
  const int lrow = lane & 15, lgrp = lane >> 4;
  const int blk = blockIdx.x;          // ((b*16)+t)*64 + h
  const int h = blk & 63;
  const int t = (blk >> 6) & 15;
  const int b = blk >> 10;
  const int bt = b * T_ + t;
  const size_t base = (size_t)bt * D_ * HW_ + h * W_;

  // stage RAW x2 -> bf16 LDS (interleaved re/im, swizzled b128 writes) + LN sums
  float s1 = 0.f, s2 = 0.f;
  #pragma unroll
  for (int i = 0; i < 8; ++i) {
    const int q = i * 4 + wave;        // d-quad 0..31
    const size_t g = base + (size_t)(q * 4) * HW_ + lane;
    float r0 = x2_re[g],           i0 = x2_im[g];
    float r1 = x2_re[g + HW_],     i1 = x2_im[g + HW_];
    float r2 = x2_re[g + 2 * HW_], i2 = x2_im[g + 2 * HW_];
    float r3 = x2_re[g + 3 * HW_], i3 = x2_im[g + 3 * HW_];
    uint4 u;
    u.x = cvt_pk(r0, i0); u.y = cvt_pk(r1, i1);
    u.z = cvt_pk(r2, i2); u.w = cvt_pk(r3, i3);
    *(uint4*)&xlds[lane][(q ^ (lane & 7)) << 3] = u;
    s1 += (r0 + r1 + r2 + r3) + (i0 + i1 + i2 + i3);
    s2 += r0 * r0 + r1 * r1 + r2 * r2 + r3 * r3
        + i0 * i0 + i1 * i1 + i2 * i2 + i3 * i3;
  }
  red1[wave][lane] = s1;
  red2[wave][lane] = s2;
  __syncthreads();
  if (tid < 64) {
    float m = red1[0][tid] + red1[1][tid] + red1[2][tid] + red1[3][tid];
    float ss = red2[0][tid] + red2[1][tid] + red2[2][tid] + red2[3][tid];
    m *= (1.f / 256.f);
    float var = ss * (1.f / 256.f) - m * m;
    mean_s[tid] = m;
    rstd_s[tid] = rsqrtf(var + 1e-5f);
  }
  if (tid < 128) {
    const float4 dc = decay[bt * 128 + tid];
    fre_s[tid] = dc.z;
    fim_s[tid] = dc.w;
    gain_s[tid] = src_gain[tid];
  }
  __syncthreads();

  f32x4 acc[4][4];
  #pragma unroll
  for (int ntl = 0; ntl < 4; ++ntl)
    #pragma unroll
    for (int st = 0; st < 4; ++st) acc[ntl][st] = (f32x4)0.f;

  const int swz = lrow & 7;   // site&7 is st-independent (st*16 ≡ 0 mod 8)
  const int ntb[4] = {wave * 2, wave * 2 + 1, wave * 2 + 8, wave * 2 + 9};
  #pragma unroll
  for (int ks = 0; ks < 8; ++ks) {
    bf16x8 bfr[4];
    #pragma unroll
    for (int st = 0; st < 4; ++st)
      bfr[st] = *(const bf16x8*)&xlds[st * 16 + lrow][(((ks * 4 + lgrp) ^ swz)) << 3];
    #pragma unroll
    for (int ntl = 0; ntl < 4; ++ntl) {
      const bf16x8 afr = ((const bf16x8*)encswz)[(ntb[ntl] * 8 + ks) * 64 + lane];
      #pragma unroll
      for (int st = 0; st < 4; ++st)
        acc[ntl][st] = __builtin_amdgcn_mfma_f32_16x16x32_bf16(
            afr, bfr[st], acc[ntl][st], 0, 0, 0);
    }
  }

  const int nbase = (b * 64 + h) * 64;
  #pragma unroll
  for (int ntl = 0; ntl < 2; ++ntl) {
    const int d0 = ntb[ntl] * 16 + lgrp * 4;    // <128
    #pragma unroll
    for (int st = 0; st < 4; ++st) {
      const int site = st * 16 + lrow;
      const float m = mean_s[site], rs = rstd_s[site];
      #pragma unroll
      for (int j = 0; j < 4; ++j) {
        const int d = d0 + j;
        const float xer = rs * acc[ntl][st][j] - rs * m * evec[d] + cvec[d];
        const float xei = rs * acc[ntl + 2][st][j] - rs * m * evec[d + 128] + cvec[d + 128];
        const float sr = tanh_fast(xer) * gain_s[d];
        const float si = tanh_fast(xei) * gain_s[d];
        const float vr = xer + sr, vi = xei + si;
        const float ur = vr * fre_s[d] - vi * fim_s[d];
        const float ui = vr * fim_s[d] + vi * fre_s[d];
        const size_t off = (size_t)t * ND_ + (size_t)d * N_ + nbase + site;
        u_re[off] = ur;
        u_im[off] = ui;
      }
    }
  }
}

// ---------------- kernel 4: sequential scan over T (in place, u layout [T][D][N]) ----------------

__global__ __launch_bounds__(256) void k_scan(
    float* __restrict__ u_re, float* __restrict__ u_im,
    const float4* __restrict__ decay) {
  const int idx = blockIdx.x * 256 + threadIdx.x;   // d*N + n
  const int n = idx & 8191;
  const int d = idx >> 13;
  const int b = n >> 12;
  float hr = 0.f, hi = 0.f;
  for (int t = 0; t < 16; ++t) {
    const float4 dc = decay[(b * 16 + t) * 128 + d];   // wave-uniform
    const size_t off = (size_t)t * ND_ + idx;
    const float ur = u_re[off], ui = u_im[off];
    const float nr = fmaf(dc.x, hr, fmaf(-dc.y, hi, ur));
    const float ni = fmaf(dc.x, hi, fmaf(dc.y, hr, ui));
    hr = nr; hi = ni;
    u_re[off] = hr;
    u_im[off] = hi;
  }
}

// ---------------- kernel 5: decode via MFMA (real part) + residual (in place on x2_re) ----------------

__global__ __launch_bounds__(256, 2) void k_decode_mfma(
    const float* __restrict__ h_re, const float* __restrict__ h_im,
    const ushort* __restrict__ decswz,
    float* __restrict__ x2_re) {
  __shared__ ushort xlds[64][256];
  const int tid = threadIdx.x;
  const int wave = tid >> 6, lane = tid & 63;
  const int lrow = lane & 15, lgrp = lane >> 4;
  const int blk = blockIdx.x;          // ((b*16)+t)*64 + h
  const int h = blk & 63;
  const int t = (blk >> 6) & 15;
  const int b = blk >> 10;
  const int bt = b * T_ + t;
  const int nbase = (b * 64 + h) * 64;

  #pragma unroll
  for (int i = 0; i < 8; ++i) {
    const int q = i * 4 + wave;        // d-quad
    const size_t o = (size_t)t * ND_ + (size_t)(q * 4) * N_ + nbase + lane;
    uint4 u;
    u.x = cvt_pk(h_re[o],          h_im[o]);
    u.y = cvt_pk(h_re[o + N_],     h_im[o + N_]);
    u.z = cvt_pk(h_re[o + 2 * N_], h_im[o + 2 * N_]);
    u.w = cvt_pk(h_re[o + 3 * N_], h_im[o + 3 * N_]);
    *(uint4*)&xlds[lane][(q ^ (lane & 7)) << 3] = u;
  }
  __syncthreads();

  f32x4 acc[2][4];
  #pragma unroll
  for (int ntl = 0; ntl < 2; ++ntl)
    #pragma unroll
    for (int st = 0; st < 4; ++st) acc[ntl][st] = (f32x4)0.f;

  const int swz = lrow & 7;
  #pragma unroll
  for (int ks = 0; ks < 8; ++ks) {
    bf16x8 bfr[4];
    #pragma unroll
    for (int st = 0; st < 4; ++st)
      bfr[st] = *(const bf16x8*)&xlds[st * 16 + lrow][(((ks * 4 + lgrp) ^ swz)) << 3];
    #pragma unroll
    for (int ntl = 0; ntl < 2; ++ntl) {
      const int ntile = wave * 2 + ntl;
      const bf16x8 afr = ((const bf16x8*)decswz)[(ntile * 8 + ks) * 64 + lane];
      #pragma unroll
      for (int st = 0; st < 4; ++st)
        acc[ntl][st] = __builtin_amdgcn_mfma_f32_16x16x32_bf16(
            afr, bfr[st], acc[ntl][st], 0, 0, 0);
    }
  }

  #pragma unroll
  for (int ntl = 0; ntl < 2; ++ntl) {
    #pragma unroll
    for (int j = 0; j < 4; ++j) {
      const int d = (wave * 2 + ntl) * 16 + lgrp * 4 + j;
      const size_t rowoff = ((size_t)bt * D_ + d) * HW_ + h * W_;
      #pragma unroll
      for (int st = 0; st < 4; ++st) {
        const int site = st * 16 + lrow;
        x2_re[rowoff + site] += acc[ntl][st][j];
      }
    }
  }
}

// ---------------- FFN weight prep ----------------

__global__ __launch_bounds__(256) void k_prep_b1(
    const float* __restrict__ w1_re, const float* __restrict__ w1_im,
    ushort* __restrict__ b1swz) {
  const int t = blockIdx.x * 256 + threadIdx.x;   // 0..32767
  const int lane = t & 63;
  const int ks = (t >> 6) & 7;
  const int ntile = t >> 9;
  const int n = ntile * 16 + (lane & 15);
  const int k0 = ks * 32 + (lane >> 4) * 8;
  ushort v[8];
  #pragma unroll
  for (int e = 0; e < 8; ++e) {
    const int kp = k0 + e;
    const int k = (kp >> 1) | ((kp & 1) << 7);   // physical -> logical
    float val;
    if (k < 128) {
      val = (n < 512) ? w1_re[k * 512 + n] : w1_im[k * 512 + (n - 512)];
    } else {
      const int kk = k - 128;
      val = (n < 512) ? -w1_im[kk * 512 + n] : w1_re[kk * 512 + (n - 512)];
    }
    v[e] = f2bf(val);
  }
  uint4 u;
  u.x = (uint)v[0] | ((uint)v[1] << 16);
  u.y = (uint)v[2] | ((uint)v[3] << 16);
  u.z = (uint)v[4] | ((uint)v[5] << 16);
  u.w = (uint)v[6] | ((uint)v[7] << 16);
  ((uint4*)b1swz)[t] = u;
}

__global__ __launch_bounds__(256) void k_prep_b2(
    const float* __restrict__ w2_re, const float* __restrict__ w2_im,
    ushort* __restrict__ b2swz) {
  const int t = blockIdx.x * 256 + threadIdx.x;   // 0..32767
  const int lane = t & 63;
  const int kc = (t >> 6) & 31;
  const int rowtile = t >> 11;
  const int n2 = rowtile * 16 + (lane & 15);
  const int k0 = kc * 32 + (lane >> 4) * 8;
  ushort v[8];
  #pragma unroll
  for (int e = 0; e < 8; ++e) {
    const int k = k0 + e;                       // act layout unchanged: no permute
    float val;
    if (k < 512) {
      val = (n2 < 128) ? w2_re[k * 128 + n2] : w2_im[k * 128 + (n2 - 128)];
    } else {
      const int kk = k - 512;
      val = (n2 < 128) ? -w2_im[kk * 128 + n2] : w2_re[kk * 128 + (n2 - 128)];
    }
    v[e] = f2bf(val);
  }
  uint4 u;
  u.x = (uint)v[0] | ((uint)v[1] << 16);
  u.y = (uint)v[2] | ((uint)v[3] << 16);
  u.z = (uint)v[4] | ((uint)v[5] << 16);
  u.w = (uint)v[6] | ((uint)v[7] << 16);
  ((uint4*)b2swz)[t] = u;
}

// ---------------- kernel 6: complex FFN via bf16 MFMA ----------------

__global__ __launch_bounds__(256, 2) void k_ffn_mfma(
    const float* __restrict__ x3_re, const float* __restrict__ x3_im,
    const ushort* __restrict__ b1swz, const ushort* __restrict__ b2swz,
    const float* __restrict__ b1_re, const float* __restrict__ b1_im,
    const float* __restrict__ b2_re, const float* __restrict__ b2_im,
    float* __restrict__ out) {
  __shared__ ushort xlds[64][256];
  __shared__ ushort actlds[64][136];
  const int tid = threadIdx.x;
  const int wave = tid >> 6, lane = tid & 63;
  const int lrow = lane & 15, lgrp = lane >> 4;
  const int blk = blockIdx.x;        // 2048 = bt*64 + h
  const int bt = blk >> 6;
  const int hw0 = (blk & 63) * 64;
  const size_t base = (size_t)bt * D_ * HW_ + hw0;

  #pragma unroll
  for (int i = 0; i < 8; ++i) {
    const int q = i * 4 + wave;        // d-quad 0..31
    const size_t g = base + (size_t)(q * 4) * HW_ + lane;
    uint4 u;
    u.x = cvt_pk(x3_re[g],           x3_im[g]);
    u.y = cvt_pk(x3_re[g + HW_],     x3_im[g + HW_]);
    u.z = cvt_pk(x3_re[g + 2 * HW_], x3_im[g + 2 * HW_]);
    u.w = cvt_pk(x3_re[g + 3 * HW_], x3_im[g + 3 * HW_]);
    *(uint4*)&xlds[lane][(q ^ (lane & 7)) << 3] = u;
  }
  __syncthreads();

  f32x4 dacc[4][4];
  #pragma unroll
  for (int rt = 0; rt < 4; ++rt)
    #pragma unroll
    for (int st = 0; st < 4; ++st) dacc[rt][st] = (f32x4)0.f;

  uint* act32 = (uint*)&actlds[0][0];
  const int swz = lrow & 7;

  for (int chunk = 0; chunk < 8; ++chunk) {
    f32x4 hacc[2][4];
    #pragma unroll
    for (int ntl = 0; ntl < 2; ++ntl)
      #pragma unroll
      for (int st = 0; st < 4; ++st) hacc[ntl][st] = (f32x4)0.f;

    #pragma unroll
    for (int ks = 0; ks < 8; ++ks) {
      bf16x8 bfr[4];
      #pragma unroll
      for (int st = 0; st < 4; ++st)
        bfr[st] = *(const bf16x8*)&xlds[st * 16 + lrow][(((ks * 4 + lgrp) ^ swz)) << 3];
      #pragma unroll
      for (int ntl = 0; ntl < 2; ++ntl) {
        const int ntile = chunk * 8 + wave * 2 + ntl;
        const bf16x8 afr = ((const bf16x8*)b1swz)[(ntile * 8 + ks) * 64 + lane];
        #pragma unroll
        for (int st = 0; st < 4; ++st)
          hacc[ntl][st] = __builtin_amdgcn_mfma_f32_16x16x32_bf16(
              afr, bfr[st], hacc[ntl][st], 0, 0, 0);
      }
    }
    __syncthreads();   // prev chunk's GEMM2 done reading actlds
    #pragma unroll
    for (int ntl = 0; ntl < 2; ++ntl) {
      const int nlocal0 = (wave * 2 + ntl) * 16 + lgrp * 4;
      const int ng0 = chunk * 128 + nlocal0;
      #pragma unroll
      for (int st = 0; st < 4; ++st) {
        float gv[4];
        #pragma unroll
        for (int j = 0; j < 4; ++j) {
          const int ng = ng0 + j;
          const float bias = (ng < 512) ? b1_re[ng] : b1_im[ng - 512];
          gv[j] = gelu_fast(hacc[ntl][st][j] + bias);
        }
        const int site = st * 16 + lrow;
        act32[site * 68 + (nlocal0 >> 1)] = cvt_pk(gv[0], gv[1]);
        act32[site * 68 + (nlocal0 >> 1) + 1] = cvt_pk(gv[2], gv[3]);
      }
    }
    __syncthreads();
    #pragma unroll
    for (int ks2 = 0; ks2 < 4; ++ks2) {
      bf16x8 bfr[4];
      #pragma unroll
      for (int st = 0; st < 4; ++st)
        bfr[st] = *(const bf16x8*)&actlds[st * 16 + lrow][ks2 * 32 + lgrp * 8];
      const int kc = chunk * 4 + ks2;
      #pragma unroll
      for (int rt = 0; rt < 4; ++rt) {
        const int rowtile = wave * 4 + rt;
        const bf16x8 afr = ((const bf16x8*)b2swz)[(rowtile * 32 + kc) * 64 + lane];
        #pragma unroll
        for (int st = 0; st < 4; ++st)
          dacc[rt][st] = __builtin_amdgcn_mfma_f32_16x16x32_bf16(
              afr, bfr[st], dacc[rt][st], 0, 0, 0);
      }
    }
  }

  #pragma unroll
  for (int rt = 0; rt < 4; ++rt) {
    #pragma unroll
    for (int j = 0; j < 4; ++j) {
      const int n2 = (wave * 4 + rt) * 16 + lgrp * 4 + j;
      const int d = n2 & 127;
      const int c = n2 >> 7;
      const float bias2 = c ? b2_im[d] : b2_re[d];
      const float* rsrc = c ? x3_im : x3_re;
      #pragma unroll
      for (int st = 0; st < 4; ++st) {
        const size_t idx = (size_t)(bt * D_ + d) * HW_ + hw0 + st * 16 + lrow;
        out[idx * 2 + c] = rsrc[idx] + dacc[rt][st][j] + bias2;
      }
    }
  }
}

// ---------------- host launcher ----------------

extern "C" void kernel_launch(void* const* d_in, const int* in_sizes, int n_in,
                              void* d_out, int out_size, void* d_ws, size_t ws_size,
                              hipStream_t stream) {
  const float* x_re   = (const float*)d_in[0];
  const float* x_im   = (const float*)d_in[1];
  const float* dt     = (const float*)d_in[2];
  const float* ln_s_g = (const float*)d_in[3];
  const float* ln_s_b = (const float*)d_in[4];
  const float* ln_t_g = (const float*)d_in[5];
  const float* ln_t_b = (const float*)d_in[6];
  const float* metric = (const float*)d_in[7];
  const float* conv_w = (const float*)d_in[8];
  const float* conv_b = (const float*)d_in[9];
  const float* nu     = (const float*)d_in[10];
  const float* theta  = (const float*)d_in[11];
  const float* enc_re = (const float*)d_in[12];
  const float* enc_im = (const float*)d_in[13];
  const float* dec_re = (const float*)d_in[14];
  const float* dec_im = (const float*)d_in[15];
  const float* src_g  = (const float*)d_in[16];
  const float* w1_re  = (const float*)d_in[17];
  const float* w1_im  = (const float*)d_in[18];
  const float* b1_re  = (const float*)d_in[19];
  const float* b1_im  = (const float*)d_in[20];
  const float* w2_re  = (const float*)d_in[21];
  const float* w2_im  = (const float*)d_in[22];
  const float* b2_re  = (const float*)d_in[23];
  const float* b2_im  = (const float*)d_in[24];
  float* out = (float*)d_out;
  float* ws = (float*)d_ws;

  // workspace layout
  float* wt   = ws;                          // weight-prep region
  float* bufA = ws + WT_FLOATS;
  float* u_re = bufA;
  float* u_im = bufA + PLANE_;
  ushort* wt16  = (ushort*)wt;
  ushort* cwswz = wt16;                      // 589,824 bf16 (conv frags, dead after conv)
  ushort* b1swz = wt16;                      // 262,144 bf16
  ushort* b2swz = wt16 + 262144;             // 262,144 bf16
  ushort* encswz = wt16 + 524288;            // 65,536 bf16
  ushort* decswz = wt16 + 589824;            // 32,768 bf16
  float*  evec   = (float*)(wt16 + 622592);  // 256 f32
  float*  cvec   = evec + 256;               // 256 f32
  float4* decay  = (float4*)(cvec + 256);    // 4096 float4 (64 KB)
  ushort* xri_bf = (ushort*)bufA;            // bf16 LN output (dead after conv)

  const size_t needA = (size_t)(WT_FLOATS + 2 * PLANE_ + 2 * PLANE_) * 4;
  const bool planA = ws_size >= needA;
  float *x2_re, *x2_im, *ffn_out;
  if (planA) {
    x2_re = bufA + 2 * (size_t)PLANE_;
    x2_im = x2_re + PLANE_;
    ffn_out = out;
  } else {
    x2_re = out;
    x2_im = out + PLANE_;
    ffn_out = bufA;
  }

  k_prep_conv<<<288, 256, 0, stream>>>(conv_w, cwswz);
  k_prep_decay<<<16, 256, 0, stream>>>(dt, nu, theta, decay);
  k_spatial_ln<<<BT_ * H_, 256, 0, stream>>>(x_re, x_im, ln_s_g, ln_s_b, metric, xri_bf);
  k_conv_mfma<<<BT_ * 32, 512, 0, stream>>>(xri_bf, cwswz, conv_b, x_re, x_im,
                                            x2_re, x2_im);
  // cwswz dead after conv; overwrite region with GEMM weights
  k_prep_b1<<<128, 256, 0, stream>>>(w1_re, w1_im, b1swz);
  k_prep_b2<<<128, 256, 0, stream>>>(w2_re, w2_im, b2swz);
  k_prep_enc<<<32, 256, 0, stream>>>(enc_re, enc_im, ln_t_g, encswz);
  k_prep_encvec<<<1, 256, 0, stream>>>(enc_re, enc_im, ln_t_g, ln_t_b, evec, cvec);
  k_prep_dec<<<16, 256, 0, stream>>>(dec_re, dec_im, decswz);
  k_temporal_mfma<<<B_ * T_ * H_, 256, 0, stream>>>(x2_re, x2_im, encswz,
                                                    evec, cvec, decay, src_g,
                                                    u_re, u_im);
  k_scan<<<ND_ / 256, 256, 0, stream>>>(u_re, u_im, decay);
  k_decode_mfma<<<B_ * T_ * H_, 256, 0, stream>>>(u_re, u_im, decswz, x2_re);
  k_ffn_mfma<<<BT_ * H_, 256, 0, stream>>>(x2_re, x2_im, b1swz, b2swz,
                                           b1_re, b1_im, b2_re, b2_im, ffn_out);
  if (!planA) {
    hipMemcpyAsync(d_out, ffn_out, (size_t)2 * PLANE_ * sizeof(float),
                   hipMemcpyDeviceToDevice, stream);
  }
}

// Round 6
// 892.568 us; speedup vs baseline: 6.8430x; 1.0234x over previous
//
#include <hip/hip_runtime.h>
#include <hip/hip_bf16.h>
#include <stdint.h>

#define B_   2
#define T_   16
#define D_   128
#define D2_  256
#define H_   64
#define W_   64
#define HW_  4096
#define BT_  32
#define N_   8192
#define ND_  1048576           // N_*D_
#define PLANE_ 16777216        // B*T*D*H*W  (one of re/im)
#define WT_FLOATS 589824       // 256*256*9

typedef short bf16x8 __attribute__((ext_vector_type(8)));
typedef float f32x4 __attribute__((ext_vector_type(4)));
typedef unsigned int uint;
typedef unsigned short ushort;

// ---------------- device helpers ----------------

__device__ __forceinline__ float softplus_f(float x) {
  return fmaxf(x, 0.0f) + log1pf(expf(-fabsf(x)));
}

// gelu(tanh approx) = x*(1 - 1/(exp(2*z)+1)), z = sqrt(2/pi)*(x+0.044715 x^3)
__device__ __forceinline__ float gelu_fast(float x) {
  const float Ac = 2.3022082963f;   // 2*sqrt(2/pi)*log2(e)
  const float Bc = 0.1029437f;      // Ac*0.044715
  float t = x * x;
  float z = x * fmaf(Bc, t, Ac);
  float e = __builtin_amdgcn_exp2f(z);
  float r = __builtin_amdgcn_rcpf(e + 1.0f);
  return fmaf(-x, r, x);
}

__device__ __forceinline__ float tanh_fast(float x) {
  float e = __builtin_amdgcn_exp2f(x * 2.8853900818f);  // 2*log2(e)
  float r = __builtin_amdgcn_rcpf(e + 1.0f);
  return fmaf(-2.0f, r, 1.0f);
}

__device__ __forceinline__ ushort f2bf(float f) {
  uint u = __float_as_uint(f);
  uint r = (u + 0x7fffu + ((u >> 16) & 1u)) >> 16;   // RNE
  return (ushort)r;
}

__device__ __forceinline__ uint cvt_pk(float a, float b) {
  __hip_bfloat162 h = __float22bfloat162_rn(make_float2(a, b));
  return *reinterpret_cast<uint*>(&h);
}

// ---------------- kernel 1: spatial complex LN + metric scale -> xri bf16 [BT][256][H][W] ----------------

__global__ __launch_bounds__(256) void k_spatial_ln(
    const float* __restrict__ x_re, const float* __restrict__ x_im,
    const float* __restrict__ g, const float* __restrict__ bb,
    const float* __restrict__ metric, ushort* __restrict__ xri) {
  __shared__ float vals[256][64];
  __shared__ float red1[4][64];
  __shared__ float red2[4][64];
  __shared__ float mean_s[64];
  __shared__ float rstd_s[64];
  const int blk = blockIdx.x;      // bt*64 + h
  const int bt = blk >> 6;
  const int h = blk & 63;
  const int tid = threadIdx.x;
  const int w = tid & 63, q = tid >> 6;

  float s1 = 0.f, s2 = 0.f;
  #pragma unroll 4
  for (int i = 0; i < 64; ++i) {
    const int c = i * 4 + q;
    const int d = c & 127;
    const float* src = (c < 128) ? x_re : x_im;
    float v = src[((size_t)bt * D_ + d) * HW_ + h * W_ + w];
    vals[c][w] = v;
    s1 += v; s2 += v * v;
  }
  red1[q][w] = s1; red2[q][w] = s2;
  __syncthreads();
  if (tid < 64) {
    float m = red1[0][tid] + red1[1][tid] + red1[2][tid] + red1[3][tid];
    float ss = red2[0][tid] + red2[1][tid] + red2[2][tid] + red2[3][tid];
    m *= (1.f / 256.f);
    float var = ss * (1.f / 256.f) - m * m;
    mean_s[tid] = m;
    rstd_s[tid] = rsqrtf(var + 1e-5f);
  }
  __syncthreads();
  const float m = mean_s[w], rs = rstd_s[w];
  #pragma unroll 4
  for (int i = 0; i < 64; ++i) {
    const int c = i * 4 + q;
    float v = (vals[c][w] - m) * rs * g[c] + bb[c];
    v *= metric[(size_t)c * HW_ + h * W_ + w];
    xri[((size_t)bt * D2_ + c) * HW_ + h * W_ + w] = f2bf(v);
  }
}

// ---------------- conv weight prep: fragment-order bf16 (K = ci straight) ----------------

__global__ __launch_bounds__(256) void k_prep_conv(
    const float* __restrict__ wg, ushort* __restrict__ cwswz) {
  const int t = blockIdx.x * 256 + threadIdx.x;   // 0..73727
  if (t >= 73728) return;
  const int lane = t & 63;
  const int nt = (t >> 6) & 15;
  const int ks = (t >> 10) & 7;
  const int kk = t >> 13;                         // 0..8
  const int co = nt * 16 + (lane & 15);
  const int ci0 = ks * 32 + (lane >> 4) * 8;
  ushort v[8];
  #pragma unroll
  for (int e = 0; e < 8; ++e)
    v[e] = f2bf(wg[((size_t)co * 256 + ci0 + e) * 9 + kk]);
  uint4 u;
  u.x = (uint)v[0] | ((uint)v[1] << 16);
  u.y = (uint)v[2] | ((uint)v[3] << 16);
  u.z = (uint)v[4] | ((uint)v[5] << 16);
  u.w = (uint)v[6] | ((uint)v[7] << 16);
  ((uint4*)cwswz)[t] = u;
}

// ---------------- kernel 2: 3x3 conv via bf16 MFMA (implicit GEMM) ----------------
// LDS rows 512B (256 bf16 ci), XOR-swizzled 16B units: unit' = unit ^ (row&7).
// A-fragments (weights) register-prefetched one ks-step ahead.

__global__ __launch_bounds__(512, 1) void k_conv_mfma(
    const ushort* __restrict__ xri, const ushort* __restrict__ cwswz,
    const float* __restrict__ bias,
    const float* __restrict__ x_re, const float* __restrict__ x_im,
    float* __restrict__ x2_re, float* __restrict__ x2_im) {
  __shared__ ushort xb[67584];   // 4*66 rows * 256 bf16 = 132 KB
  const int tid = threadIdx.x;
  const int wave = tid >> 6, lane = tid & 63;
  const int lrow = lane & 15, lgrp = lane >> 4;
  const int blk = blockIdx.x;         // 1024 = bt*32 + hp
  const int bt = blk >> 5;
  const int h0 = (blk & 31) * 2;

  uint* xb32 = (uint*)xb;
  // zero halo rows (row_in_block 0 and 65 of each j)
  {
    const int r = tid >> 7;           // 0..3
    const int p = tid & 127;          // dword
    xb32[(r * 66 + 0) * 128 + p] = 0;
    xb32[(r * 66 + 65) * 128 + p] = 0;
  }
  // main staging: 16 iters, b128 swizzled writes (conflict-free)
  #pragma unroll
  for (int i = 0; i < 16; ++i) {
    const int idx = i * 512 + tid;    // 0..8191
    const int j = idx >> 11;          // h row 0..3
    const int rem = idx & 2047;
    const int q = rem >> 6;           // ci-quad 0..31
    const int w = rem & 63;
    const int hh = h0 + j - 1;
    uint4 u = {0u, 0u, 0u, 0u};
    if (hh >= 0 && hh < 64) {
      const ushort* src = &xri[((size_t)bt * D2_ + q * 8) * HW_ + hh * W_ + w];
      #pragma unroll
      for (int e = 0; e < 4; ++e) {
        uint lo = src[(size_t)(2 * e) * HW_];
        uint hi = src[(size_t)(2 * e + 1) * HW_];
        ((uint*)&u)[e] = lo | (hi << 16);
      }
    }
    const int row = j * 66 + 1 + w;
    *(uint4*)&xb[row * 256 + ((q ^ (row & 7)) << 3)] = u;
  }
  __syncthreads();

  const int cw = wave & 3;
  const int sg = wave >> 2;
  f32x4 acc[4][4];
  #pragma unroll
  for (int j = 0; j < 4; ++j)
    #pragma unroll
    for (int i = 0; i < 4; ++i) acc[j][i] = (f32x4)0.f;

  for (int kh = 0; kh < 3; ++kh) {
    const int rowb = (sg + kh) * 66;
    for (int kw = 0; kw < 3; ++kw) {
      const int kk = kh * 3 + kw;
      // preload ks=0 A-frags
      bf16x8 ac[4], an[4];
      {
        const int fbase = ((kk * 8 + 0) * 16 + cw * 4) * 64 + lane;
        #pragma unroll
        for (int j = 0; j < 4; ++j)
          ac[j] = ((const bf16x8*)cwswz)[fbase + j * 64];
      }
      #pragma unroll
      for (int ks = 0; ks < 8; ++ks) {
        if (ks < 7) {
          const int fbase = ((kk * 8 + ks + 1) * 16 + cw * 4) * 64 + lane;
          #pragma unroll
          for (int j = 0; j < 4; ++j)
            an[j] = ((const bf16x8*)cwswz)[fbase + j * 64];
        }
        bf16x8 bfr[4];
        #pragma unroll
        for (int i = 0; i < 4; ++i) {
          const int row = rowb + i * 16 + lrow + kw;
          bfr[i] = *(const bf16x8*)&xb[row * 256 + (((ks * 4 + lgrp) ^ (row & 7)) << 3)];
        }
        #pragma unroll
        for (int j = 0; j < 4; ++j) {
          #pragma unroll
          for (int i = 0; i < 4; ++i)
            acc[j][i] = __builtin_amdgcn_mfma_f32_16x16x32_bf16(
                ac[j], bfr[i], acc[j][i], 0, 0, 0);
        }
        #pragma unroll
        for (int j = 0; j < 4; ++j) ac[j] = an[j];
      }
    }
  }

  #pragma unroll
  for (int j = 0; j < 4; ++j) {
    #pragma unroll
    for (int jj = 0; jj < 4; ++jj) {
      const int co = (cw * 4 + j) * 16 + lgrp * 4 + jj;
      const int d = co & 127;
      const float bv = bias[co];
      const float* rsrc = (co < 128) ? x_re : x_im;
      float* dst = (co < 128) ? x2_re : x2_im;
      const size_t rowoff = ((size_t)bt * D_ + d) * HW_ + (h0 + sg) * W_;
      #pragma unroll
      for (int i = 0; i < 4; ++i) {
        const int w = i * 16 + lrow;
        dst[rowoff + w] = acc[j][i][jj] + bv + rsrc[rowoff + w];
      }
    }
  }
}

// ---------------- decay/forcing table: [BT][128] float4 {decay_re, decay_im, f_re, f_im} ----------------

__global__ __launch_bounds__(256) void k_prep_decay(
    const float* __restrict__ dt, const float* __restrict__ nu,
    const float* __restrict__ theta, float4* __restrict__ decay) {
  const int idx = blockIdx.x * 256 + threadIdx.x;  // 0..4095
  const int d = idx & 127;
  const int bt = idx >> 7;
  const float dtv = dt[bt];
  const float lr = -softplus_f(nu[d]);
  const float li = theta[d];
  float s, c;
  sincosf(li * dtv, &s, &c);
  const float er = expf(lr * dtv);
  const float ar = er * c, ai = er * s;
  const float den = lr * lr + li * li;
  const float nr = ar - 1.f, ni = ai;
  float4 v;
  v.x = ar; v.y = ai;
  v.z = (nr * lr + ni * li) / den;
  v.w = (ni * lr - nr * li) / den;
  decay[idx] = v;
}

// ---------------- temporal-encode weight prep (K rows permuted to interleaved re/im) ----------------

__global__ __launch_bounds__(256) void k_prep_enc(
    const float* __restrict__ enc_re, const float* __restrict__ enc_im,
    const float* __restrict__ g, ushort* __restrict__ encswz) {
  const int t = blockIdx.x * 256 + threadIdx.x;   // 0..8191
  const int lane = t & 63;
  const int ks = (t >> 6) & 7;
  const int ntile = t >> 9;
  const int n = ntile * 16 + (lane & 15);
  const int k0 = ks * 32 + (lane >> 4) * 8;
  ushort v[8];
  #pragma unroll
  for (int e = 0; e < 8; ++e) {
    const int kp = k0 + e;
    const int k = (kp >> 1) | ((kp & 1) << 7);   // physical -> logical
    float val;
    if (k < 128) {
      val = (n < 128) ? enc_re[k * 128 + n] : enc_im[k * 128 + (n - 128)];
    } else {
      const int kk = k - 128;
      val = (n < 128) ? -enc_im[kk * 128 + n] : enc_re[kk * 128 + (n - 128)];
    }
    v[e] = f2bf(val * g[k]);
  }
  uint4 u;
  u.x = (uint)v[0] | ((uint)v[1] << 16);
  u.y = (uint)v[2] | ((uint)v[3] << 16);
  u.z = (uint)v[4] | ((uint)v[5] << 16);
  u.w = (uint)v[6] | ((uint)v[7] << 16);
  ((uint4*)encswz)[t] = u;
}

__global__ __launch_bounds__(256) void k_prep_encvec(
    const float* __restrict__ enc_re, const float* __restrict__ enc_im,
    const float* __restrict__ g, const float* __restrict__ bb,
    float* __restrict__ evec, float* __restrict__ cvec) {
  const int n = threadIdx.x;   // one block of 256
  float se = 0.f, sc = 0.f;
  for (int k = 0; k < 256; ++k) {
    float ep;
    if (k < 128) {
      ep = (n < 128) ? enc_re[k * 128 + n] : enc_im[k * 128 + (n - 128)];
    } else {
      const int kk = k - 128;
      ep = (n < 128) ? -enc_im[kk * 128 + n] : enc_re[kk * 128 + (n - 128)];
    }
    se = fmaf(g[k], ep, se);
    sc = fmaf(bb[k], ep, sc);
  }
  evec[n] = se;
  cvec[n] = sc;
}

__global__ __launch_bounds__(256) void k_prep_dec(
    const float* __restrict__ dec_re, const float* __restrict__ dec_im,
    ushort* __restrict__ decswz) {
  const int t = blockIdx.x * 256 + threadIdx.x;   // 0..4095
  const int lane = t & 63;
  const int ks = (t >> 6) & 7;
  const int ntile = t >> 9;
  const int n = ntile * 16 + (lane & 15);
  const int k0 = ks * 32 + (lane >> 4) * 8;
  ushort v[8];
  #pragma unroll
  for (int e = 0; e < 8; ++e) {
    const int kp = k0 + e;
    const int k = (kp >> 1) | ((kp & 1) << 7);
    float val = (k < 128) ? dec_re[k * 128 + n] : -dec_im[(k - 128) * 128 + n];
    v[e] = f2bf(val);
  }
  uint4 u;
  u.x = (uint)v[0] | ((uint)v[1] << 16);
  u.y = (uint)v[2] | ((uint)v[3] << 16);
  u.z = (uint)v[4] | ((uint)v[5] << 16);
  u.w = (uint)v[6] | ((uint)v[7] << 16);
  ((uint4*)decswz)[t] = u;
}

// ---------------- kernel 3: temporal LN (folded) + encode MFMA + src + ZOH -> u [T][D][N] ----------------

__global__ __launch_bounds__(256, 2) void k_temporal_mfma(
    const float* __restrict__ x2_re, const float* __restrict__ x2_im,
    const ushort* __restrict__ encswz,
    const float* __restrict__ evec, const float* __restrict__ cvec,
    const float4* __restrict__ decay,
    const float* __restrict__ src_gain,
    float* __restrict__ u_re, float* __restrict__ u_im) {
  __shared__ ushort xlds[64][256];
  __shared__ float red1[4][64], red2[4][64];
  __shared__ float mean_s[64], rstd_s[64];
  __shared__ float fre_s[128], fim_s[128], gain_s[128];
  const int tid = threadIdx.x;
  const int wave = tid >> 6, lane = tid & 63;
  const int lrow = lane & 15, lgrp = lane >> 4;
  const int blk = blockIdx.x;          // ((b*16)+t)*64 + h
  const int h = blk & 63;
  const int t = (blk >> 6) & 15;
  const int b = blk >> 10;
  const int bt = b * T_ + t;
  const size_t base = (size_t)bt * D_ * HW_ + h * W_;

  // stage RAW x2 -> bf16 LDS (interleaved re/im, swizzled b128 writes) + LN sums
  float s1 = 0.f, s2 = 0.f;
  #pragma unroll
  for (int i = 0; i < 8; ++i) {
    const int q = i * 4 + wave;        // d-quad 0..31
    const size_t g = base + (size_t)(q * 4) * HW_ + lane;
    float r0 = x2_re[g],           i0 = x2_im[g];
    float r1 = x2_re[g + HW_],     i1 = x2_im[g + HW_];
    float r2 = x2_re[g + 2 * HW_], i2 = x2_im[g + 2 * HW_];
    float r3 = x2_re[g + 3 * HW_], i3 = x2_im[g + 3 * HW_];
    uint4 u;
    u.x = cvt_pk(r0, i0); u.y = cvt_pk(r1, i1);
    u.z = cvt_pk(r2, i2); u.w = cvt_pk(r3, i3);
    *(uint4*)&xlds[lane][(q ^ (lane & 7)) << 3] = u;
    s1 += (r0 + r1 + r2 + r3) + (i0 + i1 + i2 + i3);
    s2 += r0 * r0 + r1 * r1 + r2 * r2 + r3 * r3
        + i0 * i0 + i1 * i1 + i2 * i2 + i3 * i3;
  }
  red1[wave][lane] = s1;
  red2[wave][lane] = s2;
  __syncthreads();
  if (tid < 64) {
    float m = red1[0][tid] + red1[1][tid] + red1[2][tid] + red1[3][tid];
    float ss = red2[0][tid] + red2[1][tid] + red2[2][tid] + red2[3][tid];
    m *= (1.f / 256.f);
    float var = ss * (1.f / 256.f) - m * m;
    mean_s[tid] = m;
    rstd_s[tid] = rsqrtf(var + 1e-5f);
  }
  if (tid < 128) {
    const float4 dc = decay[bt * 128 + tid];
    fre_s[tid] = dc.z;
    fim_s[tid] = dc.w;
    gain_s[tid] = src_gain[tid];
  }
  __syncthreads();

  f32x4 acc[4][4];
  #pragma unroll
  for (int ntl = 0; ntl < 4; ++ntl)
    #pragma unroll
    for (int st = 0; st < 4; ++st) acc[ntl][st] = (f32x4)0.f;

  const int swz = lrow & 7;   // site&7 is st-independent (st*16 ≡ 0 mod 8)
  const int ntb[4] = {wave * 2, wave * 2 + 1, wave * 2 + 8, wave * 2 + 9};
  #pragma unroll
  for (int ks = 0; ks < 8; ++ks) {
    bf16x8 bfr[4];
    #pragma unroll
    for (int st = 0; st < 4; ++st)
      bfr[st] = *(const bf16x8*)&xlds[st * 16 + lrow][(((ks * 4 + lgrp) ^ swz)) << 3];
    #pragma unroll
    for (int ntl = 0; ntl < 4; ++ntl) {
      const bf16x8 afr = ((const bf16x8*)encswz)[(ntb[ntl] * 8 + ks) * 64 + lane];
      #pragma unroll
      for (int st = 0; st < 4; ++st)
        acc[ntl][st] = __builtin_amdgcn_mfma_f32_16x16x32_bf16(
            afr, bfr[st], acc[ntl][st], 0, 0, 0);
    }
  }

  const int nbase = (b * 64 + h) * 64;
  #pragma unroll
  for (int ntl = 0; ntl < 2; ++ntl) {
    const int d0 = ntb[ntl] * 16 + lgrp * 4;    // <128
    #pragma unroll
    for (int st = 0; st < 4; ++st) {
      const int site = st * 16 + lrow;
      const float m = mean_s[site], rs = rstd_s[site];
      #pragma unroll
      for (int j = 0; j < 4; ++j) {
        const int d = d0 + j;
        const float xer = rs * acc[ntl][st][j] - rs * m * evec[d] + cvec[d];
        const float xei = rs * acc[ntl + 2][st][j] - rs * m * evec[d + 128] + cvec[d + 128];
        const float sr = tanh_fast(xer) * gain_s[d];
        const float si = tanh_fast(xei) * gain_s[d];
        const float vr = xer + sr, vi = xei + si;
        const float ur = vr * fre_s[d] - vi * fim_s[d];
        const float ui = vr * fim_s[d] + vi * fre_s[d];
        const size_t off = (size_t)t * ND_ + (size_t)d * N_ + nbase + site;
        u_re[off] = ur;
        u_im[off] = ui;
      }
    }
  }
}

// ---------------- kernel 4: sequential scan over T (in place, u layout [T][D][N]) ----------------

__global__ __launch_bounds__(256) void k_scan(
    float* __restrict__ u_re, float* __restrict__ u_im,
    const float4* __restrict__ decay) {
  const int idx = blockIdx.x * 256 + threadIdx.x;   // d*N + n
  const int n = idx & 8191;
  const int d = idx >> 13;
  const int b = n >> 12;
  float hr = 0.f, hi = 0.f;
  for (int t = 0; t < 16; ++t) {
    const float4 dc = decay[(b * 16 + t) * 128 + d];   // wave-uniform
    const size_t off = (size_t)t * ND_ + idx;
    const float ur = u_re[off], ui = u_im[off];
    const float nr = fmaf(dc.x, hr, fmaf(-dc.y, hi, ur));
    const float ni = fmaf(dc.x, hi, fmaf(dc.y, hr, ui));
    hr = nr; hi = ni;
    u_re[off] = hr;
    u_im[off] = hi;
  }
}

// ---------------- kernel 5: decode via MFMA (real part) + residual (in place on x2_re) ----------------

__global__ __launch_bounds__(256, 2) void k_decode_mfma(
    const float* __restrict__ h_re, const float* __restrict__ h_im,
    const ushort* __restrict__ decswz,
    float* __restrict__ x2_re) {
  __shared__ ushort xlds[64][256];
  const int tid = threadIdx.x;
  const int wave = tid >> 6, lane = tid & 63;
  const int lrow = lane & 15, lgrp = lane >> 4;
  const int blk = blockIdx.x;          // ((b*16)+t)*64 + h
  const int h = blk & 63;
  const int t = (blk >> 6) & 15;
  const int b = blk >> 10;
  const int bt = b * T_ + t;
  const int nbase = (b * 64 + h) * 64;

  #pragma unroll
  for (int i = 0; i < 8; ++i) {
    const int q = i * 4 + wave;        // d-quad
    const size_t o = (size_t)t * ND_ + (size_t)(q * 4) * N_ + nbase + lane;
    uint4 u;
    u.x = cvt_pk(h_re[o],          h_im[o]);
    u.y = cvt_pk(h_re[o + N_],     h_im[o + N_]);
    u.z = cvt_pk(h_re[o + 2 * N_], h_im[o + 2 * N_]);
    u.w = cvt_pk(h_re[o + 3 * N_], h_im[o + 3 * N_]);
    *(uint4*)&xlds[lane][(q ^ (lane & 7)) << 3] = u;
  }
  __syncthreads();

  f32x4 acc[2][4];
  #pragma unroll
  for (int ntl = 0; ntl < 2; ++ntl)
    #pragma unroll
    for (int st = 0; st < 4; ++st) acc[ntl][st] = (f32x4)0.f;

  const int swz = lrow & 7;
  #pragma unroll
  for (int ks = 0; ks < 8; ++ks) {
    bf16x8 bfr[4];
    #pragma unroll
    for (int st = 0; st < 4; ++st)
      bfr[st] = *(const bf16x8*)&xlds[st * 16 + lrow][(((ks * 4 + lgrp) ^ swz)) << 3];
    #pragma unroll
    for (int ntl = 0; ntl < 2; ++ntl) {
      const int ntile = wave * 2 + ntl;
      const bf16x8 afr = ((const bf16x8*)decswz)[(ntile * 8 + ks) * 64 + lane];
      #pragma unroll
      for (int st = 0; st < 4; ++st)
        acc[ntl][st] = __builtin_amdgcn_mfma_f32_16x16x32_bf16(
            afr, bfr[st], acc[ntl][st], 0, 0, 0);
    }
  }

  #pragma unroll
  for (int ntl = 0; ntl < 2; ++ntl) {
    #pragma unroll
    for (int j = 0; j < 4; ++j) {
      const int d = (wave * 2 + ntl) * 16 + lgrp * 4 + j;
      const size_t rowoff = ((size_t)bt * D_ + d) * HW_ + h * W_;
      #pragma unroll
      for (int st = 0; st < 4; ++st) {
        const int site = st * 16 + lrow;
        x2_re[rowoff + site] += acc[ntl][st][j];
      }
    }
  }
}

// ---------------- FFN weight prep ----------------

__global__ __launch_bounds__(256) void k_prep_b1(
    const float* __restrict__ w1_re, const float* __restrict__ w1_im,
    ushort* __restrict__ b1swz) {
  const int t = blockIdx.x * 256 + threadIdx.x;   // 0..32767
  const int lane = t & 63;
  const int ks = (t >> 6) & 7;
  const int ntile = t >> 9;
  const int n = ntile * 16 + (lane & 15);
  const int k0 = ks * 32 + (lane >> 4) * 8;
  ushort v[8];
  #pragma unroll
  for (int e = 0; e < 8; ++e) {
    const int kp = k0 + e;
    const int k = (kp >> 1) | ((kp & 1) << 7);   // physical -> logical
    float val;
    if (k < 128) {
      val = (n < 512) ? w1_re[k * 512 + n] : w1_im[k * 512 + (n - 512)];
    } else {
      const int kk = k - 128;
      val = (n < 512) ? -w1_im[kk * 512 + n] : w1_re[kk * 512 + (n - 512)];
    }
    v[e] = f2bf(val);
  }
  uint4 u;
  u.x = (uint)v[0] | ((uint)v[1] << 16);
  u.y = (uint)v[2] | ((uint)v[3] << 16);
  u.z = (uint)v[4] | ((uint)v[5] << 16);
  u.w = (uint)v[6] | ((uint)v[7] << 16);
  ((uint4*)b1swz)[t] = u;
}

__global__ __launch_bounds__(256) void k_prep_b2(
    const float* __restrict__ w2_re, const float* __restrict__ w2_im,
    ushort* __restrict__ b2swz) {
  const int t = blockIdx.x * 256 + threadIdx.x;   // 0..32767
  const int lane = t & 63;
  const int kc = (t >> 6) & 31;
  const int rowtile = t >> 11;
  const int n2 = rowtile * 16 + (lane & 15);
  const int k0 = kc * 32 + (lane >> 4) * 8;
  ushort v[8];
  #pragma unroll
  for (int e = 0; e < 8; ++e) {
    const int k = k0 + e;                       // act layout unchanged: no permute
    float val;
    if (k < 512) {
      val = (n2 < 128) ? w2_re[k * 128 + n2] : w2_im[k * 128 + (n2 - 128)];
    } else {
      const int kk = k - 512;
      val = (n2 < 128) ? -w2_im[kk * 128 + n2] : w2_re[kk * 128 + (n2 - 128)];
    }
    v[e] = f2bf(val);
  }
  uint4 u;
  u.x = (uint)v[0] | ((uint)v[1] << 16);
  u.y = (uint)v[2] | ((uint)v[3] << 16);
  u.z = (uint)v[4] | ((uint)v[5] << 16);
  u.w = (uint)v[6] | ((uint)v[7] << 16);
  ((uint4*)b2swz)[t] = u;
}

// ---------------- kernel 6: complex FFN via bf16 MFMA ----------------
// Register-prefetched weight fragments (across barriers), act double-buffer,
// ONE barrier per chunk.

__global__ __launch_bounds__(256, 2) void k_ffn_mfma(
    const float* __restrict__ x3_re, const float* __restrict__ x3_im,
    const ushort* __restrict__ b1swz, const ushort* __restrict__ b2swz,
    const float* __restrict__ b1_re, const float* __restrict__ b1_im,
    const float* __restrict__ b2_re, const float* __restrict__ b2_im,
    float* __restrict__ out) {
  __shared__ ushort xlds[64][256];
  __shared__ ushort actlds[2][64][136];
  const int tid = threadIdx.x;
  const int wave = tid >> 6, lane = tid & 63;
  const int lrow = lane & 15, lgrp = lane >> 4;
  const int blk = blockIdx.x;        // 2048 = bt*64 + h
  const int bt = blk >> 6;
  const int hw0 = (blk & 63) * 64;
  const size_t base = (size_t)bt * D_ * HW_ + hw0;
  const bf16x8* b1f = (const bf16x8*)b1swz;
  const bf16x8* b2f = (const bf16x8*)b2swz;

  #pragma unroll
  for (int i = 0; i < 8; ++i) {
    const int q = i * 4 + wave;        // d-quad 0..31
    const size_t g = base + (size_t)(q * 4) * HW_ + lane;
    uint4 u;
    u.x = cvt_pk(x3_re[g],           x3_im[g]);
    u.y = cvt_pk(x3_re[g + HW_],     x3_im[g + HW_]);
    u.z = cvt_pk(x3_re[g + 2 * HW_], x3_im[g + 2 * HW_]);
    u.w = cvt_pk(x3_re[g + 3 * HW_], x3_im[g + 3 * HW_]);
    *(uint4*)&xlds[lane][(q ^ (lane & 7)) << 3] = u;
  }

  // prefetch chunk-0 A-fragments (GEMM1 full; GEMM2 ks2 0-1)
  bf16x8 a1[2][8];
  #pragma unroll
  for (int ntl = 0; ntl < 2; ++ntl)
    #pragma unroll
    for (int ks = 0; ks < 8; ++ks)
      a1[ntl][ks] = b1f[((wave * 2 + ntl) * 8 + ks) * 64 + lane];
  bf16x8 a2[4][2];
  #pragma unroll
  for (int rt = 0; rt < 4; ++rt)
    #pragma unroll
    for (int k2 = 0; k2 < 2; ++k2)
      a2[rt][k2] = b2f[((wave * 4 + rt) * 32 + k2) * 64 + lane];

  __syncthreads();

  f32x4 dacc[4][4];
  #pragma unroll
  for (int rt = 0; rt < 4; ++rt)
    #pragma unroll
    for (int st = 0; st < 4; ++st) dacc[rt][st] = (f32x4)0.f;

  const int swz = lrow & 7;

  for (int chunk = 0; chunk < 8; ++chunk) {
    const int nc = (chunk + 1) & 7;   // next chunk (wraps harmlessly on last iter)

    // ---- GEMM1(chunk): a1 (prefetched) x xlds
    f32x4 hacc[2][4];
    #pragma unroll
    for (int ntl = 0; ntl < 2; ++ntl)
      #pragma unroll
      for (int st = 0; st < 4; ++st) hacc[ntl][st] = (f32x4)0.f;

    #pragma unroll
    for (int ks = 0; ks < 8; ++ks) {
      bf16x8 bfr[4];
      #pragma unroll
      for (int st = 0; st < 4; ++st)
        bfr[st] = *(const bf16x8*)&xlds[st * 16 + lrow][(((ks * 4 + lgrp) ^ swz)) << 3];
      #pragma unroll
      for (int ntl = 0; ntl < 2; ++ntl)
        #pragma unroll
        for (int st = 0; st < 4; ++st)
          hacc[ntl][st] = __builtin_amdgcn_mfma_f32_16x16x32_bf16(
              a1[ntl][ks], bfr[st], hacc[ntl][st], 0, 0, 0);
    }

    // ---- prefetch a1 for next chunk (hidden under gelu + barrier + GEMM2)
    #pragma unroll
    for (int ntl = 0; ntl < 2; ++ntl)
      #pragma unroll
      for (int ks = 0; ks < 8; ++ks)
        a1[ntl][ks] = b1f[((nc * 8 + wave * 2 + ntl) * 8 + ks) * 64 + lane];

    // ---- bias + gelu -> act[chunk&1]
    uint* act32 = (uint*)&actlds[chunk & 1][0][0];
    #pragma unroll
    for (int ntl = 0; ntl < 2; ++ntl) {
      const int nlocal0 = (wave * 2 + ntl) * 16 + lgrp * 4;
      const int ng0 = chunk * 128 + nlocal0;
      #pragma unroll
      for (int st = 0; st < 4; ++st) {
        float gv[4];
        #pragma unroll
        for (int j = 0; j < 4; ++j) {
          const int ng = ng0 + j;
          const float bias = (ng < 512) ? b1_re[ng] : b1_im[ng - 512];
          gv[j] = gelu_fast(hacc[ntl][st][j] + bias);
        }
        const int site = st * 16 + lrow;
        act32[site * 68 + (nlocal0 >> 1)] = cvt_pk(gv[0], gv[1]);
        act32[site * 68 + (nlocal0 >> 1) + 1] = cvt_pk(gv[2], gv[3]);
      }
    }

    // ---- load this chunk's GEMM2 ks2 2-3 frags (hidden under barrier + first-half MFMAs)
    bf16x8 a2b[4][2];
    #pragma unroll
    for (int rt = 0; rt < 4; ++rt)
      #pragma unroll
      for (int k2 = 0; k2 < 2; ++k2)
        a2b[rt][k2] = b2f[((wave * 4 + rt) * 32 + chunk * 4 + 2 + k2) * 64 + lane];

    __syncthreads();   // act[chunk&1] ready; prev GEMM2 long done (one barrier/chunk)

    // ---- GEMM2(chunk): a2/a2b x act[chunk&1]
    const ushort* actb = &actlds[chunk & 1][0][0];
    #pragma unroll
    for (int ks2 = 0; ks2 < 2; ++ks2) {
      bf16x8 bfr[4];
      #pragma unroll
      for (int st = 0; st < 4; ++st)
        bfr[st] = *(const bf16x8*)&actb[(st * 16 + lrow) * 136 + ks2 * 32 + lgrp * 8];
      #pragma unroll
      for (int rt = 0; rt < 4; ++rt)
        #pragma unroll
        for (int st = 0; st < 4; ++st)
          dacc[rt][st] = __builtin_amdgcn_mfma_f32_16x16x32_bf16(
              a2[rt][ks2], bfr[st], dacc[rt][st], 0, 0, 0);
    }
    #pragma unroll
    for (int ks2 = 0; ks2 < 2; ++ks2) {
      bf16x8 bfr[4];
      #pragma unroll
      for (int st = 0; st < 4; ++st)
        bfr[st] = *(const bf16x8*)&actb[(st * 16 + lrow) * 136 + (ks2 + 2) * 32 + lgrp * 8];
      #pragma unroll
      for (int rt = 0; rt < 4; ++rt)
        #pragma unroll
        for (int st = 0; st < 4; ++st)
          dacc[rt][st] = __builtin_amdgcn_mfma_f32_16x16x32_bf16(
              a2b[rt][ks2], bfr[st], dacc[rt][st], 0, 0, 0);
    }

    // ---- prefetch next chunk's GEMM2 ks2 0-1 frags
    #pragma unroll
    for (int rt = 0; rt < 4; ++rt)
      #pragma unroll
      for (int k2 = 0; k2 < 2; ++k2)
        a2[rt][k2] = b2f[((wave * 4 + rt) * 32 + nc * 4 + k2) * 64 + lane];
  }

  #pragma unroll
  for (int rt = 0; rt < 4; ++rt) {
    #pragma unroll
    for (int j = 0; j < 4; ++j) {
      const int n2 = (wave * 4 + rt) * 16 + lgrp * 4 + j;
      const int d = n2 & 127;
      const int c = n2 >> 7;
      const float bias2 = c ? b2_im[d] : b2_re[d];
      const float* rsrc = c ? x3_im : x3_re;
      #pragma unroll
      for (int st = 0; st < 4; ++st) {
        const size_t idx = (size_t)(bt * D_ + d) * HW_ + hw0 + st * 16 + lrow;
        out[idx * 2 + c] = rsrc[idx] + dacc[rt][st][j] + bias2;
      }
    }
  }
}

// ---------------- host launcher ----------------

extern "C" void kernel_launch(void* const* d_in, const int* in_sizes, int n_in,
                              void* d_out, int out_size, void* d_ws, size_t ws_size,
                              hipStream_t stream) {
  const float* x_re   = (const float*)d_in[0];
  const float* x_im   = (const float*)d_in[1];
  const float* dt     = (const float*)d_in[2];
  const float* ln_s_g = (const float*)d_in[3];
  const float* ln_s_b = (const float*)d_in[4];
  const float* ln_t_g = (const float*)d_in[5];
  const float* ln_t_b = (const float*)d_in[6];
  const float* metric = (const float*)d_in[7];
  const float* conv_w = (const float*)d_in[8];
  const float* conv_b = (const float*)d_in[9];
  const float* nu     = (const float*)d_in[10];
  const float* theta  = (const float*)d_in[11];
  const float* enc_re = (const float*)d_in[12];
  const float* enc_im = (const float*)d_in[13];
  const float* dec_re = (const float*)d_in[14];
  const float* dec_im = (const float*)d_in[15];
  const float* src_g  = (const float*)d_in[16];
  const float* w1_re  = (const float*)d_in[17];
  const float* w1_im  = (const float*)d_in[18];
  const float* b1_re  = (const float*)d_in[19];
  const float* b1_im  = (const float*)d_in[20];
  const float* w2_re  = (const float*)d_in[21];
  const float* w2_im  = (const float*)d_in[22];
  const float* b2_re  = (const float*)d_in[23];
  const float* b2_im  = (const float*)d_in[24];
  float* out = (float*)d_out;
  float* ws = (float*)d_ws;

  // workspace layout
  float* wt   = ws;                          // weight-prep region
  float* bufA = ws + WT_FLOATS;
  float* u_re = bufA;
  float* u_im = bufA + PLANE_;
  ushort* wt16  = (ushort*)wt;
  ushort* cwswz = wt16;                      // 589,824 bf16 (conv frags, dead after conv)
  ushort* b1swz = wt16;                      // 262,144 bf16
  ushort* b2swz = wt16 + 262144;             // 262,144 bf16
  ushort* encswz = wt16 + 524288;            // 65,536 bf16
  ushort* decswz = wt16 + 589824;            // 32,768 bf16
  float*  evec   = (float*)(wt16 + 622592);  // 256 f32
  float*  cvec   = evec + 256;               // 256 f32
  float4* decay  = (float4*)(cvec + 256);    // 4096 float4 (64 KB)
  ushort* xri_bf = (ushort*)bufA;            // bf16 LN output (dead after conv)

  const size_t needA = (size_t)(WT_FLOATS + 2 * PLANE_ + 2 * PLANE_) * 4;
  const bool planA = ws_size >= needA;
  float *x2_re, *x2_im, *ffn_out;
  if (planA) {
    x2_re = bufA + 2 * (size_t)PLANE_;
    x2_im = x2_re + PLANE_;
    ffn_out = out;
  } else {
    x2_re = out;
    x2_im = out + PLANE_;
    ffn_out = bufA;
  }

  k_prep_conv<<<288, 256, 0, stream>>>(conv_w, cwswz);
  k_prep_decay<<<16, 256, 0, stream>>>(dt, nu, theta, decay);
  k_spatial_ln<<<BT_ * H_, 256, 0, stream>>>(x_re, x_im, ln_s_g, ln_s_b, metric, xri_bf);
  k_conv_mfma<<<BT_ * 32, 512, 0, stream>>>(xri_bf, cwswz, conv_b, x_re, x_im,
                                            x2_re, x2_im);
  // cwswz dead after conv; overwrite region with GEMM weights
  k_prep_b1<<<128, 256, 0, stream>>>(w1_re, w1_im, b1swz);
  k_prep_b2<<<128, 256, 0, stream>>>(w2_re, w2_im, b2swz);
  k_prep_enc<<<32, 256, 0, stream>>>(enc_re, enc_im, ln_t_g, encswz);
  k_prep_encvec<<<1, 256, 0, stream>>>(enc_re, enc_im, ln_t_g, ln_t_b, evec, cvec);
  k_prep_dec<<<16, 256, 0, stream>>>(dec_re, dec_im, decswz);
  k_temporal_mfma<<<B_ * T_ * H_, 256, 0, stream>>>(x2_re, x2_im, encswz,
                                                    evec, cvec, decay, src_g,
                                                    u_re, u_im);
  k_scan<<<ND_ / 256, 256, 0, stream>>>(u_re, u_im, decay);
  k_decode_mfma<<<B_ * T_ * H_, 256, 0, stream>>>(u_re, u_im, decswz, x2_re);
  k_ffn_mfma<<<BT_ * H_, 256, 0, stream>>>(x2_re, x2_im, b1swz, b2swz,
                                           b1_re, b1_im, b2_re, b2_im, ffn_out);
  if (!planA) {
    hipMemcpyAsync(d_out, ffn_out, (size_t)2 * PLANE_ * sizeof(float),
                   hipMemcpyDeviceToDevice, stream);
  }
}

// Round 7
// 694.132 us; speedup vs baseline: 8.7993x; 1.2859x over previous
//
#include <hip/hip_runtime.h>
#include <hip/hip_bf16.h>
#include <stdint.h>

#define B_   2
#define T_   16
#define D_   128
#define D2_  256
#define H_   64
#define W_   64
#define HW_  4096
#define BT_  32
#define N_   8192
#define ND_  1048576           // N_*D_
#define PLANE_ 16777216        // B*T*D*H*W  (one of re/im)
#define WT_FLOATS 589824       // 256*256*9

typedef short bf16x8 __attribute__((ext_vector_type(8)));
typedef float f32x4 __attribute__((ext_vector_type(4)));
typedef unsigned int uint;
typedef unsigned short ushort;

// ---------------- device helpers ----------------

__device__ __forceinline__ float softplus_f(float x) {
  return fmaxf(x, 0.0f) + log1pf(expf(-fabsf(x)));
}

// gelu(tanh approx) = x*(1 - 1/(exp(2*z)+1)), z = sqrt(2/pi)*(x+0.044715 x^3)
__device__ __forceinline__ float gelu_fast(float x) {
  const float Ac = 2.3022082963f;   // 2*sqrt(2/pi)*log2(e)
  const float Bc = 0.1029437f;      // Ac*0.044715
  float t = x * x;
  float z = x * fmaf(Bc, t, Ac);
  float e = __builtin_amdgcn_exp2f(z);
  float r = __builtin_amdgcn_rcpf(e + 1.0f);
  return fmaf(-x, r, x);
}

__device__ __forceinline__ float tanh_fast(float x) {
  float e = __builtin_amdgcn_exp2f(x * 2.8853900818f);  // 2*log2(e)
  float r = __builtin_amdgcn_rcpf(e + 1.0f);
  return fmaf(-2.0f, r, 1.0f);
}

__device__ __forceinline__ ushort f2bf(float f) {
  uint u = __float_as_uint(f);
  uint r = (u + 0x7fffu + ((u >> 16) & 1u)) >> 16;   // RNE
  return (ushort)r;
}

__device__ __forceinline__ uint cvt_pk(float a, float b) {
  __hip_bfloat162 h = __float22bfloat162_rn(make_float2(a, b));
  return *reinterpret_cast<uint*>(&h);
}

// ---------------- kernel 1: spatial complex LN + metric -> xri bf16 [BT][H][32u][64w][8ci] ----------------
// Thread (w, q) owns c = q*64 .. q*64+63 -> emits 8 coalesced 16B units.

__global__ __launch_bounds__(256) void k_spatial_ln(
    const float* __restrict__ x_re, const float* __restrict__ x_im,
    const float* __restrict__ g, const float* __restrict__ bb,
    const float* __restrict__ metric, ushort* __restrict__ xri) {
  __shared__ float vals[256][64];
  __shared__ float red1[4][64];
  __shared__ float red2[4][64];
  __shared__ float mean_s[64];
  __shared__ float rstd_s[64];
  const int blk = blockIdx.x;      // bt*64 + h
  const int bt = blk >> 6;
  const int h = blk & 63;
  const int tid = threadIdx.x;
  const int w = tid & 63, q = tid >> 6;

  const float* src = (q < 2) ? x_re : x_im;   // wave-uniform
  float s1 = 0.f, s2 = 0.f;
  #pragma unroll 4
  for (int i = 0; i < 64; ++i) {
    const int c = q * 64 + i;
    const int d = c & 127;
    float v = src[((size_t)bt * D_ + d) * HW_ + h * W_ + w];
    vals[c][w] = v;
    s1 += v; s2 += v * v;
  }
  red1[q][w] = s1; red2[q][w] = s2;
  __syncthreads();
  if (tid < 64) {
    float m = red1[0][tid] + red1[1][tid] + red1[2][tid] + red1[3][tid];
    float ss = red2[0][tid] + red2[1][tid] + red2[2][tid] + red2[3][tid];
    m *= (1.f / 256.f);
    float var = ss * (1.f / 256.f) - m * m;
    mean_s[tid] = m;
    rstd_s[tid] = rsqrtf(var + 1e-5f);
  }
  __syncthreads();
  const float m = mean_s[w], rs = rstd_s[w];
  const size_t ubase = (((size_t)bt * 64 + h) * 32 + q * 8) * 512 + w * 8;
  #pragma unroll
  for (int j = 0; j < 8; ++j) {
    uint4 u;
    #pragma unroll
    for (int e2 = 0; e2 < 4; ++e2) {
      const int c0 = q * 64 + j * 8 + e2 * 2;
      float v0 = (vals[c0][w] - m) * rs * g[c0] + bb[c0];
      v0 *= metric[(size_t)c0 * HW_ + h * W_ + w];
      float v1 = (vals[c0 + 1][w] - m) * rs * g[c0 + 1] + bb[c0 + 1];
      v1 *= metric[(size_t)(c0 + 1) * HW_ + h * W_ + w];
      ((uint*)&u)[e2] = cvt_pk(v0, v1);
    }
    *(uint4*)&xri[ubase + (size_t)j * 512] = u;
  }
}

// ---------------- conv weight prep: fragment-order bf16 (K = ci straight) ----------------

__global__ __launch_bounds__(256) void k_prep_conv(
    const float* __restrict__ wg, ushort* __restrict__ cwswz) {
  const int t = blockIdx.x * 256 + threadIdx.x;   // 0..73727
  if (t >= 73728) return;
  const int lane = t & 63;
  const int nt = (t >> 6) & 15;
  const int ks = (t >> 10) & 7;
  const int kk = t >> 13;                         // 0..8
  const int co = nt * 16 + (lane & 15);
  const int ci0 = ks * 32 + (lane >> 4) * 8;
  ushort v[8];
  #pragma unroll
  for (int e = 0; e < 8; ++e)
    v[e] = f2bf(wg[((size_t)co * 256 + ci0 + e) * 9 + kk]);
  uint4 u;
  u.x = (uint)v[0] | ((uint)v[1] << 16);
  u.y = (uint)v[2] | ((uint)v[3] << 16);
  u.z = (uint)v[4] | ((uint)v[5] << 16);
  u.w = (uint)v[6] | ((uint)v[7] << 16);
  ((uint4*)cwswz)[t] = u;
}

// ---------------- kernel 2: 3x3 conv via bf16 MFMA (implicit GEMM) ----------------
// Unit-blocked LDS [4 rows][16 units][66 w][8ci], ci-split halves (66 KB -> 2 blocks/CU).
// Coalesced uint4 staging; compiler-scheduled A-frag loads (manual prefetch reverted).

__global__ __launch_bounds__(512, 4) void k_conv_mfma(
    const ushort* __restrict__ xri, const ushort* __restrict__ cwswz,
    const float* __restrict__ bias,
    const float* __restrict__ x_re, const float* __restrict__ x_im,
    float* __restrict__ x2_re, float* __restrict__ x2_im) {
  __shared__ ushort xb[33792];   // 4*16*66*8 ushorts = 66 KB
  const int tid = threadIdx.x;
  const int wave = tid >> 6, lane = tid & 63;
  const int lrow = lane & 15, lgrp = lane >> 4;
  const int blk = blockIdx.x;         // 1024 = bt*32 + hp
  const int bt = blk >> 5;
  const int h0 = (blk & 31) * 2;
  const int cw = wave & 3;
  const int sg = wave >> 2;

  f32x4 acc[4][4];
  #pragma unroll
  for (int j = 0; j < 4; ++j)
    #pragma unroll
    for (int i = 0; i < 4; ++i) acc[j][i] = (f32x4)0.f;

  for (int half = 0; half < 2; ++half) {
    __syncthreads();   // protect previous half's reads
    // zero halo (w slots 0 and 65)
    if (tid < 128) {
      const int j = tid >> 5;
      const int u = (tid >> 1) & 15;
      const int wz = (tid & 1) * 65;
      uint4 z = {0u, 0u, 0u, 0u};
      *(uint4*)&xb[((j * 16 + u) * 66 + wz) * 8] = z;
    }
    // coalesced staging: 8 iters x uint4
    #pragma unroll
    for (int i = 0; i < 8; ++i) {
      const int idx = i * 512 + tid;    // 0..4095
      const int w = idx & 63;
      const int u = (idx >> 6) & 15;
      const int j = idx >> 10;          // row 0..3
      const int hh = h0 + j - 1;
      uint4 v = {0u, 0u, 0u, 0u};
      if (hh >= 0 && hh < 64)
        v = *(const uint4*)&xri[(((size_t)bt * 64 + hh) * 32 + half * 16 + u) * 512
                                + w * 8];
      *(uint4*)&xb[((j * 16 + u) * 66 + 1 + w) * 8] = v;
    }
    __syncthreads();

    for (int kh = 0; kh < 3; ++kh) {
      for (int kw = 0; kw < 3; ++kw) {
        const int kk = kh * 3 + kw;
        #pragma unroll
        for (int ks = 0; ks < 4; ++ks) {
          bf16x8 bfr[4];
          #pragma unroll
          for (int i = 0; i < 4; ++i)
            bfr[i] = *(const bf16x8*)&xb[(((sg + kh) * 16 + ks * 4 + lgrp) * 66
                                          + i * 16 + lrow + kw) * 8];
          const int fbase = ((kk * 8 + half * 4 + ks) * 16 + cw * 4) * 64 + lane;
          #pragma unroll
          for (int j = 0; j < 4; ++j) {
            const bf16x8 afr = ((const bf16x8*)cwswz)[fbase + j * 64];
            #pragma unroll
            for (int i = 0; i < 4; ++i)
              acc[j][i] = __builtin_amdgcn_mfma_f32_16x16x32_bf16(
                  afr, bfr[i], acc[j][i], 0, 0, 0);
          }
        }
      }
    }
  }

  // epilogue: bias + residual, split re/im planar fp32
  #pragma unroll
  for (int j = 0; j < 4; ++j) {
    #pragma unroll
    for (int jj = 0; jj < 4; ++jj) {
      const int co = (cw * 4 + j) * 16 + lgrp * 4 + jj;
      const int d = co & 127;
      const float bv = bias[co];
      const float* rsrc = (co < 128) ? x_re : x_im;
      float* dst = (co < 128) ? x2_re : x2_im;
      const size_t rowoff = ((size_t)bt * D_ + d) * HW_ + (h0 + sg) * W_;
      #pragma unroll
      for (int i = 0; i < 4; ++i) {
        const int w = i * 16 + lrow;
        dst[rowoff + w] = acc[j][i][jj] + bv + rsrc[rowoff + w];
      }
    }
  }
}

// ---------------- decay/forcing table: [BT][128] float4 {decay_re, decay_im, f_re, f_im} ----------------

__global__ __launch_bounds__(256) void k_prep_decay(
    const float* __restrict__ dt, const float* __restrict__ nu,
    const float* __restrict__ theta, float4* __restrict__ decay) {
  const int idx = blockIdx.x * 256 + threadIdx.x;  // 0..4095
  const int d = idx & 127;
  const int bt = idx >> 7;
  const float dtv = dt[bt];
  const float lr = -softplus_f(nu[d]);
  const float li = theta[d];
  float s, c;
  sincosf(li * dtv, &s, &c);
  const float er = expf(lr * dtv);
  const float ar = er * c, ai = er * s;
  const float den = lr * lr + li * li;
  const float nr = ar - 1.f, ni = ai;
  float4 v;
  v.x = ar; v.y = ai;
  v.z = (nr * lr + ni * li) / den;
  v.w = (ni * lr - nr * li) / den;
  decay[idx] = v;
}

// ---------------- temporal-encode weight prep (K rows permuted to interleaved re/im) ----------------

__global__ __launch_bounds__(256) void k_prep_enc(
    const float* __restrict__ enc_re, const float* __restrict__ enc_im,
    const float* __restrict__ g, ushort* __restrict__ encswz) {
  const int t = blockIdx.x * 256 + threadIdx.x;   // 0..8191
  const int lane = t & 63;
  const int ks = (t >> 6) & 7;
  const int ntile = t >> 9;
  const int n = ntile * 16 + (lane & 15);
  const int k0 = ks * 32 + (lane >> 4) * 8;
  ushort v[8];
  #pragma unroll
  for (int e = 0; e < 8; ++e) {
    const int kp = k0 + e;
    const int k = (kp >> 1) | ((kp & 1) << 7);   // physical -> logical
    float val;
    if (k < 128) {
      val = (n < 128) ? enc_re[k * 128 + n] : enc_im[k * 128 + (n - 128)];
    } else {
      const int kk = k - 128;
      val = (n < 128) ? -enc_im[kk * 128 + n] : enc_re[kk * 128 + (n - 128)];
    }
    v[e] = f2bf(val * g[k]);
  }
  uint4 u;
  u.x = (uint)v[0] | ((uint)v[1] << 16);
  u.y = (uint)v[2] | ((uint)v[3] << 16);
  u.z = (uint)v[4] | ((uint)v[5] << 16);
  u.w = (uint)v[6] | ((uint)v[7] << 16);
  ((uint4*)encswz)[t] = u;
}

__global__ __launch_bounds__(256) void k_prep_encvec(
    const float* __restrict__ enc_re, const float* __restrict__ enc_im,
    const float* __restrict__ g, const float* __restrict__ bb,
    float* __restrict__ evec, float* __restrict__ cvec) {
  const int n = threadIdx.x;   // one block of 256
  float se = 0.f, sc = 0.f;
  for (int k = 0; k < 256; ++k) {
    float ep;
    if (k < 128) {
      ep = (n < 128) ? enc_re[k * 128 + n] : enc_im[k * 128 + (n - 128)];
    } else {
      const int kk = k - 128;
      ep = (n < 128) ? -enc_im[kk * 128 + n] : enc_re[kk * 128 + (n - 128)];
    }
    se = fmaf(g[k], ep, se);
    sc = fmaf(bb[k], ep, sc);
  }
  evec[n] = se;
  cvec[n] = sc;
}

__global__ __launch_bounds__(256) void k_prep_dec(
    const float* __restrict__ dec_re, const float* __restrict__ dec_im,
    ushort* __restrict__ decswz) {
  const int t = blockIdx.x * 256 + threadIdx.x;   // 0..4095
  const int lane = t & 63;
  const int ks = (t >> 6) & 7;
  const int ntile = t >> 9;
  const int n = ntile * 16 + (lane & 15);
  const int k0 = ks * 32 + (lane >> 4) * 8;
  ushort v[8];
  #pragma unroll
  for (int e = 0; e < 8; ++e) {
    const int kp = k0 + e;
    const int k = (kp >> 1) | ((kp & 1) << 7);
    float val = (k < 128) ? dec_re[k * 128 + n] : -dec_im[(k - 128) * 128 + n];
    v[e] = f2bf(val);
  }
  uint4 u;
  u.x = (uint)v[0] | ((uint)v[1] << 16);
  u.y = (uint)v[2] | ((uint)v[3] << 16);
  u.z = (uint)v[4] | ((uint)v[5] << 16);
  u.w = (uint)v[6] | ((uint)v[7] << 16);
  ((uint4*)decswz)[t] = u;
}

// ---------------- kernel 3: temporal LN (folded) + encode MFMA + src + ZOH -> u32 [T][D][N] ----------------

__global__ __launch_bounds__(256, 2) void k_temporal_mfma(
    const float* __restrict__ x2_re, const float* __restrict__ x2_im,
    const ushort* __restrict__ encswz,
    const float* __restrict__ evec, const float* __restrict__ cvec,
    const float4* __restrict__ decay,
    const float* __restrict__ src_gain,
    uint* __restrict__ u32) {
  __shared__ ushort xlds[64][256];
  __shared__ float red1[4][64], red2[4][64];
  __shared__ float mean_s[64], rstd_s[64];
  __shared__ float fre_s[128], fim_s[128], gain_s[128];
  const int tid = threadIdx.x;
  const int wave = tid >> 6, lane = tid & 63;
  const int lrow = lane & 15, lgrp = lane >> 4;
  const int blk = blockIdx.x;          // ((b*16)+t)*64 + h
  const int h = blk & 63;
  const int t = (blk >> 6) & 15;
  const int b = blk >> 10;
  const int bt = b * T_ + t;
  const size_t base = (size_t)bt * D_ * HW_ + h * W_;

  // stage RAW x2 -> bf16 LDS (interleaved re/im, swizzled b128 writes) + LN sums
  float s1 = 0.f, s2 = 0.f;
  #pragma unroll
  for (int i = 0; i < 8; ++i) {
    const int q = i * 4 + wave;        // d-quad 0..31
    const size_t g = base + (size_t)(q * 4) * HW_ + lane;
    float r0 = x2_re[g],           i0 = x2_im[g];
    float r1 = x2_re[g + HW_],     i1 = x2_im[g + HW_];
    float r2 = x2_re[g + 2 * HW_], i2 = x2_im[g + 2 * HW_];
    float r3 = x2_re[g + 3 * HW_], i3 = x2_im[g + 3 * HW_];
    uint4 u;
    u.x = cvt_pk(r0, i0); u.y = cvt_pk(r1, i1);
    u.z = cvt_pk(r2, i2); u.w = cvt_pk(r3, i3);
    *(uint4*)&xlds[lane][(q ^ (lane & 7)) << 3] = u;
    s1 += (r0 + r1 + r2 + r3) + (i0 + i1 + i2 + i3);
    s2 += r0 * r0 + r1 * r1 + r2 * r2 + r3 * r3
        + i0 * i0 + i1 * i1 + i2 * i2 + i3 * i3;
  }
  red1[wave][lane] = s1;
  red2[wave][lane] = s2;
  __syncthreads();
  if (tid < 64) {
    float m = red1[0][tid] + red1[1][tid] + red1[2][tid] + red1[3][tid];
    float ss = red2[0][tid] + red2[1][tid] + red2[2][tid] + red2[3][tid];
    m *= (1.f / 256.f);
    float var = ss * (1.f / 256.f) - m * m;
    mean_s[tid] = m;
    rstd_s[tid] = rsqrtf(var + 1e-5f);
  }
  if (tid < 128) {
    const float4 dc = decay[bt * 128 + tid];
    fre_s[tid] = dc.z;
    fim_s[tid] = dc.w;
    gain_s[tid] = src_gain[tid];
  }
  __syncthreads();

  f32x4 acc[4][4];
  #pragma unroll
  for (int ntl = 0; ntl < 4; ++ntl)
    #pragma unroll
    for (int st = 0; st < 4; ++st) acc[ntl][st] = (f32x4)0.f;

  const int swz = lrow & 7;   // site&7 is st-independent (st*16 ≡ 0 mod 8)
  const int ntb[4] = {wave * 2, wave * 2 + 1, wave * 2 + 8, wave * 2 + 9};
  #pragma unroll
  for (int ks = 0; ks < 8; ++ks) {
    bf16x8 bfr[4];
    #pragma unroll
    for (int st = 0; st < 4; ++st)
      bfr[st] = *(const bf16x8*)&xlds[st * 16 + lrow][(((ks * 4 + lgrp) ^ swz)) << 3];
    #pragma unroll
    for (int ntl = 0; ntl < 4; ++ntl) {
      const bf16x8 afr = ((const bf16x8*)encswz)[(ntb[ntl] * 8 + ks) * 64 + lane];
      #pragma unroll
      for (int st = 0; st < 4; ++st)
        acc[ntl][st] = __builtin_amdgcn_mfma_f32_16x16x32_bf16(
            afr, bfr[st], acc[ntl][st], 0, 0, 0);
    }
  }

  const int nbase = (b * 64 + h) * 64;
  #pragma unroll
  for (int ntl = 0; ntl < 2; ++ntl) {
    const int d0 = ntb[ntl] * 16 + lgrp * 4;    // <128
    #pragma unroll
    for (int st = 0; st < 4; ++st) {
      const int site = st * 16 + lrow;
      const float m = mean_s[site], rs = rstd_s[site];
      #pragma unroll
      for (int j = 0; j < 4; ++j) {
        const int d = d0 + j;
        const float xer = rs * acc[ntl][st][j] - rs * m * evec[d] + cvec[d];
        const float xei = rs * acc[ntl + 2][st][j] - rs * m * evec[d + 128] + cvec[d + 128];
        const float sr = tanh_fast(xer) * gain_s[d];
        const float si = tanh_fast(xei) * gain_s[d];
        const float vr = xer + sr, vi = xei + si;
        const float ur = vr * fre_s[d] - vi * fim_s[d];
        const float ui = vr * fim_s[d] + vi * fre_s[d];
        u32[(size_t)t * ND_ + (size_t)d * N_ + nbase + site] = cvt_pk(ur, ui);
      }
    }
  }
}

// ---------------- kernel 4: sequential scan over T (in place, packed bf16 u32 [T][D][N]) ----------------

__global__ __launch_bounds__(256) void k_scan(
    uint* __restrict__ u32, const float4* __restrict__ decay) {
  const int idx = blockIdx.x * 256 + threadIdx.x;   // d*N + n
  const int n = idx & 8191;
  const int d = idx >> 13;
  const int b = n >> 12;
  float hr = 0.f, hi = 0.f;
  #pragma unroll
  for (int t = 0; t < 16; ++t) {
    const float4 dc = decay[(b * 16 + t) * 128 + d];   // wave-uniform
    const size_t off = (size_t)t * ND_ + idx;
    const uint v = u32[off];
    const float ur = __uint_as_float(v << 16);
    const float ui = __uint_as_float(v & 0xffff0000u);
    const float nr = fmaf(dc.x, hr, fmaf(-dc.y, hi, ur));
    const float ni = fmaf(dc.x, hi, fmaf(dc.y, hr, ui));
    hr = nr; hi = ni;
    u32[off] = cvt_pk(hr, hi);
  }
}

// ---------------- kernel 5: decode via MFMA (real part) + residual (in place on x2_re) ----------------

__global__ __launch_bounds__(256, 2) void k_decode_mfma(
    const uint* __restrict__ h32, const ushort* __restrict__ decswz,
    float* __restrict__ x2_re) {
  __shared__ ushort xlds[64][256];
  const int tid = threadIdx.x;
  const int wave = tid >> 6, lane = tid & 63;
  const int lrow = lane & 15, lgrp = lane >> 4;
  const int blk = blockIdx.x;          // ((b*16)+t)*64 + h
  const int h = blk & 63;
  const int t = (blk >> 6) & 15;
  const int b = blk >> 10;
  const int bt = b * T_ + t;
  const int nbase = (b * 64 + h) * 64;

  #pragma unroll
  for (int i = 0; i < 8; ++i) {
    const int q = i * 4 + wave;        // d-quad
    const size_t o = (size_t)t * ND_ + (size_t)(q * 4) * N_ + nbase + lane;
    uint4 u;
    u.x = h32[o];
    u.y = h32[o + N_];
    u.z = h32[o + 2 * N_];
    u.w = h32[o + 3 * N_];
    *(uint4*)&xlds[lane][(q ^ (lane & 7)) << 3] = u;
  }
  __syncthreads();

  f32x4 acc[2][4];
  #pragma unroll
  for (int ntl = 0; ntl < 2; ++ntl)
    #pragma unroll
    for (int st = 0; st < 4; ++st) acc[ntl][st] = (f32x4)0.f;

  const int swz = lrow & 7;
  #pragma unroll
  for (int ks = 0; ks < 8; ++ks) {
    bf16x8 bfr[4];
    #pragma unroll
    for (int st = 0; st < 4; ++st)
      bfr[st] = *(const bf16x8*)&xlds[st * 16 + lrow][(((ks * 4 + lgrp) ^ swz)) << 3];
    #pragma unroll
    for (int ntl = 0; ntl < 2; ++ntl) {
      const int ntile = wave * 2 + ntl;
      const bf16x8 afr = ((const bf16x8*)decswz)[(ntile * 8 + ks) * 64 + lane];
      #pragma unroll
      for (int st = 0; st < 4; ++st)
        acc[ntl][st] = __builtin_amdgcn_mfma_f32_16x16x32_bf16(
            afr, bfr[st], acc[ntl][st], 0, 0, 0);
    }
  }

  #pragma unroll
  for (int ntl = 0; ntl < 2; ++ntl) {
    #pragma unroll
    for (int j = 0; j < 4; ++j) {
      const int d = (wave * 2 + ntl) * 16 + lgrp * 4 + j;
      const size_t rowoff = ((size_t)bt * D_ + d) * HW_ + h * W_;
      #pragma unroll
      for (int st = 0; st < 4; ++st) {
        const int site = st * 16 + lrow;
        x2_re[rowoff + site] += acc[ntl][st][j];
      }
    }
  }
}

// ---------------- FFN weight prep ----------------

__global__ __launch_bounds__(256) void k_prep_b1(
    const float* __restrict__ w1_re, const float* __restrict__ w1_im,
    ushort* __restrict__ b1swz) {
  const int t = blockIdx.x * 256 + threadIdx.x;   // 0..32767
  const int lane = t & 63;
  const int ks = (t >> 6) & 7;
  const int ntile = t >> 9;
  const int n = ntile * 16 + (lane & 15);
  const int k0 = ks * 32 + (lane >> 4) * 8;
  ushort v[8];
  #pragma unroll
  for (int e = 0; e < 8; ++e) {
    const int kp = k0 + e;
    const int k = (kp >> 1) | ((kp & 1) << 7);   // physical -> logical
    float val;
    if (k < 128) {
      val = (n < 512) ? w1_re[k * 512 + n] : w1_im[k * 512 + (n - 512)];
    } else {
      const int kk = k - 128;
      val = (n < 512) ? -w1_im[kk * 512 + n] : w1_re[kk * 512 + (n - 512)];
    }
    v[e] = f2bf(val);
  }
  uint4 u;
  u.x = (uint)v[0] | ((uint)v[1] << 16);
  u.y = (uint)v[2] | ((uint)v[3] << 16);
  u.z = (uint)v[4] | ((uint)v[5] << 16);
  u.w = (uint)v[6] | ((uint)v[7] << 16);
  ((uint4*)b1swz)[t] = u;
}

__global__ __launch_bounds__(256) void k_prep_b2(
    const float* __restrict__ w2_re, const float* __restrict__ w2_im,
    ushort* __restrict__ b2swz) {
  const int t = blockIdx.x * 256 + threadIdx.x;   // 0..32767
  const int lane = t & 63;
  const int kc = (t >> 6) & 31;
  const int rowtile = t >> 11;
  const int n2 = rowtile * 16 + (lane & 15);
  const int k0 = kc * 32 + (lane >> 4) * 8;
  ushort v[8];
  #pragma unroll
  for (int e = 0; e < 8; ++e) {
    const int k = k0 + e;                       // act layout unchanged: no permute
    float val;
    if (k < 512) {
      val = (n2 < 128) ? w2_re[k * 128 + n2] : w2_im[k * 128 + (n2 - 128)];
    } else {
      const int kk = k - 512;
      val = (n2 < 128) ? -w2_im[kk * 128 + n2] : w2_re[kk * 128 + (n2 - 128)];
    }
    v[e] = f2bf(val);
  }
  uint4 u;
  u.x = (uint)v[0] | ((uint)v[1] << 16);
  u.y = (uint)v[2] | ((uint)v[3] << 16);
  u.z = (uint)v[4] | ((uint)v[5] << 16);
  u.w = (uint)v[6] | ((uint)v[7] << 16);
  ((uint4*)b2swz)[t] = u;
}

// ---------------- kernel 6: complex FFN via bf16 MFMA ----------------
// Register-prefetched weight fragments, act double-buffer, one barrier per chunk,
// residual re-read from live xlds (bf16) instead of global.

__global__ __launch_bounds__(256, 2) void k_ffn_mfma(
    const float* __restrict__ x3_re, const float* __restrict__ x3_im,
    const ushort* __restrict__ b1swz, const ushort* __restrict__ b2swz,
    const float* __restrict__ b1_re, const float* __restrict__ b1_im,
    const float* __restrict__ b2_re, const float* __restrict__ b2_im,
    float* __restrict__ out) {
  __shared__ ushort xlds[64][256];
  __shared__ ushort actlds[2][64][136];
  const int tid = threadIdx.x;
  const int wave = tid >> 6, lane = tid & 63;
  const int lrow = lane & 15, lgrp = lane >> 4;
  const int blk = blockIdx.x;        // 2048 = bt*64 + h
  const int bt = blk >> 6;
  const int hw0 = (blk & 63) * 64;
  const size_t base = (size_t)bt * D_ * HW_ + hw0;
  const bf16x8* b1f = (const bf16x8*)b1swz;
  const bf16x8* b2f = (const bf16x8*)b2swz;

  #pragma unroll
  for (int i = 0; i < 8; ++i) {
    const int q = i * 4 + wave;        // d-quad 0..31
    const size_t g = base + (size_t)(q * 4) * HW_ + lane;
    uint4 u;
    u.x = cvt_pk(x3_re[g],           x3_im[g]);
    u.y = cvt_pk(x3_re[g + HW_],     x3_im[g + HW_]);
    u.z = cvt_pk(x3_re[g + 2 * HW_], x3_im[g + 2 * HW_]);
    u.w = cvt_pk(x3_re[g + 3 * HW_], x3_im[g + 3 * HW_]);
    *(uint4*)&xlds[lane][(q ^ (lane & 7)) << 3] = u;
  }

  // prefetch chunk-0 A-fragments (GEMM1 full; GEMM2 ks2 0-1)
  bf16x8 a1[2][8];
  #pragma unroll
  for (int ntl = 0; ntl < 2; ++ntl)
    #pragma unroll
    for (int ks = 0; ks < 8; ++ks)
      a1[ntl][ks] = b1f[((wave * 2 + ntl) * 8 + ks) * 64 + lane];
  bf16x8 a2[4][2];
  #pragma unroll
  for (int rt = 0; rt < 4; ++rt)
    #pragma unroll
    for (int k2 = 0; k2 < 2; ++k2)
      a2[rt][k2] = b2f[((wave * 4 + rt) * 32 + k2) * 64 + lane];

  __syncthreads();

  f32x4 dacc[4][4];
  #pragma unroll
  for (int rt = 0; rt < 4; ++rt)
    #pragma unroll
    for (int st = 0; st < 4; ++st) dacc[rt][st] = (f32x4)0.f;

  const int swz = lrow & 7;

  for (int chunk = 0; chunk < 8; ++chunk) {
    const int nc = (chunk + 1) & 7;

    // ---- GEMM1(chunk): a1 (prefetched) x xlds
    f32x4 hacc[2][4];
    #pragma unroll
    for (int ntl = 0; ntl < 2; ++ntl)
      #pragma unroll
      for (int st = 0; st < 4; ++st) hacc[ntl][st] = (f32x4)0.f;

    #pragma unroll
    for (int ks = 0; ks < 8; ++ks) {
      bf16x8 bfr[4];
      #pragma unroll
      for (int st = 0; st < 4; ++st)
        bfr[st] = *(const bf16x8*)&xlds[st * 16 + lrow][(((ks * 4 + lgrp) ^ swz)) << 3];
      #pragma unroll
      for (int ntl = 0; ntl < 2; ++ntl)
        #pragma unroll
        for (int st = 0; st < 4; ++st)
          hacc[ntl][st] = __builtin_amdgcn_mfma_f32_16x16x32_bf16(
              a1[ntl][ks], bfr[st], hacc[ntl][st], 0, 0, 0);
    }

    // ---- prefetch a1 for next chunk (hidden under gelu + barrier + GEMM2)
    #pragma unroll
    for (int ntl = 0; ntl < 2; ++ntl)
      #pragma unroll
      for (int ks = 0; ks < 8; ++ks)
        a1[ntl][ks] = b1f[((nc * 8 + wave * 2 + ntl) * 8 + ks) * 64 + lane];

    // ---- bias + gelu -> act[chunk&1]
    uint* act32 = (uint*)&actlds[chunk & 1][0][0];
    #pragma unroll
    for (int ntl = 0; ntl < 2; ++ntl) {
      const int nlocal0 = (wave * 2 + ntl) * 16 + lgrp * 4;
      const int ng0 = chunk * 128 + nlocal0;
      #pragma unroll
      for (int st = 0; st < 4; ++st) {
        float gv[4];
        #pragma unroll
        for (int j = 0; j < 4; ++j) {
          const int ng = ng0 + j;
          const float bias = (ng < 512) ? b1_re[ng] : b1_im[ng - 512];
          gv[j] = gelu_fast(hacc[ntl][st][j] + bias);
        }
        const int site = st * 16 + lrow;
        act32[site * 68 + (nlocal0 >> 1)] = cvt_pk(gv[0], gv[1]);
        act32[site * 68 + (nlocal0 >> 1) + 1] = cvt_pk(gv[2], gv[3]);
      }
    }

    // ---- load this chunk's GEMM2 ks2 2-3 frags
    bf16x8 a2b[4][2];
    #pragma unroll
    for (int rt = 0; rt < 4; ++rt)
      #pragma unroll
      for (int k2 = 0; k2 < 2; ++k2)
        a2b[rt][k2] = b2f[((wave * 4 + rt) * 32 + chunk * 4 + 2 + k2) * 64 + lane];

    __syncthreads();   // act[chunk&1] ready (one barrier/chunk)

    // ---- GEMM2(chunk)
    const ushort* actb = &actlds[chunk & 1][0][0];
    #pragma unroll
    for (int ks2 = 0; ks2 < 2; ++ks2) {
      bf16x8 bfr[4];
      #pragma unroll
      for (int st = 0; st < 4; ++st)
        bfr[st] = *(const bf16x8*)&actb[(st * 16 + lrow) * 136 + ks2 * 32 + lgrp * 8];
      #pragma unroll
      for (int rt = 0; rt < 4; ++rt)
        #pragma unroll
        for (int st = 0; st < 4; ++st)
          dacc[rt][st] = __builtin_amdgcn_mfma_f32_16x16x32_bf16(
              a2[rt][ks2], bfr[st], dacc[rt][st], 0, 0, 0);
    }
    #pragma unroll
    for (int ks2 = 0; ks2 < 2; ++ks2) {
      bf16x8 bfr[4];
      #pragma unroll
      for (int st = 0; st < 4; ++st)
        bfr[st] = *(const bf16x8*)&actb[(st * 16 + lrow) * 136 + (ks2 + 2) * 32 + lgrp * 8];
      #pragma unroll
      for (int rt = 0; rt < 4; ++rt)
        #pragma unroll
        for (int st = 0; st < 4; ++st)
          dacc[rt][st] = __builtin_amdgcn_mfma_f32_16x16x32_bf16(
              a2b[rt][ks2], bfr[st], dacc[rt][st], 0, 0, 0);
    }

    // ---- prefetch next chunk's GEMM2 ks2 0-1 frags
    #pragma unroll
    for (int rt = 0; rt < 4; ++rt)
      #pragma unroll
      for (int k2 = 0; k2 < 2; ++k2)
        a2[rt][k2] = b2f[((wave * 4 + rt) * 32 + nc * 4 + k2) * 64 + lane];
  }

  // epilogue: residual from xlds (bf16), bias2, interleaved [.,2] output
  #pragma unroll
  for (int rt = 0; rt < 4; ++rt) {
    #pragma unroll
    for (int j = 0; j < 4; ++j) {
      const int n2 = (wave * 4 + rt) * 16 + lgrp * 4 + j;
      const int d = n2 & 127;
      const int c = n2 >> 7;
      const float bias2 = c ? b2_im[d] : b2_re[d];
      #pragma unroll
      for (int st = 0; st < 4; ++st) {
        const int site = st * 16 + lrow;
        const uint pr = *(const uint*)&xlds[site][(((d >> 2) ^ (site & 7)) << 3)
                                                  + (d & 3) * 2];
        const float rv = c ? __uint_as_float(pr & 0xffff0000u)
                           : __uint_as_float(pr << 16);
        const size_t idx = (size_t)(bt * D_ + d) * HW_ + hw0 + site;
        out[idx * 2 + c] = rv + dacc[rt][st][j] + bias2;
      }
    }
  }
}

// ---------------- host launcher ----------------

extern "C" void kernel_launch(void* const* d_in, const int* in_sizes, int n_in,
                              void* d_out, int out_size, void* d_ws, size_t ws_size,
                              hipStream_t stream) {
  const float* x_re   = (const float*)d_in[0];
  const float* x_im   = (const float*)d_in[1];
  const float* dt     = (const float*)d_in[2];
  const float* ln_s_g = (const float*)d_in[3];
  const float* ln_s_b = (const float*)d_in[4];
  const float* ln_t_g = (const float*)d_in[5];
  const float* ln_t_b = (const float*)d_in[6];
  const float* metric = (const float*)d_in[7];
  const float* conv_w = (const float*)d_in[8];
  const float* conv_b = (const float*)d_in[9];
  const float* nu     = (const float*)d_in[10];
  const float* theta  = (const float*)d_in[11];
  const float* enc_re = (const float*)d_in[12];
  const float* enc_im = (const float*)d_in[13];
  const float* dec_re = (const float*)d_in[14];
  const float* dec_im = (const float*)d_in[15];
  const float* src_g  = (const float*)d_in[16];
  const float* w1_re  = (const float*)d_in[17];
  const float* w1_im  = (const float*)d_in[18];
  const float* b1_re  = (const float*)d_in[19];
  const float* b1_im  = (const float*)d_in[20];
  const float* w2_re  = (const float*)d_in[21];
  const float* w2_im  = (const float*)d_in[22];
  const float* b2_re  = (const float*)d_in[23];
  const float* b2_im  = (const float*)d_in[24];
  float* out = (float*)d_out;
  float* ws = (float*)d_ws;

  // workspace layout
  float* wt   = ws;                          // weight-prep region
  float* bufA = ws + WT_FLOATS;
  ushort* wt16  = (ushort*)wt;
  ushort* cwswz = wt16;                      // 589,824 bf16 (conv frags, dead after conv)
  ushort* b1swz = wt16;                      // 262,144 bf16
  ushort* b2swz = wt16 + 262144;             // 262,144 bf16
  ushort* encswz = wt16 + 524288;            // 65,536 bf16
  ushort* decswz = wt16 + 589824;            // 32,768 bf16
  float*  evec   = (float*)(wt16 + 622592);  // 256 f32
  float*  cvec   = evec + 256;               // 256 f32
  float4* decay  = (float4*)(cvec + 256);    // 4096 float4 (64 KB)
  ushort* xri_bf = (ushort*)bufA;            // 67 MB unit-blocked LN out (dead after conv)
  uint*   u32    = (uint*)bufA;              // 67 MB packed bf16 u/h (after conv)

  const size_t needA = (size_t)(WT_FLOATS + 2 * PLANE_ + 2 * PLANE_) * 4;
  const bool planA = ws_size >= needA;
  float *x2_re, *x2_im, *ffn_out;
  if (planA) {
    x2_re = bufA + 2 * (size_t)PLANE_;
    x2_im = x2_re + PLANE_;
    ffn_out = out;
  } else {
    x2_re = out;
    x2_im = out + PLANE_;
    ffn_out = bufA;
  }

  k_prep_conv<<<288, 256, 0, stream>>>(conv_w, cwswz);
  k_prep_decay<<<16, 256, 0, stream>>>(dt, nu, theta, decay);
  k_spatial_ln<<<BT_ * H_, 256, 0, stream>>>(x_re, x_im, ln_s_g, ln_s_b, metric, xri_bf);
  k_conv_mfma<<<BT_ * 32, 512, 0, stream>>>(xri_bf, cwswz, conv_b, x_re, x_im,
                                            x2_re, x2_im);
  // cwswz dead after conv; overwrite region with GEMM weights
  k_prep_b1<<<128, 256, 0, stream>>>(w1_re, w1_im, b1swz);
  k_prep_b2<<<128, 256, 0, stream>>>(w2_re, w2_im, b2swz);
  k_prep_enc<<<32, 256, 0, stream>>>(enc_re, enc_im, ln_t_g, encswz);
  k_prep_encvec<<<1, 256, 0, stream>>>(enc_re, enc_im, ln_t_g, ln_t_b, evec, cvec);
  k_prep_dec<<<16, 256, 0, stream>>>(dec_re, dec_im, decswz);
  k_temporal_mfma<<<B_ * T_ * H_, 256, 0, stream>>>(x2_re, x2_im, encswz,
                                                    evec, cvec, decay, src_g, u32);
  k_scan<<<ND_ / 256, 256, 0, stream>>>(u32, decay);
  k_decode_mfma<<<B_ * T_ * H_, 256, 0, stream>>>(u32, decswz, x2_re);
  k_ffn_mfma<<<BT_ * H_, 256, 0, stream>>>(x2_re, x2_im, b1swz, b2swz,
                                           b1_re, b1_im, b2_re, b2_im, ffn_out);
  if (!planA) {
    hipMemcpyAsync(d_out, ffn_out, (size_t)2 * PLANE_ * sizeof(float),
                   hipMemcpyDeviceToDevice, stream);
  }
}

// Round 8
// 664.812 us; speedup vs baseline: 9.1874x; 1.0441x over previous
//
#include <hip/hip_runtime.h>
#include <hip/hip_bf16.h>
#include <stdint.h>

#define B_   2
#define T_   16
#define D_   128
#define D2_  256
#define H_   64
#define W_   64
#define HW_  4096
#define BT_  32
#define N_   8192
#define ND_  1048576           // N_*D_
#define PLANE_ 16777216        // B*T*D*H*W  (one of re/im)
#define WT_FLOATS 589824       // 256*256*9

typedef short bf16x8 __attribute__((ext_vector_type(8)));
typedef float f32x4 __attribute__((ext_vector_type(4)));
typedef unsigned int uint;
typedef unsigned short ushort;

// ---------------- device helpers ----------------

__device__ __forceinline__ float softplus_f(float x) {
  return fmaxf(x, 0.0f) + log1pf(expf(-fabsf(x)));
}

__device__ __forceinline__ float gelu_fast(float x) {
  const float Ac = 2.3022082963f;   // 2*sqrt(2/pi)*log2(e)
  const float Bc = 0.1029437f;      // Ac*0.044715
  float t = x * x;
  float z = x * fmaf(Bc, t, Ac);
  float e = __builtin_amdgcn_exp2f(z);
  float r = __builtin_amdgcn_rcpf(e + 1.0f);
  return fmaf(-x, r, x);
}

__device__ __forceinline__ float tanh_fast(float x) {
  float e = __builtin_amdgcn_exp2f(x * 2.8853900818f);  // 2*log2(e)
  float r = __builtin_amdgcn_rcpf(e + 1.0f);
  return fmaf(-2.0f, r, 1.0f);
}

__device__ __forceinline__ ushort f2bf(float f) {
  uint u = __float_as_uint(f);
  uint r = (u + 0x7fffu + ((u >> 16) & 1u)) >> 16;   // RNE
  return (ushort)r;
}

__device__ __forceinline__ uint cvt_pk(float a, float b) {
  __hip_bfloat162 h = __float22bfloat162_rn(make_float2(a, b));
  return *reinterpret_cast<uint*>(&h);
}

// ---------------- kernel 1: spatial complex LN + metric -> xri bf16 [BT][H][32u][64w][8ci] ----------------

__global__ __launch_bounds__(256) void k_spatial_ln(
    const float* __restrict__ x_re, const float* __restrict__ x_im,
    const float* __restrict__ g, const float* __restrict__ bb,
    const float* __restrict__ metric, ushort* __restrict__ xri) {
  __shared__ float vals[256][64];
  __shared__ float red1[4][64];
  __shared__ float red2[4][64];
  __shared__ float mean_s[64];
  __shared__ float rstd_s[64];
  const int blk = blockIdx.x;      // bt*64 + h
  const int bt = blk >> 6;
  const int h = blk & 63;
  const int tid = threadIdx.x;
  const int w = tid & 63, q = tid >> 6;

  const float* src = (q < 2) ? x_re : x_im;   // wave-uniform
  float s1 = 0.f, s2 = 0.f;
  #pragma unroll 4
  for (int i = 0; i < 64; ++i) {
    const int c = q * 64 + i;
    const int d = c & 127;
    float v = src[((size_t)bt * D_ + d) * HW_ + h * W_ + w];
    vals[c][w] = v;
    s1 += v; s2 += v * v;
  }
  red1[q][w] = s1; red2[q][w] = s2;
  __syncthreads();
  if (tid < 64) {
    float m = red1[0][tid] + red1[1][tid] + red1[2][tid] + red1[3][tid];
    float ss = red2[0][tid] + red2[1][tid] + red2[2][tid] + red2[3][tid];
    m *= (1.f / 256.f);
    float var = ss * (1.f / 256.f) - m * m;
    mean_s[tid] = m;
    rstd_s[tid] = rsqrtf(var + 1e-5f);
  }
  __syncthreads();
  const float m = mean_s[w], rs = rstd_s[w];
  const size_t ubase = (((size_t)bt * 64 + h) * 32 + q * 8) * 512 + w * 8;
  #pragma unroll
  for (int j = 0; j < 8; ++j) {
    uint4 u;
    #pragma unroll
    for (int e2 = 0; e2 < 4; ++e2) {
      const int c0 = q * 64 + j * 8 + e2 * 2;
      float v0 = (vals[c0][w] - m) * rs * g[c0] + bb[c0];
      v0 *= metric[(size_t)c0 * HW_ + h * W_ + w];
      float v1 = (vals[c0 + 1][w] - m) * rs * g[c0 + 1] + bb[c0 + 1];
      v1 *= metric[(size_t)(c0 + 1) * HW_ + h * W_ + w];
      ((uint*)&u)[e2] = cvt_pk(v0, v1);
    }
    *(uint4*)&xri[ubase + (size_t)j * 512] = u;
  }
}

// ---------------- conv weight prep: fragment-order bf16 ----------------

__global__ __launch_bounds__(256) void k_prep_conv(
    const float* __restrict__ wg, ushort* __restrict__ cwswz) {
  const int t = blockIdx.x * 256 + threadIdx.x;   // 0..73727
  if (t >= 73728) return;
  const int lane = t & 63;
  const int nt = (t >> 6) & 15;
  const int ks = (t >> 10) & 7;
  const int kk = t >> 13;                         // 0..8
  const int co = nt * 16 + (lane & 15);
  const int ci0 = ks * 32 + (lane >> 4) * 8;
  ushort v[8];
  #pragma unroll
  for (int e = 0; e < 8; ++e)
    v[e] = f2bf(wg[((size_t)co * 256 + ci0 + e) * 9 + kk]);
  uint4 u;
  u.x = (uint)v[0] | ((uint)v[1] << 16);
  u.y = (uint)v[2] | ((uint)v[3] << 16);
  u.z = (uint)v[4] | ((uint)v[5] << 16);
  u.w = (uint)v[6] | ((uint)v[7] << 16);
  ((uint4*)cwswz)[t] = u;
}

// ---------------- kernel 2: 3x3 conv via bf16 MFMA -> x2p packed bf16 [BT][128][HW] ----------------
// Epilogue: im-waves (cw>=2) stash bf16 im in dead xb; re-waves pack uint and store.

__global__ __launch_bounds__(512, 4) void k_conv_mfma(
    const ushort* __restrict__ xri, const ushort* __restrict__ cwswz,
    const float* __restrict__ bias,
    const float* __restrict__ x_re, const float* __restrict__ x_im,
    uint* __restrict__ x2p) {
  __shared__ ushort xb[33792];   // 66 KB
  const int tid = threadIdx.x;
  const int wave = tid >> 6, lane = tid & 63;
  const int lrow = lane & 15, lgrp = lane >> 4;
  const int blk = blockIdx.x;         // 1024 = bt*32 + hp
  const int bt = blk >> 5;
  const int h0 = (blk & 31) * 2;
  const int cw = wave & 3;
  const int sg = wave >> 2;

  f32x4 acc[4][4];
  #pragma unroll
  for (int j = 0; j < 4; ++j)
    #pragma unroll
    for (int i = 0; i < 4; ++i) acc[j][i] = (f32x4)0.f;

  for (int half = 0; half < 2; ++half) {
    __syncthreads();   // protect previous half's reads
    if (tid < 128) {
      const int j = tid >> 5;
      const int u = (tid >> 1) & 15;
      const int wz = (tid & 1) * 65;
      uint4 z = {0u, 0u, 0u, 0u};
      *(uint4*)&xb[((j * 16 + u) * 66 + wz) * 8] = z;
    }
    #pragma unroll
    for (int i = 0; i < 8; ++i) {
      const int idx = i * 512 + tid;    // 0..4095
      const int w = idx & 63;
      const int u = (idx >> 6) & 15;
      const int j = idx >> 10;          // row 0..3
      const int hh = h0 + j - 1;
      uint4 v = {0u, 0u, 0u, 0u};
      if (hh >= 0 && hh < 64)
        v = *(const uint4*)&xri[(((size_t)bt * 64 + hh) * 32 + half * 16 + u) * 512
                                + w * 8];
      *(uint4*)&xb[((j * 16 + u) * 66 + 1 + w) * 8] = v;
    }
    __syncthreads();

    for (int kh = 0; kh < 3; ++kh) {
      for (int kw = 0; kw < 3; ++kw) {
        const int kk = kh * 3 + kw;
        #pragma unroll
        for (int ks = 0; ks < 4; ++ks) {
          bf16x8 bfr[4];
          #pragma unroll
          for (int i = 0; i < 4; ++i)
            bfr[i] = *(const bf16x8*)&xb[(((sg + kh) * 16 + ks * 4 + lgrp) * 66
                                          + i * 16 + lrow + kw) * 8];
          const int fbase = ((kk * 8 + half * 4 + ks) * 16 + cw * 4) * 64 + lane;
          #pragma unroll
          for (int j = 0; j < 4; ++j) {
            const bf16x8 afr = ((const bf16x8*)cwswz)[fbase + j * 64];
            #pragma unroll
            for (int i = 0; i < 4; ++i)
              acc[j][i] = __builtin_amdgcn_mfma_f32_16x16x32_bf16(
                  afr, bfr[i], acc[j][i], 0, 0, 0);
          }
        }
      }
    }
  }

  // ---- epilogue: cross-wave pack re/im -> x2p
  __syncthreads();   // xb reads done; reuse as im buffer [128 site][132 d-pad]
  if (cw >= 2) {
    #pragma unroll
    for (int j = 0; j < 4; ++j) {
      #pragma unroll
      for (int jj = 0; jj < 4; ++jj) {
        const int co = (cw * 4 + j) * 16 + lgrp * 4 + jj;   // 128..255
        const int d = co - 128;
        const float bv = bias[co];
        const size_t rowoff = ((size_t)bt * D_ + d) * HW_ + (h0 + sg) * W_;
        #pragma unroll
        for (int i = 0; i < 4; ++i) {
          const int w = i * 16 + lrow;
          const float imv = acc[j][i][jj] + bv + x_im[rowoff + w];
          xb[(sg * 64 + w) * 132 + d] = f2bf(imv);
        }
      }
    }
  }
  __syncthreads();
  if (cw < 2) {
    #pragma unroll
    for (int j = 0; j < 4; ++j) {
      #pragma unroll
      for (int jj = 0; jj < 4; ++jj) {
        const int d = (cw * 4 + j) * 16 + lgrp * 4 + jj;    // 0..127
        const float bv = bias[d];
        const size_t rowoff = ((size_t)bt * D_ + d) * HW_ + (h0 + sg) * W_;
        #pragma unroll
        for (int i = 0; i < 4; ++i) {
          const int w = i * 16 + lrow;
          const float rev = acc[j][i][jj] + bv + x_re[rowoff + w];
          const uint im16 = xb[(sg * 64 + w) * 132 + d];
          x2p[rowoff + w] = (uint)f2bf(rev) | (im16 << 16);
        }
      }
    }
  }
}

// ---------------- decay/forcing table ----------------

__global__ __launch_bounds__(256) void k_prep_decay(
    const float* __restrict__ dt, const float* __restrict__ nu,
    const float* __restrict__ theta, float4* __restrict__ decay) {
  const int idx = blockIdx.x * 256 + threadIdx.x;  // 0..4095
  const int d = idx & 127;
  const int bt = idx >> 7;
  const float dtv = dt[bt];
  const float lr = -softplus_f(nu[d]);
  const float li = theta[d];
  float s, c;
  sincosf(li * dtv, &s, &c);
  const float er = expf(lr * dtv);
  const float ar = er * c, ai = er * s;
  const float den = lr * lr + li * li;
  const float nr = ar - 1.f, ni = ai;
  float4 v;
  v.x = ar; v.y = ai;
  v.z = (nr * lr + ni * li) / den;
  v.w = (ni * lr - nr * li) / den;
  decay[idx] = v;
}

// ---------------- temporal-encode weight prep ----------------

__global__ __launch_bounds__(256) void k_prep_enc(
    const float* __restrict__ enc_re, const float* __restrict__ enc_im,
    const float* __restrict__ g, ushort* __restrict__ encswz) {
  const int t = blockIdx.x * 256 + threadIdx.x;   // 0..8191
  const int lane = t & 63;
  const int ks = (t >> 6) & 7;
  const int ntile = t >> 9;
  const int n = ntile * 16 + (lane & 15);
  const int k0 = ks * 32 + (lane >> 4) * 8;
  ushort v[8];
  #pragma unroll
  for (int e = 0; e < 8; ++e) {
    const int kp = k0 + e;
    const int k = (kp >> 1) | ((kp & 1) << 7);   // physical -> logical
    float val;
    if (k < 128) {
      val = (n < 128) ? enc_re[k * 128 + n] : enc_im[k * 128 + (n - 128)];
    } else {
      const int kk = k - 128;
      val = (n < 128) ? -enc_im[kk * 128 + n] : enc_re[kk * 128 + (n - 128)];
    }
    v[e] = f2bf(val * g[k]);
  }
  uint4 u;
  u.x = (uint)v[0] | ((uint)v[1] << 16);
  u.y = (uint)v[2] | ((uint)v[3] << 16);
  u.z = (uint)v[4] | ((uint)v[5] << 16);
  u.w = (uint)v[6] | ((uint)v[7] << 16);
  ((uint4*)encswz)[t] = u;
}

__global__ __launch_bounds__(256) void k_prep_encvec(
    const float* __restrict__ enc_re, const float* __restrict__ enc_im,
    const float* __restrict__ g, const float* __restrict__ bb,
    float* __restrict__ evec, float* __restrict__ cvec) {
  const int n = threadIdx.x;   // one block of 256
  float se = 0.f, sc = 0.f;
  for (int k = 0; k < 256; ++k) {
    float ep;
    if (k < 128) {
      ep = (n < 128) ? enc_re[k * 128 + n] : enc_im[k * 128 + (n - 128)];
    } else {
      const int kk = k - 128;
      ep = (n < 128) ? -enc_im[kk * 128 + n] : enc_re[kk * 128 + (n - 128)];
    }
    se = fmaf(g[k], ep, se);
    sc = fmaf(bb[k], ep, sc);
  }
  evec[n] = se;
  cvec[n] = sc;
}

__global__ __launch_bounds__(256) void k_prep_dec(
    const float* __restrict__ dec_re, const float* __restrict__ dec_im,
    ushort* __restrict__ decswz) {
  const int t = blockIdx.x * 256 + threadIdx.x;   // 0..4095
  const int lane = t & 63;
  const int ks = (t >> 6) & 7;
  const int ntile = t >> 9;
  const int n = ntile * 16 + (lane & 15);
  const int k0 = ks * 32 + (lane >> 4) * 8;
  ushort v[8];
  #pragma unroll
  for (int e = 0; e < 8; ++e) {
    const int kp = k0 + e;
    const int k = (kp >> 1) | ((kp & 1) << 7);
    float val = (k < 128) ? dec_re[k * 128 + n] : -dec_im[(k - 128) * 128 + n];
    v[e] = f2bf(val);
  }
  uint4 u;
  u.x = (uint)v[0] | ((uint)v[1] << 16);
  u.y = (uint)v[2] | ((uint)v[3] << 16);
  u.z = (uint)v[4] | ((uint)v[5] << 16);
  u.w = (uint)v[6] | ((uint)v[7] << 16);
  ((uint4*)decswz)[t] = u;
}

// ---------------- kernel 3: temporal LN (folded) + encode MFMA + src + ZOH -> u32 [T][D][N] ----------------

__global__ __launch_bounds__(256, 2) void k_temporal_mfma(
    const uint* __restrict__ x2p,
    const ushort* __restrict__ encswz,
    const float* __restrict__ evec, const float* __restrict__ cvec,
    const float4* __restrict__ decay,
    const float* __restrict__ src_gain,
    uint* __restrict__ u32) {
  __shared__ ushort xlds[64][256];
  __shared__ float red1[4][64], red2[4][64];
  __shared__ float mean_s[64], rstd_s[64];
  __shared__ float fre_s[128], fim_s[128], gain_s[128];
  const int tid = threadIdx.x;
  const int wave = tid >> 6, lane = tid & 63;
  const int lrow = lane & 15, lgrp = lane >> 4;
  const int blk = blockIdx.x;          // ((b*16)+t)*64 + h
  const int h = blk & 63;
  const int t = (blk >> 6) & 15;
  const int b = blk >> 10;
  const int bt = b * T_ + t;

  // stage packed x2 -> LDS (pass-through) + LN sums
  float s1 = 0.f, s2 = 0.f;
  #pragma unroll
  for (int i = 0; i < 8; ++i) {
    const int q = i * 4 + wave;        // d-quad 0..31
    const uint* src = &x2p[((size_t)bt * D_ + q * 4) * HW_ + h * W_ + lane];
    uint4 u;
    u.x = src[0];
    u.y = src[HW_];
    u.z = src[2 * HW_];
    u.w = src[3 * HW_];
    *(uint4*)&xlds[lane][(q ^ (lane & 7)) << 3] = u;
    #pragma unroll
    for (int e = 0; e < 4; ++e) {
      const uint v = ((const uint*)&u)[e];
      const float re = __uint_as_float(v << 16);
      const float im = __uint_as_float(v & 0xffff0000u);
      s1 += re + im;
      s2 += re * re + im * im;
    }
  }
  red1[wave][lane] = s1;
  red2[wave][lane] = s2;
  __syncthreads();
  if (tid < 64) {
    float m = red1[0][tid] + red1[1][tid] + red1[2][tid] + red1[3][tid];
    float ss = red2[0][tid] + red2[1][tid] + red2[2][tid] + red2[3][tid];
    m *= (1.f / 256.f);
    float var = ss * (1.f / 256.f) - m * m;
    mean_s[tid] = m;
    rstd_s[tid] = rsqrtf(var + 1e-5f);
  }
  if (tid < 128) {
    const float4 dc = decay[bt * 128 + tid];
    fre_s[tid] = dc.z;
    fim_s[tid] = dc.w;
    gain_s[tid] = src_gain[tid];
  }
  __syncthreads();

  f32x4 acc[4][4];
  #pragma unroll
  for (int ntl = 0; ntl < 4; ++ntl)
    #pragma unroll
    for (int st = 0; st < 4; ++st) acc[ntl][st] = (f32x4)0.f;

  const int swz = lrow & 7;
  const int ntb[4] = {wave * 2, wave * 2 + 1, wave * 2 + 8, wave * 2 + 9};
  #pragma unroll
  for (int ks = 0; ks < 8; ++ks) {
    bf16x8 bfr[4];
    #pragma unroll
    for (int st = 0; st < 4; ++st)
      bfr[st] = *(const bf16x8*)&xlds[st * 16 + lrow][(((ks * 4 + lgrp) ^ swz)) << 3];
    #pragma unroll
    for (int ntl = 0; ntl < 4; ++ntl) {
      const bf16x8 afr = ((const bf16x8*)encswz)[(ntb[ntl] * 8 + ks) * 64 + lane];
      #pragma unroll
      for (int st = 0; st < 4; ++st)
        acc[ntl][st] = __builtin_amdgcn_mfma_f32_16x16x32_bf16(
            afr, bfr[st], acc[ntl][st], 0, 0, 0);
    }
  }

  const int nbase = (b * 64 + h) * 64;
  #pragma unroll
  for (int ntl = 0; ntl < 2; ++ntl) {
    const int d0 = ntb[ntl] * 16 + lgrp * 4;    // <128
    #pragma unroll
    for (int st = 0; st < 4; ++st) {
      const int site = st * 16 + lrow;
      const float m = mean_s[site], rs = rstd_s[site];
      #pragma unroll
      for (int j = 0; j < 4; ++j) {
        const int d = d0 + j;
        const float xer = rs * acc[ntl][st][j] - rs * m * evec[d] + cvec[d];
        const float xei = rs * acc[ntl + 2][st][j] - rs * m * evec[d + 128] + cvec[d + 128];
        const float sr = tanh_fast(xer) * gain_s[d];
        const float si = tanh_fast(xei) * gain_s[d];
        const float vr = xer + sr, vi = xei + si;
        const float ur = vr * fre_s[d] - vi * fim_s[d];
        const float ui = vr * fim_s[d] + vi * fre_s[d];
        u32[(size_t)t * ND_ + (size_t)d * N_ + nbase + site] = cvt_pk(ur, ui);
      }
    }
  }
}

// ---------------- kernel 4: sequential scan over T (in place, packed bf16 u32 [T][D][N]) ----------------

__global__ __launch_bounds__(256) void k_scan(
    uint* __restrict__ u32, const float4* __restrict__ decay) {
  const int idx = blockIdx.x * 256 + threadIdx.x;   // d*N + n
  const int n = idx & 8191;
  const int d = idx >> 13;
  const int b = n >> 12;
  float hr = 0.f, hi = 0.f;
  #pragma unroll
  for (int t = 0; t < 16; ++t) {
    const float4 dc = decay[(b * 16 + t) * 128 + d];   // wave-uniform
    const size_t off = (size_t)t * ND_ + idx;
    const uint v = u32[off];
    const float ur = __uint_as_float(v << 16);
    const float ui = __uint_as_float(v & 0xffff0000u);
    const float nr = fmaf(dc.x, hr, fmaf(-dc.y, hi, ur));
    const float ni = fmaf(dc.x, hi, fmaf(dc.y, hr, ui));
    hr = nr; hi = ni;
    u32[off] = cvt_pk(hr, hi);
  }
}

// ---------------- FFN weight prep ----------------

__global__ __launch_bounds__(256) void k_prep_b1(
    const float* __restrict__ w1_re, const float* __restrict__ w1_im,
    ushort* __restrict__ b1swz) {
  const int t = blockIdx.x * 256 + threadIdx.x;   // 0..32767
  const int lane = t & 63;
  const int ks = (t >> 6) & 7;
  const int ntile = t >> 9;
  const int n = ntile * 16 + (lane & 15);
  const int k0 = ks * 32 + (lane >> 4) * 8;
  ushort v[8];
  #pragma unroll
  for (int e = 0; e < 8; ++e) {
    const int kp = k0 + e;
    const int k = (kp >> 1) | ((kp & 1) << 7);   // physical -> logical
    float val;
    if (k < 128) {
      val = (n < 512) ? w1_re[k * 512 + n] : w1_im[k * 512 + (n - 512)];
    } else {
      const int kk = k - 128;
      val = (n < 512) ? -w1_im[kk * 512 + n] : w1_re[kk * 512 + (n - 512)];
    }
    v[e] = f2bf(val);
  }
  uint4 u;
  u.x = (uint)v[0] | ((uint)v[1] << 16);
  u.y = (uint)v[2] | ((uint)v[3] << 16);
  u.z = (uint)v[4] | ((uint)v[5] << 16);
  u.w = (uint)v[6] | ((uint)v[7] << 16);
  ((uint4*)b1swz)[t] = u;
}

__global__ __launch_bounds__(256) void k_prep_b2(
    const float* __restrict__ w2_re, const float* __restrict__ w2_im,
    ushort* __restrict__ b2swz) {
  const int t = blockIdx.x * 256 + threadIdx.x;   // 0..32767
  const int lane = t & 63;
  const int kc = (t >> 6) & 31;
  const int rowtile = t >> 11;
  const int n2 = rowtile * 16 + (lane & 15);
  const int k0 = kc * 32 + (lane >> 4) * 8;
  ushort v[8];
  #pragma unroll
  for (int e = 0; e < 8; ++e) {
    const int k = k0 + e;                       // act layout: no permute
    float val;
    if (k < 512) {
      val = (n2 < 128) ? w2_re[k * 128 + n2] : w2_im[k * 128 + (n2 - 128)];
    } else {
      const int kk = k - 512;
      val = (n2 < 128) ? -w2_im[kk * 128 + n2] : w2_re[kk * 128 + (n2 - 128)];
    }
    v[e] = f2bf(val);
  }
  uint4 u;
  u.x = (uint)v[0] | ((uint)v[1] << 16);
  u.y = (uint)v[2] | ((uint)v[3] << 16);
  u.z = (uint)v[4] | ((uint)v[5] << 16);
  u.w = (uint)v[6] | ((uint)v[7] << 16);
  ((uint4*)b2swz)[t] = u;
}

// ---------------- kernel 6: drift-decode (fused) + complex FFN via bf16 MFMA ----------------
// Stages x2p + h; drift GEMM adds decode into xlds re-halves; then the chunked FFN.

__global__ __launch_bounds__(256, 2) void k_ffn_mfma(
    const uint* __restrict__ x2p, const uint* __restrict__ h32,
    const ushort* __restrict__ decswz,
    const ushort* __restrict__ b1swz, const ushort* __restrict__ b2swz,
    const float* __restrict__ b1_re, const float* __restrict__ b1_im,
    const float* __restrict__ b2_re, const float* __restrict__ b2_im,
    float* __restrict__ out) {
  __shared__ ushort xlds[64][256];
  __shared__ ushort actlds[2][64][136];
  const int tid = threadIdx.x;
  const int wave = tid >> 6, lane = tid & 63;
  const int lrow = lane & 15, lgrp = lane >> 4;
  const int blk = blockIdx.x;        // 2048 = bt*64 + h
  const int bt = blk >> 6;
  const int hrow = blk & 63;
  const int hw0 = hrow * 64;
  const int b = bt >> 4, t = bt & 15;
  const int nbase = (b * 64 + hrow) * 64;
  const bf16x8* b1f = (const bf16x8*)b1swz;
  const bf16x8* b2f = (const bf16x8*)b2swz;
  const bf16x8* dcf = (const bf16x8*)decswz;
  ushort* hbuf = &actlds[0][0][0];   // [64 site][264 pad] view, dead before chunk 0

  // stage x2 (packed, pass-through) and h (packed)
  #pragma unroll
  for (int i = 0; i < 8; ++i) {
    const int q = i * 4 + wave;        // d-quad 0..31
    const uint* src = &x2p[((size_t)bt * D_ + q * 4) * HW_ + hw0 + lane];
    uint4 u;
    u.x = src[0]; u.y = src[HW_]; u.z = src[2 * HW_]; u.w = src[3 * HW_];
    *(uint4*)&xlds[lane][(q ^ (lane & 7)) << 3] = u;
  }
  #pragma unroll
  for (int i = 0; i < 8; ++i) {
    const int q = i * 4 + wave;
    const size_t o = (size_t)t * ND_ + (size_t)(q * 4) * N_ + nbase + lane;
    uint4 u;
    u.x = h32[o]; u.y = h32[o + N_]; u.z = h32[o + 2 * N_]; u.w = h32[o + 3 * N_];
    *(uint4*)&hbuf[lane * 264 + ((q ^ (lane & 7)) << 3)] = u;
  }

  // prefetch chunk-0 A-fragments
  bf16x8 a1[2][8];
  #pragma unroll
  for (int ntl = 0; ntl < 2; ++ntl)
    #pragma unroll
    for (int ks = 0; ks < 8; ++ks)
      a1[ntl][ks] = b1f[((wave * 2 + ntl) * 8 + ks) * 64 + lane];
  bf16x8 a2[4][2];
  #pragma unroll
  for (int rt = 0; rt < 4; ++rt)
    #pragma unroll
    for (int k2 = 0; k2 < 2; ++k2)
      a2[rt][k2] = b2f[((wave * 4 + rt) * 32 + k2) * 64 + lane];

  __syncthreads();
  const int swz = lrow & 7;

  // ---- fused decode: drift = h @ decP (real), RMW into xlds re-halves
  {
    f32x4 dr[2][4];
    #pragma unroll
    for (int ntl = 0; ntl < 2; ++ntl)
      #pragma unroll
      for (int st = 0; st < 4; ++st) dr[ntl][st] = (f32x4)0.f;
    #pragma unroll
    for (int ks = 0; ks < 8; ++ks) {
      bf16x8 bfr[4];
      #pragma unroll
      for (int st = 0; st < 4; ++st)
        bfr[st] = *(const bf16x8*)&hbuf[(st * 16 + lrow) * 264
                                        + (((ks * 4 + lgrp) ^ swz) << 3)];
      #pragma unroll
      for (int ntl = 0; ntl < 2; ++ntl) {
        const bf16x8 afr = dcf[((wave * 2 + ntl) * 8 + ks) * 64 + lane];
        #pragma unroll
        for (int st = 0; st < 4; ++st)
          dr[ntl][st] = __builtin_amdgcn_mfma_f32_16x16x32_bf16(
              afr, bfr[st], dr[ntl][st], 0, 0, 0);
      }
    }
    #pragma unroll
    for (int ntl = 0; ntl < 2; ++ntl) {
      #pragma unroll
      for (int st = 0; st < 4; ++st) {
        const int site = st * 16 + lrow;
        #pragma unroll
        for (int j = 0; j < 4; ++j) {
          const int d = (wave * 2 + ntl) * 16 + lgrp * 4 + j;
          ushort* p = &xlds[site][(((d >> 2) ^ (site & 7)) << 3) + (d & 3) * 2];
          const uint v = *(uint*)p;
          const float re = __uint_as_float(v << 16) + dr[ntl][st][j];
          *(uint*)p = (v & 0xffff0000u) | (uint)f2bf(re);
        }
      }
    }
  }
  __syncthreads();   // xlds now holds x3; hbuf (actlds) free

  f32x4 dacc[4][4];
  #pragma unroll
  for (int rt = 0; rt < 4; ++rt)
    #pragma unroll
    for (int st = 0; st < 4; ++st) dacc[rt][st] = (f32x4)0.f;

  for (int chunk = 0; chunk < 8; ++chunk) {
    const int nc = (chunk + 1) & 7;

    // ---- GEMM1(chunk)
    f32x4 hacc[2][4];
    #pragma unroll
    for (int ntl = 0; ntl < 2; ++ntl)
      #pragma unroll
      for (int st = 0; st < 4; ++st) hacc[ntl][st] = (f32x4)0.f;

    #pragma unroll
    for (int ks = 0; ks < 8; ++ks) {
      bf16x8 bfr[4];
      #pragma unroll
      for (int st = 0; st < 4; ++st)
        bfr[st] = *(const bf16x8*)&xlds[st * 16 + lrow][(((ks * 4 + lgrp) ^ swz)) << 3];
      #pragma unroll
      for (int ntl = 0; ntl < 2; ++ntl)
        #pragma unroll
        for (int st = 0; st < 4; ++st)
          hacc[ntl][st] = __builtin_amdgcn_mfma_f32_16x16x32_bf16(
              a1[ntl][ks], bfr[st], hacc[ntl][st], 0, 0, 0);
    }

    // ---- prefetch a1 for next chunk
    #pragma unroll
    for (int ntl = 0; ntl < 2; ++ntl)
      #pragma unroll
      for (int ks = 0; ks < 8; ++ks)
        a1[ntl][ks] = b1f[((nc * 8 + wave * 2 + ntl) * 8 + ks) * 64 + lane];

    // ---- bias + gelu -> act[chunk&1]
    uint* act32 = (uint*)&actlds[chunk & 1][0][0];
    #pragma unroll
    for (int ntl = 0; ntl < 2; ++ntl) {
      const int nlocal0 = (wave * 2 + ntl) * 16 + lgrp * 4;
      const int ng0 = chunk * 128 + nlocal0;
      #pragma unroll
      for (int st = 0; st < 4; ++st) {
        float gv[4];
        #pragma unroll
        for (int j = 0; j < 4; ++j) {
          const int ng = ng0 + j;
          const float bias = (ng < 512) ? b1_re[ng] : b1_im[ng - 512];
          gv[j] = gelu_fast(hacc[ntl][st][j] + bias);
        }
        const int site = st * 16 + lrow;
        act32[site * 68 + (nlocal0 >> 1)] = cvt_pk(gv[0], gv[1]);
        act32[site * 68 + (nlocal0 >> 1) + 1] = cvt_pk(gv[2], gv[3]);
      }
    }

    // ---- load this chunk's GEMM2 ks2 2-3 frags
    bf16x8 a2b[4][2];
    #pragma unroll
    for (int rt = 0; rt < 4; ++rt)
      #pragma unroll
      for (int k2 = 0; k2 < 2; ++k2)
        a2b[rt][k2] = b2f[((wave * 4 + rt) * 32 + chunk * 4 + 2 + k2) * 64 + lane];

    __syncthreads();   // act[chunk&1] ready (one barrier/chunk)

    // ---- GEMM2(chunk)
    const ushort* actb = &actlds[chunk & 1][0][0];
    #pragma unroll
    for (int ks2 = 0; ks2 < 2; ++ks2) {
      bf16x8 bfr[4];
      #pragma unroll
      for (int st = 0; st < 4; ++st)
        bfr[st] = *(const bf16x8*)&actb[(st * 16 + lrow) * 136 + ks2 * 32 + lgrp * 8];
      #pragma unroll
      for (int rt = 0; rt < 4; ++rt)
        #pragma unroll
        for (int st = 0; st < 4; ++st)
          dacc[rt][st] = __builtin_amdgcn_mfma_f32_16x16x32_bf16(
              a2[rt][ks2], bfr[st], dacc[rt][st], 0, 0, 0);
    }
    #pragma unroll
    for (int ks2 = 0; ks2 < 2; ++ks2) {
      bf16x8 bfr[4];
      #pragma unroll
      for (int st = 0; st < 4; ++st)
        bfr[st] = *(const bf16x8*)&actb[(st * 16 + lrow) * 136 + (ks2 + 2) * 32 + lgrp * 8];
      #pragma unroll
      for (int rt = 0; rt < 4; ++rt)
        #pragma unroll
        for (int st = 0; st < 4; ++st)
          dacc[rt][st] = __builtin_amdgcn_mfma_f32_16x16x32_bf16(
              a2b[rt][ks2], bfr[st], dacc[rt][st], 0, 0, 0);
    }

    // ---- prefetch next chunk's GEMM2 ks2 0-1 frags
    #pragma unroll
    for (int rt = 0; rt < 4; ++rt)
      #pragma unroll
      for (int k2 = 0; k2 < 2; ++k2)
        a2[rt][k2] = b2f[((wave * 4 + rt) * 32 + nc * 4 + k2) * 64 + lane];
  }

  // epilogue: residual x3 from xlds, bias2, interleaved [.,2] output
  #pragma unroll
  for (int rt = 0; rt < 4; ++rt) {
    #pragma unroll
    for (int j = 0; j < 4; ++j) {
      const int n2 = (wave * 4 + rt) * 16 + lgrp * 4 + j;
      const int d = n2 & 127;
      const int c = n2 >> 7;
      const float bias2 = c ? b2_im[d] : b2_re[d];
      #pragma unroll
      for (int st = 0; st < 4; ++st) {
        const int site = st * 16 + lrow;
        const uint pr = *(const uint*)&xlds[site][(((d >> 2) ^ (site & 7)) << 3)
                                                  + (d & 3) * 2];
        const float rv = c ? __uint_as_float(pr & 0xffff0000u)
                           : __uint_as_float(pr << 16);
        const size_t idx = (size_t)(bt * D_ + d) * HW_ + hw0 + site;
        out[idx * 2 + c] = rv + dacc[rt][st][j] + bias2;
      }
    }
  }
}

// ---------------- host launcher ----------------

extern "C" void kernel_launch(void* const* d_in, const int* in_sizes, int n_in,
                              void* d_out, int out_size, void* d_ws, size_t ws_size,
                              hipStream_t stream) {
  const float* x_re   = (const float*)d_in[0];
  const float* x_im   = (const float*)d_in[1];
  const float* dt     = (const float*)d_in[2];
  const float* ln_s_g = (const float*)d_in[3];
  const float* ln_s_b = (const float*)d_in[4];
  const float* ln_t_g = (const float*)d_in[5];
  const float* ln_t_b = (const float*)d_in[6];
  const float* metric = (const float*)d_in[7];
  const float* conv_w = (const float*)d_in[8];
  const float* conv_b = (const float*)d_in[9];
  const float* nu     = (const float*)d_in[10];
  const float* theta  = (const float*)d_in[11];
  const float* enc_re = (const float*)d_in[12];
  const float* enc_im = (const float*)d_in[13];
  const float* dec_re = (const float*)d_in[14];
  const float* dec_im = (const float*)d_in[15];
  const float* src_g  = (const float*)d_in[16];
  const float* w1_re  = (const float*)d_in[17];
  const float* w1_im  = (const float*)d_in[18];
  const float* b1_re  = (const float*)d_in[19];
  const float* b1_im  = (const float*)d_in[20];
  const float* w2_re  = (const float*)d_in[21];
  const float* w2_im  = (const float*)d_in[22];
  const float* b2_re  = (const float*)d_in[23];
  const float* b2_im  = (const float*)d_in[24];
  float* out = (float*)d_out;
  float* ws = (float*)d_ws;

  // workspace layout
  float* wt   = ws;                          // weight-prep region (~2.5 MB)
  float* bufA = ws + WT_FLOATS;
  ushort* wt16  = (ushort*)wt;
  ushort* cwswz = wt16;                      // conv frags (dead after conv)
  ushort* b1swz = wt16;                      // FFN frags (overwrite after conv)
  ushort* b2swz = wt16 + 262144;
  ushort* encswz = wt16 + 524288;
  ushort* decswz = wt16 + 589824;
  float*  evec   = (float*)(wt16 + 622592);
  float*  cvec   = evec + 256;
  float4* decay  = (float4*)(cvec + 256);    // 64 KB
  ushort* xri_bf = (ushort*)bufA;            // 67 MB (dead after conv)

  const size_t needA = ((size_t)WT_FLOATS + 2 * (size_t)PLANE_) * 4 + (1u << 20);
  const bool planA = ws_size >= needA;
  uint *u32p, *x2p;
  float* ffn_out;
  if (planA) {
    u32p = (uint*)bufA;                 // 67 MB (overwrites dead xri)
    x2p  = (uint*)bufA + PLANE_;        // 67 MB
    ffn_out = out;
  } else {
    // route intermediates through d_out; final d2d copy restores result
    u32p = (uint*)out;
    x2p  = (uint*)out + PLANE_;
    ffn_out = bufA;
  }

  k_prep_conv<<<288, 256, 0, stream>>>(conv_w, cwswz);
  k_prep_decay<<<16, 256, 0, stream>>>(dt, nu, theta, decay);
  k_spatial_ln<<<BT_ * H_, 256, 0, stream>>>(x_re, x_im, ln_s_g, ln_s_b, metric, xri_bf);
  k_conv_mfma<<<BT_ * 32, 512, 0, stream>>>(xri_bf, cwswz, conv_b, x_re, x_im, x2p);
  // cwswz dead after conv; overwrite region with GEMM weights
  k_prep_b1<<<128, 256, 0, stream>>>(w1_re, w1_im, b1swz);
  k_prep_b2<<<128, 256, 0, stream>>>(w2_re, w2_im, b2swz);
  k_prep_enc<<<32, 256, 0, stream>>>(enc_re, enc_im, ln_t_g, encswz);
  k_prep_encvec<<<1, 256, 0, stream>>>(enc_re, enc_im, ln_t_g, ln_t_b, evec, cvec);
  k_prep_dec<<<16, 256, 0, stream>>>(dec_re, dec_im, decswz);
  k_temporal_mfma<<<B_ * T_ * H_, 256, 0, stream>>>(x2p, encswz, evec, cvec,
                                                    decay, src_g, u32p);
  k_scan<<<ND_ / 256, 256, 0, stream>>>(u32p, decay);
  k_ffn_mfma<<<BT_ * H_, 256, 0, stream>>>(x2p, u32p, decswz, b1swz, b2swz,
                                           b1_re, b1_im, b2_re, b2_im, ffn_out);
  if (!planA) {
    hipMemcpyAsync(d_out, ffn_out, (size_t)2 * PLANE_ * sizeof(float),
                   hipMemcpyDeviceToDevice, stream);
  }
}